// Round 1
// baseline (1113.917 us; speedup 1.0000x reference)
//
#include <hip/hip_runtime.h>

#define DEV __device__ __forceinline__

// ---------------- constants ----------------
// N_NODES=32768, N_EDGES=65536, H=8, D=64, DS=63, M=128, R=H*N=262144
#define NNODES 32768
#define NEDGES 65536
#define NROWS  262144
#define EPSF   1e-7f
#define INV_SQRT63 0.1259881576697424f
#define SQRT2F 1.4142135623730951f

// ---------------- ws layout (bytes) ----------------
#define OFF_WT    0u          // float [3][8][64][64] transposed weights: WT[s][h][c][o] = W_s[h][o][c]
#define OFF_PPK   393216u     // uint  [63][64] packed bf16 pair (P[c][m], P[c][m+64])
#define OFF_U     409600u     // float [N][64]   u (u[.,0]=0)
#define OFF_V     8798208u    // float [R][64]   v rows
#define OFF_PHIQ  75907072u   // bf16  [R][128]
#define OFF_PHIK  143015936u  // bf16  [R][128]
#define OFF_LAST  210124800u  // float [8][128][64]  (zeroed)
#define OFF_TACC  210386944u  // float [N][64]       (zeroed)
#define OFF_EA    218775552u  // float [1]           (zeroed)
#define ZERO_OFF  210124800u
#define ZERO_SZ   8651008u

// ---------------- helpers ----------------
DEV float wave_sum(float v) {
#pragma unroll
  for (int o = 1; o < 64; o <<= 1) v += __shfl_xor(v, o, 64);
  return v;
}
DEV unsigned short f2bf(float f) {
  unsigned u = __float_as_uint(f);
  return (unsigned short)((u + 0x7fffu + ((u >> 16) & 1u)) >> 16);
}
DEV float bf2f(unsigned short h) { return __uint_as_float(((unsigned)h) << 16); }
DEV float rdlane(float v, int c) {
  return __uint_as_float((unsigned)__builtin_amdgcn_readlane((int)__float_as_uint(v), c));
}

// ---------------- K0: prep (transpose W, pack P to bf16 pairs) ----------------
__global__ __launch_bounds__(256) void k0_prep(const float* __restrict__ Wq, const float* __restrict__ Wk,
                                               const float* __restrict__ Wv, const float* __restrict__ P,
                                               float* __restrict__ WT, unsigned* __restrict__ PPK) {
  int tid = blockIdx.x * blockDim.x + threadIdx.x;
  int stride = gridDim.x * blockDim.x;
  for (int i = tid; i < 3 * 8 * 64 * 64; i += stride) {
    int o = i & 63, c = (i >> 6) & 63, h = (i >> 12) & 7, s = i >> 15;
    const float* W = (s == 0) ? Wq : ((s == 1) ? Wk : Wv);
    WT[i] = W[(h * 64 + o) * 64 + c];
  }
  for (int i = tid; i < 63 * 64; i += stride) {
    int m = i & 63, c = i >> 6;
    unsigned lo = f2bf(P[c * 128 + m]);
    unsigned hi = f2bf(P[c * 128 + 64 + m]);
    PPK[i] = lo | (hi << 16);
  }
}

// ---------------- K1: u = logmap0(proj(expmap0(z))) ----------------
__global__ __launch_bounds__(256) void k1_u(const float* __restrict__ z, float* __restrict__ u) {
  int lane = threadIdx.x & 63, w = threadIdx.x >> 6;
  int node = blockIdx.x * 4 + w;
  float x = z[node * 64 + lane];
  float xs = lane ? x : 0.f;
  float s2 = wave_sum(xs * xs);
  float xn = fmaxf(sqrtf(s2), EPSF);
  float sh = sinhf(xn);
  float t0 = sqrtf(1.f + sh * sh);
  float tt = fmaxf(t0, 1.f + EPSF);
  float al = acoshf(tt);
  u[node * 64 + lane] = lane ? (al * x / xn) : 0.f;
}

// ---------------- K2: mu -> (q,k,v rows) -> phi_q, phi_k, V ----------------
// block = 512 thr (8 waves); each wave handles 4 consecutive flat rows at a time.
// 256 rows/block -> grid 1024 (128 blocks per original head; all block rows share head h)
__global__ __launch_bounds__(512) void k2_phi(const float* __restrict__ u, const float* __restrict__ WT,
                                              const unsigned* __restrict__ PPK, float* __restrict__ V,
                                              unsigned short* __restrict__ phiq, unsigned short* __restrict__ phik) {
  __shared__ float wt[3 * 64 * 64];   // 48 KB : wt[s][c][o]
  __shared__ unsigned ppk[63 * 64];   // 15.75 KB
  int tid = threadIdx.x;
  int h = blockIdx.x >> 7;  // 128 blocks per head
  for (int i = tid; i < 3 * 4096; i += 512) {
    int s = i >> 12, co = i & 4095;
    wt[i] = WT[((s * 8 + h) << 12) + co];
  }
  for (int i = tid; i < 63 * 64; i += 512) ppk[i] = PPK[i];
  __syncthreads();

  int lane = tid & 63, w = tid >> 6;
  int rbase0 = blockIdx.x * 256;
  for (int batch = 0; batch < 8; ++batch) {
    int r0 = rbase0 + batch * 32 + w * 4;
    int n0 = r0 & (NNODES - 1);
    float ur[4];
#pragma unroll
    for (int j = 0; j < 4; ++j) ur[j] = u[(n0 + j) * 64 + lane];

    float muq[4] = {0, 0, 0, 0}, muk[4] = {0, 0, 0, 0}, muv[4] = {0, 0, 0, 0};
    for (int c = 1; c < 64; ++c) {
      float wq = wt[c * 64 + lane];
      float wk = wt[4096 + c * 64 + lane];
      float wv = wt[8192 + c * 64 + lane];
#pragma unroll
      for (int j = 0; j < 4; ++j) {
        float a = rdlane(ur[j], c);
        muq[j] = fmaf(a, wq, muq[j]);
        muk[j] = fmaf(a, wk, muk[j]);
        muv[j] = fmaf(a, wv, muv[j]);
      }
    }

    float sq[4], sk[4], frontq[4], frontk[4];
#pragma unroll
    for (int j = 0; j < 4; ++j) {
      // q
      float s2 = wave_sum(lane ? muq[j] * muq[j] : 0.f);
      float xn = fmaxf(sqrtf(s2), EPSF);
      float sh = sinhf(xn);
      float tq = sqrtf(1.f + sh * sh);
      frontq[j] = expf(1.f - tq * tq) * INV_SQRT63;
      sq[j] = muq[j] * (sh / xn);
      // k
      s2 = wave_sum(lane ? muk[j] * muk[j] : 0.f);
      xn = fmaxf(sqrtf(s2), EPSF);
      sh = sinhf(xn);
      float tk = sqrtf(1.f + sh * sh);
      frontk[j] = expf(1.f - tk * tk) * INV_SQRT63;
      sk[j] = muk[j] * (sh / xn);
      // v (store row)
      s2 = wave_sum(lane ? muv[j] * muv[j] : 0.f);
      xn = fmaxf(sqrtf(s2), EPSF);
      sh = sinhf(xn);
      float vt = sqrtf(1.f + sh * sh);
      V[(r0 + j) * 64 + lane] = lane ? (muv[j] * (sh / xn)) : vt;
    }

    float aq0[4] = {0, 0, 0, 0}, aq1[4] = {0, 0, 0, 0};
    float ak0[4] = {0, 0, 0, 0}, ak1[4] = {0, 0, 0, 0};
    for (int c = 1; c < 64; ++c) {
      unsigned p = ppk[(c - 1) * 64 + lane];
      float p0 = __uint_as_float(p << 16);
      float p1 = __uint_as_float(p & 0xffff0000u);
#pragma unroll
      for (int j = 0; j < 4; ++j) {
        float aq = rdlane(sq[j], c);
        float ak = rdlane(sk[j], c);
        aq0[j] = fmaf(aq, p0, aq0[j]);
        aq1[j] = fmaf(aq, p1, aq1[j]);
        ak0[j] = fmaf(ak, p0, ak0[j]);
        ak1[j] = fmaf(ak, p1, ak1[j]);
      }
    }
#pragma unroll
    for (int j = 0; j < 4; ++j) {
      int r = r0 + j;
      phiq[r * 128 + lane]      = f2bf(expf(aq0[j] * SQRT2F) * frontq[j]);
      phiq[r * 128 + 64 + lane] = f2bf(expf(aq1[j] * SQRT2F) * frontq[j]);
      phik[r * 128 + lane]      = f2bf(expf(ak0[j] * SQRT2F) * frontk[j]);
      phik[r * 128 + 64 + lane] = f2bf(expf(ak1[j] * SQRT2F) * frontk[j]);
    }
  }
}

// ---------------- K3: last[h'][m][d] = sum_{r % 8 == h'} phik[r][m] * V[r][d] ----------------
// grid 512 = (h' = b&7, chunk = b>>3 over 64). thread owns 4m x 8d register tile.
__global__ __launch_bounds__(256) void k3_last(const unsigned short* __restrict__ phik, const float* __restrict__ V,
                                               float* __restrict__ last) {
  int b = blockIdx.x;
  int hp = b & 7, chunk = b >> 3;
  int t = threadIdx.x;
  int m0 = (t & 31) * 4, d0 = (t >> 5) * 8;
  float acc[4][8];
#pragma unroll
  for (int i = 0; i < 4; ++i)
#pragma unroll
    for (int j = 0; j < 8; ++j) acc[i][j] = 0.f;
  int n0 = chunk * 512;
  for (int it = 0; it < 512; ++it) {
    int r = (n0 + it) * 8 + hp;
    ushort4 pk4 = *(const ushort4*)(phik + r * 128 + m0);
    float4 va = *(const float4*)(V + r * 64 + d0);
    float4 vb = *(const float4*)(V + r * 64 + d0 + 4);
    float p[4] = {bf2f(pk4.x), bf2f(pk4.y), bf2f(pk4.z), bf2f(pk4.w)};
    float vv[8] = {va.x, va.y, va.z, va.w, vb.x, vb.y, vb.z, vb.w};
#pragma unroll
    for (int i = 0; i < 4; ++i)
#pragma unroll
      for (int j = 0; j < 8; ++j) acc[i][j] = fmaf(p[i], vv[j], acc[i][j]);
  }
#pragma unroll
  for (int i = 0; i < 4; ++i)
#pragma unroll
    for (int j = 0; j < 8; ++j) atomicAdd(&last[(hp * 128 + m0 + i) * 64 + d0 + j], acc[i][j]);
}

// ---------------- K4: zo rows, per-row Minkowski normalize, atomic-accumulate t ----------------
// grid 512 = (h' = b&7, chunk = b>>3). last[h'] staged in LDS (32 KB). wave handles 2 rows/iter.
__global__ __launch_bounds__(256) void k4_zo(const unsigned short* __restrict__ phiq, const float* __restrict__ last,
                                             float* __restrict__ tacc) {
  __shared__ float lst[8192];
  int b = blockIdx.x;
  int hp = b & 7, chunk = b >> 3;
  for (int i = threadIdx.x; i < 8192; i += 256) lst[i] = last[hp * 8192 + i];
  __syncthreads();
  int lane = threadIdx.x & 63, w = threadIdx.x >> 6;
  int base = chunk * 512 + w * 2;
  for (int it = 0; it < 64; ++it) {
    int np = base + it * 8;
    int r0 = np * 8 + hp;
    int r1 = (np + 1) * 8 + hp;
    float acc0 = 0.f, acc1 = 0.f;
    for (int mq = 0; mq < 128; mq += 4) {
      ushort4 p0 = *(const ushort4*)(phiq + r0 * 128 + mq);  // wave-uniform addr (broadcast)
      ushort4 p1 = *(const ushort4*)(phiq + r1 * 128 + mq);
      float l0 = lst[(mq + 0) * 64 + lane];
      float l1 = lst[(mq + 1) * 64 + lane];
      float l2 = lst[(mq + 2) * 64 + lane];
      float l3 = lst[(mq + 3) * 64 + lane];
      acc0 = fmaf(bf2f(p0.x), l0, acc0); acc0 = fmaf(bf2f(p0.y), l1, acc0);
      acc0 = fmaf(bf2f(p0.z), l2, acc0); acc0 = fmaf(bf2f(p0.w), l3, acc0);
      acc1 = fmaf(bf2f(p1.x), l0, acc1); acc1 = fmaf(bf2f(p1.y), l1, acc1);
      acc1 = fmaf(bf2f(p1.z), l2, acc1); acc1 = fmaf(bf2f(p1.w), l3, acc1);
    }
    float m0 = wave_sum(lane ? acc0 * acc0 : -acc0 * acc0);
    float m1 = wave_sum(lane ? acc1 * acc1 : -acc1 * acc1);
    atomicAdd(&tacc[np * 64 + lane], acc0 / sqrtf(fabsf(m0)));
    atomicAdd(&tacc[(np + 1) * 64 + lane], acc1 / sqrtf(fabsf(m1)));
  }
}

// ---------------- K5: link loss: sum over edges of <Qblock[end], Kblock[start]>_F ----------------
__global__ __launch_bounds__(256) void k5_ea(const unsigned short* __restrict__ phiq,
                                             const unsigned short* __restrict__ phik,
                                             const int* __restrict__ ei, float* __restrict__ ea) {
  __shared__ float part[4];
  int lane = threadIdx.x & 63, w = threadIdx.x >> 6;
  int wid = blockIdx.x * 4 + w;
  float acc = 0.f;
  for (int i = 0; i < 64; ++i) {
    int e = wid * 64 + i;
    int s = ei[e];            // start -> K block
    int d = ei[NEDGES + e];   // end   -> Q block
    const unsigned short* bq = phiq + (size_t)d * 1024;
    const unsigned short* bk = phik + (size_t)s * 1024;
    uint4 qa = *(const uint4*)(bq + lane * 16);
    uint4 qb = *(const uint4*)(bq + lane * 16 + 8);
    uint4 ka = *(const uint4*)(bk + lane * 16);
    uint4 kb = *(const uint4*)(bk + lane * 16 + 8);
    unsigned qs[8] = {qa.x, qa.y, qa.z, qa.w, qb.x, qb.y, qb.z, qb.w};
    unsigned ks[8] = {ka.x, ka.y, ka.z, ka.w, kb.x, kb.y, kb.z, kb.w};
#pragma unroll
    for (int p = 0; p < 8; ++p) {
      float q0 = __uint_as_float(qs[p] << 16);
      float q1 = __uint_as_float(qs[p] & 0xffff0000u);
      float k0 = __uint_as_float(ks[p] << 16);
      float k1 = __uint_as_float(ks[p] & 0xffff0000u);
      acc = fmaf(q0, k0, acc);
      acc = fmaf(q1, k1, acc);
    }
  }
  acc = wave_sum(acc);
  if (lane == 0) part[w] = acc;
  __syncthreads();
  if (threadIdx.x == 0) atomicAdd(ea, part[0] + part[1] + part[2] + part[3]);
}

// ---------------- K6: finalize z_next + link_loss ----------------
__global__ __launch_bounds__(256) void k6_out(const float* __restrict__ tacc, const float* __restrict__ ea,
                                              float* __restrict__ out) {
  int lane = threadIdx.x & 63, w = threadIdx.x >> 6;
  int node = blockIdx.x * 4 + w;
  float t = tacc[node * 64 + lane] * 0.125f;
  float m2 = wave_sum(lane ? t * t : -t * t);
  out[node * 64 + lane] = t / sqrtf(fabsf(m2));
  if (blockIdx.x == 0 && threadIdx.x == 0) out[NNODES * 64] = ea[0] * (1.0f / (8.0f * (float)NEDGES));
}

// ---------------- launch ----------------
extern "C" void kernel_launch(void* const* d_in, const int* in_sizes, int n_in,
                              void* d_out, int out_size, void* d_ws, size_t ws_size,
                              hipStream_t stream) {
  const float* z  = (const float*)d_in[0];
  const float* Wq = (const float*)d_in[1];
  const float* Wk = (const float*)d_in[2];
  const float* Wv = (const float*)d_in[3];
  const float* P  = (const float*)d_in[4];
  const int* ei   = (const int*)d_in[5];
  char* ws = (char*)d_ws;
  float*          WT   = (float*)(ws + OFF_WT);
  unsigned*       PPK  = (unsigned*)(ws + OFF_PPK);
  float*          u    = (float*)(ws + OFF_U);
  float*          V    = (float*)(ws + OFF_V);
  unsigned short* phiq = (unsigned short*)(ws + OFF_PHIQ);
  unsigned short* phik = (unsigned short*)(ws + OFF_PHIK);
  float*          last = (float*)(ws + OFF_LAST);
  float*          tacc = (float*)(ws + OFF_TACC);
  float*          ea   = (float*)(ws + OFF_EA);

  hipMemsetAsync(ws + ZERO_OFF, 0, ZERO_SZ, stream);
  k0_prep<<<96, 256, 0, stream>>>(Wq, Wk, Wv, P, WT, PPK);
  k1_u<<<NNODES / 4, 256, 0, stream>>>(z, u);
  k2_phi<<<NROWS / 256, 512, 0, stream>>>(u, WT, PPK, V, phiq, phik);
  k3_last<<<512, 256, 0, stream>>>(phik, V, last);
  k4_zo<<<512, 256, 0, stream>>>(phiq, last, tacc);
  k5_ea<<<NEDGES / 256, 256, 0, stream>>>(phiq, phik, ei, ea);
  k6_out<<<NNODES / 4, 256, 0, stream>>>(tacc, ea, (float*)d_out);
}

// Round 2
// 695.180 us; speedup vs baseline: 1.6023x; 1.6023x over previous
//
#include <hip/hip_runtime.h>

#define DEV __device__ __forceinline__

// ---------------- constants ----------------
// N_NODES=32768, N_EDGES=65536, H=8, D=64, DS=63, M=128, R=H*N=262144
#define NNODES 32768
#define NEDGES 65536
#define NROWS  262144
#define EPSF   1e-7f
#define INV_SQRT63 0.1259881576697424f
#define SQRT2F 1.4142135623730951f

// ---------------- ws layout (bytes) ----------------
#define OFF_WFRAG 0u          // bf16 [3][8][2][4][64][8]  W in MFMA B-fragment order (196608 B)
#define OFF_PFRAG 196608u     // bf16 [2][8][64][8]        sqrt(2)*P padded, B-fragment order (16384 B)
#define OFF_U     409600u     // float [N][64]   u (u[.,0]=0)
#define OFF_V     8798208u    // float [R][64]   v rows
#define OFF_PHIQ  75907072u   // bf16  [R][128]
#define OFF_PHIK  143015936u  // bf16  [R][128]
#define OFF_LAST  210124800u  // float [8][128][64]  (zeroed)
#define OFF_TACC  210386944u  // float [N][64]       (zeroed)
#define OFF_EA    218775552u  // float [1]           (zeroed)
#define ZERO_OFF  210124800u
#define ZERO_SZ   8651008u

typedef short s8v __attribute__((ext_vector_type(8)));   // 8 bf16 in 4 VGPRs (MFMA A/B frag)
typedef float f4v __attribute__((ext_vector_type(4)));   // MFMA C/D frag

// ---------------- helpers ----------------
DEV float wave_sum(float v) {
#pragma unroll
  for (int o = 1; o < 64; o <<= 1) v += __shfl_xor(v, o, 64);
  return v;
}
DEV unsigned short f2bf(float f) {
  unsigned u = __float_as_uint(f);
  return (unsigned short)((u + 0x7fffu + ((u >> 16) & 1u)) >> 16);
}
DEV float bf2f(unsigned short h) { return __uint_as_float(((unsigned)h) << 16); }

// ---------------- K0: pack W and sqrt(2)*P into MFMA B-fragment order (bf16) ----------------
// B-frag layout for v_mfma_f32_16x16x32_bf16: lane holds B[k][n], n = lane&15, k = (lane>>4)*8 + j.
__global__ __launch_bounds__(256) void k0_prep(const float* __restrict__ Wq, const float* __restrict__ Wk,
                                               const float* __restrict__ Wv, const float* __restrict__ P,
                                               unsigned short* __restrict__ Wfrag, unsigned short* __restrict__ Pfrag) {
  int tid = blockIdx.x * blockDim.x + threadIdx.x;
  int stride = gridDim.x * blockDim.x;
  // Wfrag[sm][h][ks][nt][lane][j]  (3*8*2*4*64*8 = 98304)
  for (int i = tid; i < 98304; i += stride) {
    int j = i & 7, lane = (i >> 3) & 63, nt = (i >> 9) & 3, ks = (i >> 11) & 1, h = (i >> 12) & 7, sm = i >> 15;
    int k = ks * 32 + (lane >> 4) * 8 + j;   // input channel c
    int n = nt * 16 + (lane & 15);           // output channel o
    const float* W = (sm == 0) ? Wq : ((sm == 1) ? Wk : Wv);
    Wfrag[i] = f2bf(W[(h * 64 + n) * 64 + k]);
  }
  // Pfrag[ks][nt][lane][j]  (2*8*64*8 = 8192); k=0 row is zero pad (comp 0 excluded)
  for (int i = tid; i < 8192; i += stride) {
    int j = i & 7, lane = (i >> 3) & 63, nt = (i >> 9) & 7, ks = (i >> 12) & 1;
    int k = ks * 32 + (lane >> 4) * 8 + j;
    int m = nt * 16 + (lane & 15);
    Pfrag[i] = (k == 0) ? (unsigned short)0 : f2bf(P[(k - 1) * 128 + m] * SQRT2F);
  }
}

// ---------------- K1: u = logmap0(proj(expmap0(z))) ----------------
__global__ __launch_bounds__(256) void k1_u(const float* __restrict__ z, float* __restrict__ u) {
  int lane = threadIdx.x & 63, w = threadIdx.x >> 6;
  int node = blockIdx.x * 4 + w;
  float x = z[node * 64 + lane];
  float xs = lane ? x : 0.f;
  float s2 = wave_sum(xs * xs);
  float xn = fmaxf(sqrtf(s2), EPSF);
  float sh = sinhf(xn);
  float t0 = sqrtf(1.f + sh * sh);
  float tt = fmaxf(t0, 1.f + EPSF);
  float al = acoshf(tt);
  u[node * 64 + lane] = lane ? (al * x / xn) : 0.f;
}

// ---------------- K2: MFMA version of mu -> (q,k,v) -> phi_q, phi_k, V ----------------
// Block = 256 thr (4 waves). Wave owns 32 consecutive rows (2 MFMA m-tiles) of one head.
// Grid 2048: head h = b>>8, tile t = b&255, nodes n0 = t*128 + wave*32, flat rows r0 = h*32768+n0.
// Phase 1: mu = u @ W_h^T per mat (MFMA), quarter-wave row-norm, sinh; V -> global,
//          s_{q,k} -> per-wave LDS (bf16, stride 72). Phase 2: wx = s @ (sqrt2*P) (MFMA),
//          phi = bf16(exp(wx)*front) -> global.
__global__ __launch_bounds__(256) void k2_mfma(const float* __restrict__ u, const unsigned short* __restrict__ Wfrag,
                                               const unsigned short* __restrict__ Pfrag, float* __restrict__ V,
                                               unsigned short* __restrict__ phiq, unsigned short* __restrict__ phik) {
  __shared__ short sbuf[2][4][32 * 72];  // [mat q/k][wave][row*72 + col], 36864 B
  int w = threadIdx.x >> 6, lane = threadIdx.x & 63;
  int q = lane >> 4, l = lane & 15;
  int b = blockIdx.x;
  int h = b >> 8, t = b & 255;
  int n0 = t * 128 + w * 32;
  int r0 = h * 32768 + n0;

  // A-fragments of u (rows n0..n0+31), bf16: a[mt][ks], A[m=l][k=ks*32+q*8+j]
  s8v afr[2][2];
#pragma unroll
  for (int mt = 0; mt < 2; ++mt)
#pragma unroll
    for (int ks = 0; ks < 2; ++ks) {
      const float* up = u + (size_t)(n0 + mt * 16 + l) * 64 + ks * 32 + q * 8;
      float4 x0 = *(const float4*)up;
      float4 x1 = *(const float4*)(up + 4);
      s8v a;
      a[0] = (short)f2bf(x0.x); a[1] = (short)f2bf(x0.y); a[2] = (short)f2bf(x0.z); a[3] = (short)f2bf(x0.w);
      a[4] = (short)f2bf(x1.x); a[5] = (short)f2bf(x1.y); a[6] = (short)f2bf(x1.z); a[7] = (short)f2bf(x1.w);
      afr[mt][ks] = a;
    }

  const s8v* Wf = (const s8v*)Wfrag;
  const s8v* Pf = (const s8v*)Pfrag;
  float front[2][2][4];  // [mat q/k][mt][reg]

#pragma unroll
  for (int sm = 0; sm < 3; ++sm) {
    f4v acc[2][4];
#pragma unroll
    for (int mt = 0; mt < 2; ++mt)
#pragma unroll
      for (int nt = 0; nt < 4; ++nt) acc[mt][nt] = (f4v)(0.f);
#pragma unroll
    for (int ks = 0; ks < 2; ++ks)
#pragma unroll
      for (int nt = 0; nt < 4; ++nt) {
        s8v bf = Wf[(((sm * 8 + h) * 2 + ks) * 4 + nt) * 64 + lane];
#pragma unroll
        for (int mt = 0; mt < 2; ++mt)
          acc[mt][nt] = __builtin_amdgcn_mfma_f32_16x16x32_bf16(afr[mt][ks], bf, acc[mt][nt], 0, 0, 0);
      }
    // row-wise: C layout col = nt*16 + l, row = mt*16 + q*4 + reg (row lives in one 16-lane quarter)
#pragma unroll
    for (int mt = 0; mt < 2; ++mt) {
      float rs[4];
#pragma unroll
      for (int reg = 0; reg < 4; ++reg) {
        float v0 = (l == 0) ? 0.f : acc[mt][0][reg];  // exclude comp 0 from spatial norm
        rs[reg] = v0 * v0 + acc[mt][1][reg] * acc[mt][1][reg] + acc[mt][2][reg] * acc[mt][2][reg] +
                  acc[mt][3][reg] * acc[mt][3][reg];
      }
#pragma unroll
      for (int reg = 0; reg < 4; ++reg) {
#pragma unroll
        for (int off = 1; off < 16; off <<= 1) rs[reg] += __shfl_xor(rs[reg], off, 64);
      }
#pragma unroll
      for (int reg = 0; reg < 4; ++reg) {
        float xn = fmaxf(sqrtf(rs[reg]), EPSF);
        float sh = sinhf(xn);
        float ratio = sh / xn;
        float tt = sqrtf(1.f + sh * sh);
        if (sm == 2) {
#pragma unroll
          for (int nt = 0; nt < 4; ++nt) {
            float val = acc[mt][nt][reg] * ratio;
            if (l == 0 && nt == 0) val = tt;  // time component
            V[(size_t)(r0 + mt * 16 + q * 4 + reg) * 64 + nt * 16 + l] = val;
          }
        } else {
          front[sm][mt][reg] = expf(1.f - tt * tt) * INV_SQRT63;
#pragma unroll
          for (int nt = 0; nt < 4; ++nt) {
            float val = acc[mt][nt][reg] * ratio;
            if (l == 0 && nt == 0) val = 0.f;  // comp 0 excluded from phi GEMM
            sbuf[sm][w][(mt * 16 + q * 4 + reg) * 72 + nt * 16 + l] = (short)f2bf(val);
          }
        }
      }
    }
  }

  // Phase 2: phi GEMMs (per-wave LDS, no barrier needed)
#pragma unroll
  for (int sm = 0; sm < 2; ++sm) {
    s8v af[2][2];
#pragma unroll
    for (int mt = 0; mt < 2; ++mt)
#pragma unroll
      for (int ks = 0; ks < 2; ++ks)
        af[mt][ks] = *(const s8v*)&sbuf[sm][w][(mt * 16 + l) * 72 + ks * 32 + q * 8];
    f4v acc2[2][8];
#pragma unroll
    for (int mt = 0; mt < 2; ++mt)
#pragma unroll
      for (int nt = 0; nt < 8; ++nt) acc2[mt][nt] = (f4v)(0.f);
#pragma unroll
    for (int ks = 0; ks < 2; ++ks)
#pragma unroll
      for (int nt = 0; nt < 8; ++nt) {
        s8v bf = Pf[(ks * 8 + nt) * 64 + lane];
#pragma unroll
        for (int mt = 0; mt < 2; ++mt)
          acc2[mt][nt] = __builtin_amdgcn_mfma_f32_16x16x32_bf16(af[mt][ks], bf, acc2[mt][nt], 0, 0, 0);
      }
    unsigned short* dst = sm ? phik : phiq;
#pragma unroll
    for (int mt = 0; mt < 2; ++mt)
#pragma unroll
      for (int nt = 0; nt < 8; ++nt)
#pragma unroll
        for (int reg = 0; reg < 4; ++reg) {
          float val = expf(acc2[mt][nt][reg]) * front[sm][mt][reg];
          dst[(size_t)(r0 + mt * 16 + q * 4 + reg) * 128 + nt * 16 + l] = f2bf(val);
        }
  }
}

// ---------------- K3: last[h'][m][d] = sum_{r % 8 == h'} phik[r][m] * V[r][d] ----------------
__global__ __launch_bounds__(256) void k3_last(const unsigned short* __restrict__ phik, const float* __restrict__ V,
                                               float* __restrict__ last) {
  int b = blockIdx.x;
  int hp = b & 7, chunk = b >> 3;
  int t = threadIdx.x;
  int m0 = (t & 31) * 4, d0 = (t >> 5) * 8;
  float acc[4][8];
#pragma unroll
  for (int i = 0; i < 4; ++i)
#pragma unroll
    for (int j = 0; j < 8; ++j) acc[i][j] = 0.f;
  int n0 = chunk * 512;
  for (int it = 0; it < 512; ++it) {
    int r = (n0 + it) * 8 + hp;
    ushort4 pk4 = *(const ushort4*)(phik + r * 128 + m0);
    float4 va = *(const float4*)(V + r * 64 + d0);
    float4 vb = *(const float4*)(V + r * 64 + d0 + 4);
    float p[4] = {bf2f(pk4.x), bf2f(pk4.y), bf2f(pk4.z), bf2f(pk4.w)};
    float vv[8] = {va.x, va.y, va.z, va.w, vb.x, vb.y, vb.z, vb.w};
#pragma unroll
    for (int i = 0; i < 4; ++i)
#pragma unroll
      for (int j = 0; j < 8; ++j) acc[i][j] = fmaf(p[i], vv[j], acc[i][j]);
  }
#pragma unroll
  for (int i = 0; i < 4; ++i)
#pragma unroll
    for (int j = 0; j < 8; ++j) atomicAdd(&last[(hp * 128 + m0 + i) * 64 + d0 + j], acc[i][j]);
}

// ---------------- K4: zo rows, per-row Minkowski normalize, atomic-accumulate t ----------------
__global__ __launch_bounds__(256) void k4_zo(const unsigned short* __restrict__ phiq, const float* __restrict__ last,
                                             float* __restrict__ tacc) {
  __shared__ float lst[8192];
  int b = blockIdx.x;
  int hp = b & 7, chunk = b >> 3;
  for (int i = threadIdx.x; i < 8192; i += 256) lst[i] = last[hp * 8192 + i];
  __syncthreads();
  int lane = threadIdx.x & 63, w = threadIdx.x >> 6;
  int base = chunk * 512 + w * 2;
  for (int it = 0; it < 64; ++it) {
    int np = base + it * 8;
    int r0 = np * 8 + hp;
    int r1 = (np + 1) * 8 + hp;
    float acc0 = 0.f, acc1 = 0.f;
    for (int mq = 0; mq < 128; mq += 4) {
      ushort4 p0 = *(const ushort4*)(phiq + r0 * 128 + mq);
      ushort4 p1 = *(const ushort4*)(phiq + r1 * 128 + mq);
      float l0 = lst[(mq + 0) * 64 + lane];
      float l1 = lst[(mq + 1) * 64 + lane];
      float l2 = lst[(mq + 2) * 64 + lane];
      float l3 = lst[(mq + 3) * 64 + lane];
      acc0 = fmaf(bf2f(p0.x), l0, acc0); acc0 = fmaf(bf2f(p0.y), l1, acc0);
      acc0 = fmaf(bf2f(p0.z), l2, acc0); acc0 = fmaf(bf2f(p0.w), l3, acc0);
      acc1 = fmaf(bf2f(p1.x), l0, acc1); acc1 = fmaf(bf2f(p1.y), l1, acc1);
      acc1 = fmaf(bf2f(p1.z), l2, acc1); acc1 = fmaf(bf2f(p1.w), l3, acc1);
    }
    float m0 = wave_sum(lane ? acc0 * acc0 : -acc0 * acc0);
    float m1 = wave_sum(lane ? acc1 * acc1 : -acc1 * acc1);
    atomicAdd(&tacc[np * 64 + lane], acc0 / sqrtf(fabsf(m0)));
    atomicAdd(&tacc[(np + 1) * 64 + lane], acc1 / sqrtf(fabsf(m1)));
  }
}

// ---------------- K5: link loss: sum over edges of <Qblock[end], Kblock[start]>_F ----------------
__global__ __launch_bounds__(256) void k5_ea(const unsigned short* __restrict__ phiq,
                                             const unsigned short* __restrict__ phik,
                                             const int* __restrict__ ei, float* __restrict__ ea) {
  __shared__ float part[4];
  int lane = threadIdx.x & 63, w = threadIdx.x >> 6;
  int wid = blockIdx.x * 4 + w;
  float acc = 0.f;
  for (int i = 0; i < 64; ++i) {
    int e = wid * 64 + i;
    int s = ei[e];
    int d = ei[NEDGES + e];
    const unsigned short* bq = phiq + (size_t)d * 1024;
    const unsigned short* bk = phik + (size_t)s * 1024;
    uint4 qa = *(const uint4*)(bq + lane * 16);
    uint4 qb = *(const uint4*)(bq + lane * 16 + 8);
    uint4 ka = *(const uint4*)(bk + lane * 16);
    uint4 kb = *(const uint4*)(bk + lane * 16 + 8);
    unsigned qs[8] = {qa.x, qa.y, qa.z, qa.w, qb.x, qb.y, qb.z, qb.w};
    unsigned ks[8] = {ka.x, ka.y, ka.z, ka.w, kb.x, kb.y, kb.z, kb.w};
#pragma unroll
    for (int p = 0; p < 8; ++p) {
      float q0 = __uint_as_float(qs[p] << 16);
      float q1 = __uint_as_float(qs[p] & 0xffff0000u);
      float k0 = __uint_as_float(ks[p] << 16);
      float k1 = __uint_as_float(ks[p] & 0xffff0000u);
      acc = fmaf(q0, k0, acc);
      acc = fmaf(q1, k1, acc);
    }
  }
  acc = wave_sum(acc);
  if (lane == 0) part[w] = acc;
  __syncthreads();
  if (threadIdx.x == 0) atomicAdd(ea, part[0] + part[1] + part[2] + part[3]);
}

// ---------------- K6: finalize z_next + link_loss ----------------
__global__ __launch_bounds__(256) void k6_out(const float* __restrict__ tacc, const float* __restrict__ ea,
                                              float* __restrict__ out) {
  int lane = threadIdx.x & 63, w = threadIdx.x >> 6;
  int node = blockIdx.x * 4 + w;
  float t = tacc[node * 64 + lane] * 0.125f;
  float m2 = wave_sum(lane ? t * t : -t * t);
  out[node * 64 + lane] = t / sqrtf(fabsf(m2));
  if (blockIdx.x == 0 && threadIdx.x == 0) out[NNODES * 64] = ea[0] * (1.0f / (8.0f * (float)NEDGES));
}

// ---------------- launch ----------------
extern "C" void kernel_launch(void* const* d_in, const int* in_sizes, int n_in,
                              void* d_out, int out_size, void* d_ws, size_t ws_size,
                              hipStream_t stream) {
  const float* z  = (const float*)d_in[0];
  const float* Wq = (const float*)d_in[1];
  const float* Wk = (const float*)d_in[2];
  const float* Wv = (const float*)d_in[3];
  const float* P  = (const float*)d_in[4];
  const int* ei   = (const int*)d_in[5];
  char* ws = (char*)d_ws;
  unsigned short* Wfrag = (unsigned short*)(ws + OFF_WFRAG);
  unsigned short* Pfrag = (unsigned short*)(ws + OFF_PFRAG);
  float*          u     = (float*)(ws + OFF_U);
  float*          V     = (float*)(ws + OFF_V);
  unsigned short* phiq  = (unsigned short*)(ws + OFF_PHIQ);
  unsigned short* phik  = (unsigned short*)(ws + OFF_PHIK);
  float*          last  = (float*)(ws + OFF_LAST);
  float*          tacc  = (float*)(ws + OFF_TACC);
  float*          ea    = (float*)(ws + OFF_EA);

  hipMemsetAsync(ws + ZERO_OFF, 0, ZERO_SZ, stream);
  k0_prep<<<96, 256, 0, stream>>>(Wq, Wk, Wv, P, Wfrag, Pfrag);
  k1_u<<<NNODES / 4, 256, 0, stream>>>(z, u);
  k2_mfma<<<2048, 256, 0, stream>>>(u, Wfrag, Pfrag, V, phiq, phik);
  k3_last<<<512, 256, 0, stream>>>(phik, V, last);
  k4_zo<<<512, 256, 0, stream>>>(phiq, last, tacc);
  k5_ea<<<NEDGES / 256, 256, 0, stream>>>(phiq, phik, ei, ea);
  k6_out<<<NNODES / 4, 256, 0, stream>>>(tacc, ea, (float*)d_out);
}

// Round 3
// 497.942 us; speedup vs baseline: 2.2370x; 1.3961x over previous
//
#include <hip/hip_runtime.h>

#define DEV __device__ __forceinline__

// ---------------- constants ----------------
// N_NODES=32768, N_EDGES=65536, H=8, D=64, DS=63, M=128, R=H*N=262144
#define NNODES 32768
#define NEDGES 65536
#define NROWS  262144
#define EPSF   1e-7f
#define INV_SQRT63 0.1259881576697424f
#define SQRT2F 1.4142135623730951f

// ---------------- ws layout (bytes) ----------------
#define OFF_WFRAG 0u          // bf16 [3][8][2][4][64][8]  W in MFMA B-fragment order (196608 B)
#define OFF_PFRAG 196608u     // bf16 [2][8][64][8]        sqrt(2)*P padded, B-fragment order (16384 B)
#define OFF_U     409600u     // float [N][64] u ; REUSED after k2 as lastB (bf16 B-frag of last, 131072 B)
#define OFF_LASTB 409600u
#define OFF_V     8798208u    // float [R][64]   v rows
#define OFF_PHIQ  75907072u   // bf16  [R][128]
#define OFF_PHIK  143015936u  // bf16  [R][128]
#define OFF_LAST  210124800u  // float [8][128][64]  (zeroed, 262144 B)
#define OFF_EA    218775552u  // float [1]           (zeroed)

typedef short s8v __attribute__((ext_vector_type(8)));   // 8 bf16 in 4 VGPRs (MFMA A/B frag)
typedef float f4v __attribute__((ext_vector_type(4)));   // MFMA C/D frag

// ---------------- helpers ----------------
DEV float wave_sum(float v) {
#pragma unroll
  for (int o = 1; o < 64; o <<= 1) v += __shfl_xor(v, o, 64);
  return v;
}
DEV unsigned short f2bf(float f) {
  unsigned u = __float_as_uint(f);
  return (unsigned short)((u + 0x7fffu + ((u >> 16) & 1u)) >> 16);
}
DEV float bf2f(unsigned short h) { return __uint_as_float(((unsigned)h) << 16); }

// ---------------- K0: pack W and sqrt(2)*P into MFMA B-fragment order (bf16) ----------------
__global__ __launch_bounds__(256) void k0_prep(const float* __restrict__ Wq, const float* __restrict__ Wk,
                                               const float* __restrict__ Wv, const float* __restrict__ P,
                                               unsigned short* __restrict__ Wfrag, unsigned short* __restrict__ Pfrag) {
  int tid = blockIdx.x * blockDim.x + threadIdx.x;
  int stride = gridDim.x * blockDim.x;
  for (int i = tid; i < 98304; i += stride) {
    int j = i & 7, lane = (i >> 3) & 63, nt = (i >> 9) & 3, ks = (i >> 11) & 1, h = (i >> 12) & 7, sm = i >> 15;
    int k = ks * 32 + (lane >> 4) * 8 + j;
    int n = nt * 16 + (lane & 15);
    const float* W = (sm == 0) ? Wq : ((sm == 1) ? Wk : Wv);
    Wfrag[i] = f2bf(W[(h * 64 + n) * 64 + k]);
  }
  for (int i = tid; i < 8192; i += stride) {
    int j = i & 7, lane = (i >> 3) & 63, nt = (i >> 9) & 7, ks = (i >> 12) & 1;
    int k = ks * 32 + (lane >> 4) * 8 + j;
    int m = nt * 16 + (lane & 15);
    Pfrag[i] = (k == 0) ? (unsigned short)0 : f2bf(P[(k - 1) * 128 + m] * SQRT2F);
  }
}

// ---------------- K1: u = logmap0(proj(expmap0(z))) ----------------
__global__ __launch_bounds__(256) void k1_u(const float* __restrict__ z, float* __restrict__ u) {
  int lane = threadIdx.x & 63, w = threadIdx.x >> 6;
  int node = blockIdx.x * 4 + w;
  float x = z[node * 64 + lane];
  float xs = lane ? x : 0.f;
  float s2 = wave_sum(xs * xs);
  float xn = fmaxf(sqrtf(s2), EPSF);
  float sh = sinhf(xn);
  float t0 = sqrtf(1.f + sh * sh);
  float tt = fmaxf(t0, 1.f + EPSF);
  float al = acoshf(tt);
  u[node * 64 + lane] = lane ? (al * x / xn) : 0.f;
}

// ---------------- K2: MFMA mu -> (q,k,v) -> phi_q, phi_k, V ----------------
__global__ __launch_bounds__(256) void k2_mfma(const float* __restrict__ u, const unsigned short* __restrict__ Wfrag,
                                               const unsigned short* __restrict__ Pfrag, float* __restrict__ V,
                                               unsigned short* __restrict__ phiq, unsigned short* __restrict__ phik) {
  __shared__ short sbuf[2][4][32 * 72];
  int w = threadIdx.x >> 6, lane = threadIdx.x & 63;
  int q = lane >> 4, l = lane & 15;
  int b = blockIdx.x;
  int h = b >> 8, t = b & 255;
  int n0 = t * 128 + w * 32;
  int r0 = h * 32768 + n0;

  s8v afr[2][2];
#pragma unroll
  for (int mt = 0; mt < 2; ++mt)
#pragma unroll
    for (int ks = 0; ks < 2; ++ks) {
      const float* up = u + (size_t)(n0 + mt * 16 + l) * 64 + ks * 32 + q * 8;
      float4 x0 = *(const float4*)up;
      float4 x1 = *(const float4*)(up + 4);
      s8v a;
      a[0] = (short)f2bf(x0.x); a[1] = (short)f2bf(x0.y); a[2] = (short)f2bf(x0.z); a[3] = (short)f2bf(x0.w);
      a[4] = (short)f2bf(x1.x); a[5] = (short)f2bf(x1.y); a[6] = (short)f2bf(x1.z); a[7] = (short)f2bf(x1.w);
      afr[mt][ks] = a;
    }

  const s8v* Wf = (const s8v*)Wfrag;
  const s8v* Pf = (const s8v*)Pfrag;
  float front[2][2][4];

#pragma unroll
  for (int sm = 0; sm < 3; ++sm) {
    f4v acc[2][4];
#pragma unroll
    for (int mt = 0; mt < 2; ++mt)
#pragma unroll
      for (int nt = 0; nt < 4; ++nt) acc[mt][nt] = (f4v)(0.f);
#pragma unroll
    for (int ks = 0; ks < 2; ++ks)
#pragma unroll
      for (int nt = 0; nt < 4; ++nt) {
        s8v bf = Wf[(((sm * 8 + h) * 2 + ks) * 4 + nt) * 64 + lane];
#pragma unroll
        for (int mt = 0; mt < 2; ++mt)
          acc[mt][nt] = __builtin_amdgcn_mfma_f32_16x16x32_bf16(afr[mt][ks], bf, acc[mt][nt], 0, 0, 0);
      }
#pragma unroll
    for (int mt = 0; mt < 2; ++mt) {
      float rs[4];
#pragma unroll
      for (int reg = 0; reg < 4; ++reg) {
        float v0 = (l == 0) ? 0.f : acc[mt][0][reg];
        rs[reg] = v0 * v0 + acc[mt][1][reg] * acc[mt][1][reg] + acc[mt][2][reg] * acc[mt][2][reg] +
                  acc[mt][3][reg] * acc[mt][3][reg];
      }
#pragma unroll
      for (int reg = 0; reg < 4; ++reg) {
#pragma unroll
        for (int off = 1; off < 16; off <<= 1) rs[reg] += __shfl_xor(rs[reg], off, 64);
      }
#pragma unroll
      for (int reg = 0; reg < 4; ++reg) {
        float xn = fmaxf(sqrtf(rs[reg]), EPSF);
        float sh = sinhf(xn);
        float ratio = sh / xn;
        float tt = sqrtf(1.f + sh * sh);
        if (sm == 2) {
#pragma unroll
          for (int nt = 0; nt < 4; ++nt) {
            float val = acc[mt][nt][reg] * ratio;
            if (l == 0 && nt == 0) val = tt;
            V[(size_t)(r0 + mt * 16 + q * 4 + reg) * 64 + nt * 16 + l] = val;
          }
        } else {
          front[sm][mt][reg] = expf(1.f - tt * tt) * INV_SQRT63;
#pragma unroll
          for (int nt = 0; nt < 4; ++nt) {
            float val = acc[mt][nt][reg] * ratio;
            if (l == 0 && nt == 0) val = 0.f;
            sbuf[sm][w][(mt * 16 + q * 4 + reg) * 72 + nt * 16 + l] = (short)f2bf(val);
          }
        }
      }
    }
  }

#pragma unroll
  for (int sm = 0; sm < 2; ++sm) {
    s8v af[2][2];
#pragma unroll
    for (int mt = 0; mt < 2; ++mt)
#pragma unroll
      for (int ks = 0; ks < 2; ++ks)
        af[mt][ks] = *(const s8v*)&sbuf[sm][w][(mt * 16 + l) * 72 + ks * 32 + q * 8];
    f4v acc2[2][8];
#pragma unroll
    for (int mt = 0; mt < 2; ++mt)
#pragma unroll
      for (int nt = 0; nt < 8; ++nt) acc2[mt][nt] = (f4v)(0.f);
#pragma unroll
    for (int ks = 0; ks < 2; ++ks)
#pragma unroll
      for (int nt = 0; nt < 8; ++nt) {
        s8v bf = Pf[(ks * 8 + nt) * 64 + lane];
#pragma unroll
        for (int mt = 0; mt < 2; ++mt)
          acc2[mt][nt] = __builtin_amdgcn_mfma_f32_16x16x32_bf16(af[mt][ks], bf, acc2[mt][nt], 0, 0, 0);
      }
    unsigned short* dst = sm ? phik : phiq;
#pragma unroll
    for (int mt = 0; mt < 2; ++mt)
#pragma unroll
      for (int nt = 0; nt < 8; ++nt)
#pragma unroll
        for (int reg = 0; reg < 4; ++reg) {
          float val = expf(acc2[mt][nt][reg]) * front[sm][mt][reg];
          dst[(size_t)(r0 + mt * 16 + q * 4 + reg) * 128 + nt * 16 + l] = f2bf(val);
        }
  }
}

// ---------------- K3: last[h'][m][d] = sum_{r % 8 == h'} phik[r][m] * V[r][d] ----------------
__global__ __launch_bounds__(256) void k3_last(const unsigned short* __restrict__ phik, const float* __restrict__ V,
                                               float* __restrict__ last) {
  int b = blockIdx.x;
  int hp = b & 7, chunk = b >> 3;
  int t = threadIdx.x;
  int m0 = (t & 31) * 4, d0 = (t >> 5) * 8;
  float acc[4][8];
#pragma unroll
  for (int i = 0; i < 4; ++i)
#pragma unroll
    for (int j = 0; j < 8; ++j) acc[i][j] = 0.f;
  int n0 = chunk * 512;
  for (int it = 0; it < 512; ++it) {
    int r = (n0 + it) * 8 + hp;
    ushort4 pk4 = *(const ushort4*)(phik + r * 128 + m0);
    float4 va = *(const float4*)(V + r * 64 + d0);
    float4 vb = *(const float4*)(V + r * 64 + d0 + 4);
    float p[4] = {bf2f(pk4.x), bf2f(pk4.y), bf2f(pk4.z), bf2f(pk4.w)};
    float vv[8] = {va.x, va.y, va.z, va.w, vb.x, vb.y, vb.z, vb.w};
#pragma unroll
    for (int i = 0; i < 4; ++i)
#pragma unroll
      for (int j = 0; j < 8; ++j) acc[i][j] = fmaf(p[i], vv[j], acc[i][j]);
  }
#pragma unroll
  for (int i = 0; i < 4; ++i)
#pragma unroll
    for (int j = 0; j < 8; ++j) atomicAdd(&last[(hp * 128 + m0 + i) * 64 + d0 + j], acc[i][j]);
}

// ---------------- K3p: pack last (f32) -> B-fragment bf16: lastB[h'][ks4][nt4][lane][j] ----------------
__global__ __launch_bounds__(256) void k3p_pack(const float* __restrict__ last, unsigned short* __restrict__ lastB) {
  int i = blockIdx.x * 256 + threadIdx.x;  // 65536 total
  int j = i & 7, lane = (i >> 3) & 63, nt = (i >> 9) & 3, ks = (i >> 11) & 3, h = (i >> 13) & 7;
  int k = ks * 32 + (lane >> 4) * 8 + j;   // RF index m
  int n = nt * 16 + (lane & 15);           // d
  lastB[i] = f2bf(last[(h * 128 + k) * 64 + n]);
}

// ---------------- K4: MFMA zo = phiq @ last[h'] ; row-norm; 8-head mean; final normalize ----------------
// Block = 512 thr (8 waves); wave w handles h'=w for 32 nodes (rows 8n+w). Grid = NNODES/32 = 1024.
__global__ __launch_bounds__(512) void k4_mfma(const unsigned short* __restrict__ phiq,
                                               const unsigned short* __restrict__ lastB,
                                               const float* __restrict__ ea, float* __restrict__ out) {
  __shared__ float zbuf[8][32][64];  // 64 KB
  int w = threadIdx.x >> 6, lane = threadIdx.x & 63;
  int q = lane >> 4, l = lane & 15;
  int n0 = blockIdx.x * 32;

  const s8v* Bf = (const s8v*)lastB;
  s8v bf[4][4];
#pragma unroll
  for (int ks = 0; ks < 4; ++ks)
#pragma unroll
    for (int nt = 0; nt < 4; ++nt) bf[ks][nt] = Bf[((w * 4 + ks) * 4 + nt) * 64 + lane];

  s8v af[2][4];
#pragma unroll
  for (int mt = 0; mt < 2; ++mt)
#pragma unroll
    for (int ks = 0; ks < 4; ++ks)
      af[mt][ks] = *(const s8v*)(phiq + (size_t)(8 * (n0 + mt * 16 + l) + w) * 128 + ks * 32 + q * 8);

  f4v acc[2][4];
#pragma unroll
  for (int mt = 0; mt < 2; ++mt)
#pragma unroll
    for (int nt = 0; nt < 4; ++nt) acc[mt][nt] = (f4v)(0.f);
#pragma unroll
  for (int ks = 0; ks < 4; ++ks)
#pragma unroll
    for (int nt = 0; nt < 4; ++nt)
#pragma unroll
      for (int mt = 0; mt < 2; ++mt)
        acc[mt][nt] = __builtin_amdgcn_mfma_f32_16x16x32_bf16(af[mt][ks], bf[ks][nt], acc[mt][nt], 0, 0, 0);

  // per-row Minkowski normalize (row = mt*16 + q*4 + reg, col = nt*16 + l), write zbuf[w]
#pragma unroll
  for (int mt = 0; mt < 2; ++mt) {
    float rs[4];
#pragma unroll
    for (int reg = 0; reg < 4; ++reg) {
      float v0 = acc[mt][0][reg];
      float s0 = (l == 0) ? -v0 * v0 : v0 * v0;
      rs[reg] = s0 + acc[mt][1][reg] * acc[mt][1][reg] + acc[mt][2][reg] * acc[mt][2][reg] +
                acc[mt][3][reg] * acc[mt][3][reg];
    }
#pragma unroll
    for (int reg = 0; reg < 4; ++reg) {
#pragma unroll
      for (int off = 1; off < 16; off <<= 1) rs[reg] += __shfl_xor(rs[reg], off, 64);
    }
#pragma unroll
    for (int reg = 0; reg < 4; ++reg) {
      float inv = 1.f / sqrtf(fabsf(rs[reg]));
      int i = mt * 16 + q * 4 + reg;
#pragma unroll
      for (int nt = 0; nt < 4; ++nt) zbuf[w][i][nt * 16 + l] = acc[mt][nt][reg] * inv;
    }
  }
  __syncthreads();

  // mean over 8 heads + final Minkowski normalize + store z_next
  int tid = threadIdx.x;
  int i = tid >> 4, c0 = (tid & 15) * 4;
  float4 s = make_float4(0.f, 0.f, 0.f, 0.f);
#pragma unroll
  for (int w2 = 0; w2 < 8; ++w2) {
    float4 v = *(const float4*)&zbuf[w2][i][c0];
    s.x += v.x; s.y += v.y; s.z += v.z; s.w += v.w;
  }
  s.x *= 0.125f; s.y *= 0.125f; s.z *= 0.125f; s.w *= 0.125f;
  float m2 = ((c0 == 0) ? -s.x * s.x : s.x * s.x) + s.y * s.y + s.z * s.z + s.w * s.w;
#pragma unroll
  for (int off = 1; off < 16; off <<= 1) m2 += __shfl_xor(m2, off, 64);
  float inv = 1.f / sqrtf(fabsf(m2));
  float4 o = make_float4(s.x * inv, s.y * inv, s.z * inv, s.w * inv);
  *(float4*)(out + (size_t)(n0 + i) * 64 + c0) = o;
  if (blockIdx.x == 0 && tid == 0) out[(size_t)NNODES * 64] = ea[0] * (1.0f / 524288.0f);
}

// ---------------- K5: link loss ----------------
__global__ __launch_bounds__(256) void k5_ea(const unsigned short* __restrict__ phiq,
                                             const unsigned short* __restrict__ phik,
                                             const int* __restrict__ ei, float* __restrict__ ea) {
  __shared__ float part[4];
  int lane = threadIdx.x & 63, w = threadIdx.x >> 6;
  int wid = blockIdx.x * 4 + w;
  float acc = 0.f;
  for (int i = 0; i < 64; ++i) {
    int e = wid * 64 + i;
    int s = ei[e];
    int d = ei[NEDGES + e];
    const unsigned short* bq = phiq + (size_t)d * 1024;
    const unsigned short* bk = phik + (size_t)s * 1024;
    uint4 qa = *(const uint4*)(bq + lane * 16);
    uint4 qb = *(const uint4*)(bq + lane * 16 + 8);
    uint4 ka = *(const uint4*)(bk + lane * 16);
    uint4 kb = *(const uint4*)(bk + lane * 16 + 8);
    unsigned qs[8] = {qa.x, qa.y, qa.z, qa.w, qb.x, qb.y, qb.z, qb.w};
    unsigned ks[8] = {ka.x, ka.y, ka.z, ka.w, kb.x, kb.y, kb.z, kb.w};
#pragma unroll
    for (int p = 0; p < 8; ++p) {
      float q0 = __uint_as_float(qs[p] << 16);
      float q1 = __uint_as_float(qs[p] & 0xffff0000u);
      float k0 = __uint_as_float(ks[p] << 16);
      float k1 = __uint_as_float(ks[p] & 0xffff0000u);
      acc = fmaf(q0, k0, acc);
      acc = fmaf(q1, k1, acc);
    }
  }
  acc = wave_sum(acc);
  if (lane == 0) part[w] = acc;
  __syncthreads();
  if (threadIdx.x == 0) atomicAdd(ea, part[0] + part[1] + part[2] + part[3]);
}

// ---------------- launch ----------------
extern "C" void kernel_launch(void* const* d_in, const int* in_sizes, int n_in,
                              void* d_out, int out_size, void* d_ws, size_t ws_size,
                              hipStream_t stream) {
  const float* z  = (const float*)d_in[0];
  const float* Wq = (const float*)d_in[1];
  const float* Wk = (const float*)d_in[2];
  const float* Wv = (const float*)d_in[3];
  const float* P  = (const float*)d_in[4];
  const int* ei   = (const int*)d_in[5];
  char* ws = (char*)d_ws;
  unsigned short* Wfrag = (unsigned short*)(ws + OFF_WFRAG);
  unsigned short* Pfrag = (unsigned short*)(ws + OFF_PFRAG);
  float*          u     = (float*)(ws + OFF_U);
  unsigned short* lastB = (unsigned short*)(ws + OFF_LASTB);  // reuses u region after k2
  float*          V     = (float*)(ws + OFF_V);
  unsigned short* phiq  = (unsigned short*)(ws + OFF_PHIQ);
  unsigned short* phik  = (unsigned short*)(ws + OFF_PHIK);
  float*          last  = (float*)(ws + OFF_LAST);
  float*          ea    = (float*)(ws + OFF_EA);

  hipMemsetAsync(last, 0, 262144, stream);
  hipMemsetAsync(ea, 0, 4, stream);
  k0_prep<<<96, 256, 0, stream>>>(Wq, Wk, Wv, P, Wfrag, Pfrag);
  k1_u<<<NNODES / 4, 256, 0, stream>>>(z, u);
  k2_mfma<<<2048, 256, 0, stream>>>(u, Wfrag, Pfrag, V, phiq, phik);
  k3_last<<<512, 256, 0, stream>>>(phik, V, last);
  k3p_pack<<<256, 256, 0, stream>>>(last, lastB);
  k5_ea<<<NEDGES / 256, 256, 0, stream>>>(phiq, phik, ei, ea);
  k4_mfma<<<NNODES / 32, 512, 0, stream>>>(phiq, lastB, ea, (float*)d_out);
}

// Round 4
// 289.181 us; speedup vs baseline: 3.8520x; 1.7219x over previous
//
#include <hip/hip_runtime.h>

#define DEV __device__ __forceinline__

// ---------------- constants ----------------
// N_NODES=32768, N_EDGES=65536, H=8, D=64, DS=63, M=128, R=H*N=262144
#define NNODES 32768
#define NEDGES 65536
#define NROWS  262144
#define EPSF   1e-7f
#define INV_SQRT63 0.1259881576697424f
#define SQRT2F 1.4142135623730951f

// ---------------- ws layout (bytes) ----------------
// Sequenced reuse: Wfrag (k0->k2) then lastB (k3p->k4) share offset 0.
#define OFF_WFRAG 0u          // bf16 [3][8][2][4][64][8]  W in MFMA B-frag order (196608 B) [dead after k2]
#define OFF_LASTB 0u          // bf16 [8][4][4][64][8] B-frag of last (131072 B) [written k3p, read k4]
#define OFF_PFRAG 196608u     // bf16 [2][8][64][8]  sqrt(2)*P padded, B-frag order (16384 B)
#define OFF_EA    212992u     // float [1] (zeroed)
#define OFF_U     409600u     // float [N][64] u (8388608 B) [dead after k2]
#define OFF_VT    8798208u    // bf16 [8][64][32768]  v^T per head, node-contiguous (33554432 B)
#define OFF_PART  42352640u   // float [128][8][128][64] split-K partials of last (33554432 B)
#define OFF_PHIQ  75907072u   // bf16 [R][128]
#define OFF_PHIK  143015936u  // bf16 [R][128]
// end: 210124800

typedef short s8v __attribute__((ext_vector_type(8)));   // 8 bf16 in 4 VGPRs (MFMA A/B frag)
typedef float f4v __attribute__((ext_vector_type(4)));   // MFMA C/D frag

// ---------------- helpers ----------------
DEV float wave_sum(float v) {
#pragma unroll
  for (int o = 1; o < 64; o <<= 1) v += __shfl_xor(v, o, 64);
  return v;
}
DEV unsigned short f2bf(float f) {
  unsigned u = __float_as_uint(f);
  return (unsigned short)((u + 0x7fffu + ((u >> 16) & 1u)) >> 16);
}
DEV float bf2f(unsigned short h) { return __uint_as_float(((unsigned)h) << 16); }

// ---------------- K0: pack W and sqrt(2)*P into MFMA B-fragment order (bf16) ----------------
__global__ __launch_bounds__(256) void k0_prep(const float* __restrict__ Wq, const float* __restrict__ Wk,
                                               const float* __restrict__ Wv, const float* __restrict__ P,
                                               unsigned short* __restrict__ Wfrag, unsigned short* __restrict__ Pfrag) {
  int tid = blockIdx.x * blockDim.x + threadIdx.x;
  int stride = gridDim.x * blockDim.x;
  for (int i = tid; i < 98304; i += stride) {
    int j = i & 7, lane = (i >> 3) & 63, nt = (i >> 9) & 3, ks = (i >> 11) & 1, h = (i >> 12) & 7, sm = i >> 15;
    int k = ks * 32 + (lane >> 4) * 8 + j;
    int n = nt * 16 + (lane & 15);
    const float* W = (sm == 0) ? Wq : ((sm == 1) ? Wk : Wv);
    Wfrag[i] = f2bf(W[(h * 64 + n) * 64 + k]);
  }
  for (int i = tid; i < 8192; i += stride) {
    int j = i & 7, lane = (i >> 3) & 63, nt = (i >> 9) & 7, ks = (i >> 12) & 1;
    int k = ks * 32 + (lane >> 4) * 8 + j;
    int m = nt * 16 + (lane & 15);
    Pfrag[i] = (k == 0) ? (unsigned short)0 : f2bf(P[(k - 1) * 128 + m] * SQRT2F);
  }
}

// ---------------- K1: u = logmap0(proj(expmap0(z))) ----------------
__global__ __launch_bounds__(256) void k1_u(const float* __restrict__ z, float* __restrict__ u) {
  int lane = threadIdx.x & 63, w = threadIdx.x >> 6;
  int node = blockIdx.x * 4 + w;
  float x = z[node * 64 + lane];
  float xs = lane ? x : 0.f;
  float s2 = wave_sum(xs * xs);
  float xn = fmaxf(sqrtf(s2), EPSF);
  float sh = sinhf(xn);
  float t0 = sqrtf(1.f + sh * sh);
  float tt = fmaxf(t0, 1.f + EPSF);
  float al = acoshf(tt);
  u[node * 64 + lane] = lane ? (al * x / xn) : 0.f;
}

// ---------------- K2: MFMA mu -> (q,k,v) -> phi_q, phi_k, VT(bf16) ----------------
__global__ __launch_bounds__(256) void k2_mfma(const float* __restrict__ u, const unsigned short* __restrict__ Wfrag,
                                               const unsigned short* __restrict__ Pfrag,
                                               unsigned short* __restrict__ VT,
                                               unsigned short* __restrict__ phiq, unsigned short* __restrict__ phik) {
  __shared__ short sbuf[2][4][32 * 72];
  int w = threadIdx.x >> 6, lane = threadIdx.x & 63;
  int q = lane >> 4, l = lane & 15;
  int b = blockIdx.x;
  int h = b >> 8, t = b & 255;
  int n0 = t * 128 + w * 32;
  int r0 = h * 32768 + n0;

  s8v afr[2][2];
#pragma unroll
  for (int mt = 0; mt < 2; ++mt)
#pragma unroll
    for (int ks = 0; ks < 2; ++ks) {
      const float* up = u + (size_t)(n0 + mt * 16 + l) * 64 + ks * 32 + q * 8;
      float4 x0 = *(const float4*)up;
      float4 x1 = *(const float4*)(up + 4);
      s8v a;
      a[0] = (short)f2bf(x0.x); a[1] = (short)f2bf(x0.y); a[2] = (short)f2bf(x0.z); a[3] = (short)f2bf(x0.w);
      a[4] = (short)f2bf(x1.x); a[5] = (short)f2bf(x1.y); a[6] = (short)f2bf(x1.z); a[7] = (short)f2bf(x1.w);
      afr[mt][ks] = a;
    }

  const s8v* Wf = (const s8v*)Wfrag;
  const s8v* Pf = (const s8v*)Pfrag;
  float front[2][2][4];

#pragma unroll
  for (int sm = 0; sm < 3; ++sm) {
    f4v acc[2][4];
#pragma unroll
    for (int mt = 0; mt < 2; ++mt)
#pragma unroll
      for (int nt = 0; nt < 4; ++nt) acc[mt][nt] = (f4v)(0.f);
#pragma unroll
    for (int ks = 0; ks < 2; ++ks)
#pragma unroll
      for (int nt = 0; nt < 4; ++nt) {
        s8v bf = Wf[(((sm * 8 + h) * 2 + ks) * 4 + nt) * 64 + lane];
#pragma unroll
        for (int mt = 0; mt < 2; ++mt)
          acc[mt][nt] = __builtin_amdgcn_mfma_f32_16x16x32_bf16(afr[mt][ks], bf, acc[mt][nt], 0, 0, 0);
      }
#pragma unroll
    for (int mt = 0; mt < 2; ++mt) {
      float rs[4];
      float vbuf[4][4];  // [nt][reg] (sm==2 only)
#pragma unroll
      for (int reg = 0; reg < 4; ++reg) {
        float v0 = (l == 0) ? 0.f : acc[mt][0][reg];
        rs[reg] = v0 * v0 + acc[mt][1][reg] * acc[mt][1][reg] + acc[mt][2][reg] * acc[mt][2][reg] +
                  acc[mt][3][reg] * acc[mt][3][reg];
      }
#pragma unroll
      for (int reg = 0; reg < 4; ++reg) {
#pragma unroll
        for (int off = 1; off < 16; off <<= 1) rs[reg] += __shfl_xor(rs[reg], off, 64);
      }
#pragma unroll
      for (int reg = 0; reg < 4; ++reg) {
        float xn = fmaxf(sqrtf(rs[reg]), EPSF);
        float sh = sinhf(xn);
        float ratio = sh / xn;
        float tt = sqrtf(1.f + sh * sh);
        if (sm == 2) {
#pragma unroll
          for (int nt = 0; nt < 4; ++nt) {
            float val = acc[mt][nt][reg] * ratio;
            if (l == 0 && nt == 0) val = tt;
            vbuf[nt][reg] = val;
          }
        } else {
          front[sm][mt][reg] = expf(1.f - tt * tt) * INV_SQRT63;
#pragma unroll
          for (int nt = 0; nt < 4; ++nt) {
            float val = acc[mt][nt][reg] * ratio;
            if (l == 0 && nt == 0) val = 0.f;
            sbuf[sm][w][(mt * 16 + q * 4 + reg) * 72 + nt * 16 + l] = (short)f2bf(val);
          }
        }
      }
      if (sm == 2) {
        // VT[h][d][n]: d = nt*16+l, nodes n0+mt*16+q*4 .. +4 (reg-contiguous) -> 8B store
#pragma unroll
        for (int nt = 0; nt < 4; ++nt) {
          ushort4 pk;
          pk.x = f2bf(vbuf[nt][0]); pk.y = f2bf(vbuf[nt][1]);
          pk.z = f2bf(vbuf[nt][2]); pk.w = f2bf(vbuf[nt][3]);
          *(ushort4*)(VT + (((size_t)(h * 64 + nt * 16 + l)) << 15) + n0 + mt * 16 + q * 4) = pk;
        }
      }
    }
  }

#pragma unroll
  for (int sm = 0; sm < 2; ++sm) {
    s8v af[2][2];
#pragma unroll
    for (int mt = 0; mt < 2; ++mt)
#pragma unroll
      for (int ks = 0; ks < 2; ++ks)
        af[mt][ks] = *(const s8v*)&sbuf[sm][w][(mt * 16 + l) * 72 + ks * 32 + q * 8];
    f4v acc2[2][8];
#pragma unroll
    for (int mt = 0; mt < 2; ++mt)
#pragma unroll
      for (int nt = 0; nt < 8; ++nt) acc2[mt][nt] = (f4v)(0.f);
#pragma unroll
    for (int ks = 0; ks < 2; ++ks)
#pragma unroll
      for (int nt = 0; nt < 8; ++nt) {
        s8v bf = Pf[(ks * 8 + nt) * 64 + lane];
#pragma unroll
        for (int mt = 0; mt < 2; ++mt)
          acc2[mt][nt] = __builtin_amdgcn_mfma_f32_16x16x32_bf16(af[mt][ks], bf, acc2[mt][nt], 0, 0, 0);
      }
    unsigned short* dst = sm ? phik : phiq;
#pragma unroll
    for (int mt = 0; mt < 2; ++mt)
#pragma unroll
      for (int nt = 0; nt < 8; ++nt)
#pragma unroll
        for (int reg = 0; reg < 4; ++reg) {
          float val = expf(acc2[mt][nt][reg]) * front[sm][mt][reg];
          dst[(size_t)(r0 + mt * 16 + q * 4 + reg) * 128 + nt * 16 + l] = f2bf(val);
        }
  }
}

// ---------------- K3: MFMA split-K  part[c][h] += phik_h^T @ V_h  (per-chunk, no atomics) ----------------
// Grid 1024 = 8 heads x 128 chunks (256 nodes each). Block 256 thr / 4 waves; wave = 2 m-tiles.
// A[m][k] = phik[8*(nb+k)+h][m]  (8x2B gather/lane, L1-resident working set)
// B[k][n] = VT[h][n][nb+k]       (natural 16B loads)
__global__ __launch_bounds__(256) void k3_mfma(const unsigned short* __restrict__ phik,
                                               const unsigned short* __restrict__ VT,
                                               float* __restrict__ part) {
  int b = blockIdx.x;
  int h = b >> 7, c = b & 127;
  int w = threadIdx.x >> 6, lane = threadIdx.x & 63;
  int q = lane >> 4, l = lane & 15;
  int n0 = c * 256;

  f4v acc[2][4];
#pragma unroll
  for (int mtl = 0; mtl < 2; ++mtl)
#pragma unroll
    for (int nt = 0; nt < 4; ++nt) acc[mtl][nt] = (f4v)(0.f);

  const unsigned short* ap = phik + (size_t)(8 * (n0 + q * 8) + h) * 128 + l;

  for (int ks = 0; ks < 8; ++ks) {
    int nb = n0 + ks * 32;
    s8v bfr[4];
#pragma unroll
    for (int nt = 0; nt < 4; ++nt)
      bfr[nt] = *(const s8v*)(VT + (((size_t)(h * 64 + nt * 16 + l)) << 15) + nb + q * 8);
    s8v afr[2];
#pragma unroll
    for (int mtl = 0; mtl < 2; ++mtl) {
      int moff = (w * 2 + mtl) * 16;
      s8v a;
#pragma unroll
      for (int j = 0; j < 8; ++j) a[j] = (short)ap[(size_t)(ks * 32 + j) * 1024 + moff];
      afr[mtl] = a;
    }
#pragma unroll
    for (int mtl = 0; mtl < 2; ++mtl)
#pragma unroll
      for (int nt = 0; nt < 4; ++nt)
        acc[mtl][nt] = __builtin_amdgcn_mfma_f32_16x16x32_bf16(afr[mtl], bfr[nt], acc[mtl][nt], 0, 0, 0);
  }

  float* dst = part + (((size_t)(c * 8 + h)) << 13);
#pragma unroll
  for (int mtl = 0; mtl < 2; ++mtl)
#pragma unroll
    for (int nt = 0; nt < 4; ++nt)
#pragma unroll
      for (int reg = 0; reg < 4; ++reg)
        dst[((w * 2 + mtl) * 16 + q * 4 + reg) * 64 + nt * 16 + l] = acc[mtl][nt][reg];
}

// ---------------- K3p: reduce 128 split-K partials -> lastB (bf16 B-frag order) ----------------
__global__ __launch_bounds__(256) void k3p_pack(const float* __restrict__ part, unsigned short* __restrict__ lastB) {
  int t = blockIdx.x * 256 + threadIdx.x;  // 65536 = h*8192 + k*64 + n
  float s = 0.f;
#pragma unroll 8
  for (int c = 0; c < 128; ++c) s += part[((size_t)c << 16) + t];
  int n = t & 63, k = (t >> 6) & 127, h = t >> 13;
  int ks = k >> 5, j = k & 7, qq = (k >> 3) & 3;
  int lane = qq * 16 + (n & 15), nt = n >> 4;
  lastB[((((h * 4 + ks) * 4 + nt) * 64 + lane) << 3) + j] = f2bf(s);
}

// ---------------- K4: MFMA zo = phiq @ last[h'] ; row-norm; 8-head mean; final normalize ----------------
__global__ __launch_bounds__(512) void k4_mfma(const unsigned short* __restrict__ phiq,
                                               const unsigned short* __restrict__ lastB,
                                               const float* __restrict__ ea, float* __restrict__ out) {
  __shared__ float zbuf[8][32][64];
  int w = threadIdx.x >> 6, lane = threadIdx.x & 63;
  int q = lane >> 4, l = lane & 15;
  int n0 = blockIdx.x * 32;

  const s8v* Bf = (const s8v*)lastB;
  s8v bf[4][4];
#pragma unroll
  for (int ks = 0; ks < 4; ++ks)
#pragma unroll
    for (int nt = 0; nt < 4; ++nt) bf[ks][nt] = Bf[((w * 4 + ks) * 4 + nt) * 64 + lane];

  s8v af[2][4];
#pragma unroll
  for (int mt = 0; mt < 2; ++mt)
#pragma unroll
    for (int ks = 0; ks < 4; ++ks)
      af[mt][ks] = *(const s8v*)(phiq + (size_t)(8 * (n0 + mt * 16 + l) + w) * 128 + ks * 32 + q * 8);

  f4v acc[2][4];
#pragma unroll
  for (int mt = 0; mt < 2; ++mt)
#pragma unroll
    for (int nt = 0; nt < 4; ++nt) acc[mt][nt] = (f4v)(0.f);
#pragma unroll
  for (int ks = 0; ks < 4; ++ks)
#pragma unroll
    for (int nt = 0; nt < 4; ++nt)
#pragma unroll
      for (int mt = 0; mt < 2; ++mt)
        acc[mt][nt] = __builtin_amdgcn_mfma_f32_16x16x32_bf16(af[mt][ks], bf[ks][nt], acc[mt][nt], 0, 0, 0);

#pragma unroll
  for (int mt = 0; mt < 2; ++mt) {
    float rs[4];
#pragma unroll
    for (int reg = 0; reg < 4; ++reg) {
      float v0 = acc[mt][0][reg];
      float s0 = (l == 0) ? -v0 * v0 : v0 * v0;
      rs[reg] = s0 + acc[mt][1][reg] * acc[mt][1][reg] + acc[mt][2][reg] * acc[mt][2][reg] +
                acc[mt][3][reg] * acc[mt][3][reg];
    }
#pragma unroll
    for (int reg = 0; reg < 4; ++reg) {
#pragma unroll
      for (int off = 1; off < 16; off <<= 1) rs[reg] += __shfl_xor(rs[reg], off, 64);
    }
#pragma unroll
    for (int reg = 0; reg < 4; ++reg) {
      float inv = 1.f / sqrtf(fabsf(rs[reg]));
      int i = mt * 16 + q * 4 + reg;
#pragma unroll
      for (int nt = 0; nt < 4; ++nt) zbuf[w][i][nt * 16 + l] = acc[mt][nt][reg] * inv;
    }
  }
  __syncthreads();

  int tid = threadIdx.x;
  int i = tid >> 4, c0 = (tid & 15) * 4;
  float4 s = make_float4(0.f, 0.f, 0.f, 0.f);
#pragma unroll
  for (int w2 = 0; w2 < 8; ++w2) {
    float4 v = *(const float4*)&zbuf[w2][i][c0];
    s.x += v.x; s.y += v.y; s.z += v.z; s.w += v.w;
  }
  s.x *= 0.125f; s.y *= 0.125f; s.z *= 0.125f; s.w *= 0.125f;
  float m2 = ((c0 == 0) ? -s.x * s.x : s.x * s.x) + s.y * s.y + s.z * s.z + s.w * s.w;
#pragma unroll
  for (int off = 1; off < 16; off <<= 1) m2 += __shfl_xor(m2, off, 64);
  float inv = 1.f / sqrtf(fabsf(m2));
  float4 o = make_float4(s.x * inv, s.y * inv, s.z * inv, s.w * inv);
  *(float4*)(out + (size_t)(n0 + i) * 64 + c0) = o;
  if (blockIdx.x == 0 && tid == 0) out[(size_t)NNODES * 64] = ea[0] * (1.0f / 524288.0f);
}

// ---------------- K5: link loss ----------------
__global__ __launch_bounds__(256) void k5_ea(const unsigned short* __restrict__ phiq,
                                             const unsigned short* __restrict__ phik,
                                             const int* __restrict__ ei, float* __restrict__ ea) {
  __shared__ float part[4];
  int lane = threadIdx.x & 63, w = threadIdx.x >> 6;
  int wid = blockIdx.x * 4 + w;
  float acc = 0.f;
  for (int i = 0; i < 64; ++i) {
    int e = wid * 64 + i;
    int s = ei[e];
    int d = ei[NEDGES + e];
    const unsigned short* bq = phiq + (size_t)d * 1024;
    const unsigned short* bk = phik + (size_t)s * 1024;
    uint4 qa = *(const uint4*)(bq + lane * 16);
    uint4 qb = *(const uint4*)(bq + lane * 16 + 8);
    uint4 ka = *(const uint4*)(bk + lane * 16);
    uint4 kb = *(const uint4*)(bk + lane * 16 + 8);
    unsigned qs[8] = {qa.x, qa.y, qa.z, qa.w, qb.x, qb.y, qb.z, qb.w};
    unsigned ks[8] = {ka.x, ka.y, ka.z, ka.w, kb.x, kb.y, kb.z, kb.w};
#pragma unroll
    for (int p = 0; p < 8; ++p) {
      float q0 = __uint_as_float(qs[p] << 16);
      float q1 = __uint_as_float(qs[p] & 0xffff0000u);
      float k0 = __uint_as_float(ks[p] << 16);
      float k1 = __uint_as_float(ks[p] & 0xffff0000u);
      acc = fmaf(q0, k0, acc);
      acc = fmaf(q1, k1, acc);
    }
  }
  acc = wave_sum(acc);
  if (lane == 0) part[w] = acc;
  __syncthreads();
  if (threadIdx.x == 0) atomicAdd(ea, part[0] + part[1] + part[2] + part[3]);
}

// ---------------- launch ----------------
extern "C" void kernel_launch(void* const* d_in, const int* in_sizes, int n_in,
                              void* d_out, int out_size, void* d_ws, size_t ws_size,
                              hipStream_t stream) {
  const float* z  = (const float*)d_in[0];
  const float* Wq = (const float*)d_in[1];
  const float* Wk = (const float*)d_in[2];
  const float* Wv = (const float*)d_in[3];
  const float* P  = (const float*)d_in[4];
  const int* ei   = (const int*)d_in[5];
  char* ws = (char*)d_ws;
  unsigned short* Wfrag = (unsigned short*)(ws + OFF_WFRAG);
  unsigned short* lastB = (unsigned short*)(ws + OFF_LASTB);  // sequenced reuse of Wfrag region
  unsigned short* Pfrag = (unsigned short*)(ws + OFF_PFRAG);
  float*          ea    = (float*)(ws + OFF_EA);
  float*          u     = (float*)(ws + OFF_U);
  unsigned short* VT    = (unsigned short*)(ws + OFF_VT);
  float*          part  = (float*)(ws + OFF_PART);
  unsigned short* phiq  = (unsigned short*)(ws + OFF_PHIQ);
  unsigned short* phik  = (unsigned short*)(ws + OFF_PHIK);

  hipMemsetAsync(ea, 0, 4, stream);
  k0_prep<<<96, 256, 0, stream>>>(Wq, Wk, Wv, P, Wfrag, Pfrag);
  k1_u<<<NNODES / 4, 256, 0, stream>>>(z, u);
  k2_mfma<<<2048, 256, 0, stream>>>(u, Wfrag, Pfrag, VT, phiq, phik);
  k3_mfma<<<1024, 256, 0, stream>>>(phik, VT, part);
  k3p_pack<<<256, 256, 0, stream>>>(part, lastB);
  k5_ea<<<NEDGES / 256, 256, 0, stream>>>(phiq, phik, ei, ea);
  k4_mfma<<<NNODES / 32, 512, 0, stream>>>(phiq, lastB, ea, (float*)d_out);
}

// Round 5
// 259.855 us; speedup vs baseline: 4.2867x; 1.1129x over previous
//
#include <hip/hip_runtime.h>

#define DEV __device__ __forceinline__

// ---------------- constants ----------------
// N_NODES=32768, N_EDGES=65536, H=8, D=64, DS=63, M=128, R=H*N=262144
#define NNODES 32768
#define NEDGES 65536
#define NROWS  262144
#define EPSF   1e-7f
#define SQRT2F 1.4142135623730951f
#define LOG2E  1.4426950408889634f
#define LOG2SQRT63 2.9886399611087573f   // log2(sqrt(63))

// ---------------- ws layout (bytes) ----------------
// Sequenced reuse: Wfrag (k0->k2) then lastB (k3p->k4) share offset 0.
#define OFF_WFRAG 0u          // bf16 [3][8][2][4][64][8]  W in MFMA B-frag order (196608 B) [dead after k2]
#define OFF_LASTB 0u          // bf16 [8][4][4][64][8] B-frag of last (131072 B) [written k3p, read k4]
#define OFF_PFRAG 196608u     // bf16 [8][2][64][8]  sqrt(2)*log2e*P, MFMA A-frag order (16384 B)
#define OFF_EA    212992u     // float [1] (zeroed)
#define OFF_U     409600u     // bf16 [N][64] u (4194304 B) [dead after k2]
#define OFF_VT    8798208u    // bf16 [8][64][32768]  v^T per head, node-contiguous (33554432 B)
#define OFF_PART  42352640u   // float [128][8][128][64] split-K partials of last (33554432 B)
#define OFF_PHIQ  75907072u   // bf16 [R][128]
#define OFF_PHIK  143015936u  // bf16 [R][128]
// end: 210124800

typedef short s8v __attribute__((ext_vector_type(8)));   // 8 bf16 in 4 VGPRs (MFMA A/B frag)
typedef float f4v __attribute__((ext_vector_type(4)));   // MFMA C/D frag

// ---------------- helpers ----------------
DEV float wave_sum(float v) {
#pragma unroll
  for (int o = 1; o < 64; o <<= 1) v += __shfl_xor(v, o, 64);
  return v;
}
DEV unsigned short f2bf(float f) {  // rne
  unsigned u = __float_as_uint(f);
  return (unsigned short)((u + 0x7fffu + ((u >> 16) & 1u)) >> 16);
}
DEV float bf2f(unsigned short h) { return __uint_as_float(((unsigned)h) << 16); }
// pack two f32 -> two bf16 (round-half-up) in one uint: low short = bf16(lo), high = bf16(hi)
DEV unsigned pack2(float lo, float hi) {
  return __builtin_amdgcn_perm(__float_as_uint(hi) + 0x8000u, __float_as_uint(lo) + 0x8000u, 0x07060302u);
}
DEV float frcp(float x) { return __builtin_amdgcn_rcpf(x); }

// ---------------- K0: pack W (B-frag) and sqrt(2)*log2e*P (A-frag) as bf16 ----------------
__global__ __launch_bounds__(256) void k0_prep(const float* __restrict__ Wq, const float* __restrict__ Wk,
                                               const float* __restrict__ Wv, const float* __restrict__ P,
                                               unsigned short* __restrict__ Wfrag, unsigned short* __restrict__ Pfrag) {
  int tid = blockIdx.x * blockDim.x + threadIdx.x;
  int stride = gridDim.x * blockDim.x;
  // Wfrag[sm][h][ks][nt][lane][j] : B[k][n], n = nt*16+(lane&15), k = ks*32+(lane>>4)*8+j
  for (int i = tid; i < 98304; i += stride) {
    int j = i & 7, lane = (i >> 3) & 63, nt = (i >> 9) & 3, ks = (i >> 11) & 1, h = (i >> 12) & 7, sm = i >> 15;
    int k = ks * 32 + (lane >> 4) * 8 + j;
    int n = nt * 16 + (lane & 15);
    const float* W = (sm == 0) ? Wq : ((sm == 1) ? Wk : Wv);
    Wfrag[i] = f2bf(W[(h * 64 + n) * 64 + k]);
  }
  // Pfrag[mt8][ks2][lane][j] : A[m][k], m = mt*16+(lane&15), k = ks*32+(lane>>4)*8+j ; k=0 zero pad
  for (int i = tid; i < 8192; i += stride) {
    int j = i & 7, lane = (i >> 3) & 63, ks = (i >> 9) & 1, mt = (i >> 10) & 7;
    int k = ks * 32 + (lane >> 4) * 8 + j;
    int m = mt * 16 + (lane & 15);
    Pfrag[i] = (k == 0) ? (unsigned short)0 : f2bf(P[(k - 1) * 128 + m] * (SQRT2F * LOG2E));
  }
}

// ---------------- K1: u = logmap0(proj(expmap0(z))) -> bf16 ----------------
__global__ __launch_bounds__(256) void k1_u(const float* __restrict__ z, unsigned short* __restrict__ ubf) {
  int lane = threadIdx.x & 63, w = threadIdx.x >> 6;
  int node = blockIdx.x * 4 + w;
  float x = z[node * 64 + lane];
  float xs = lane ? x : 0.f;
  float s2 = wave_sum(xs * xs);
  float xn = fmaxf(sqrtf(s2), EPSF);
  float sh = sinhf(xn);
  float t0 = sqrtf(1.f + sh * sh);
  float tt = fmaxf(t0, 1.f + EPSF);
  float al = acoshf(tt);
  ubf[node * 64 + lane] = lane ? f2bf(al * x / xn) : (unsigned short)0;
}

// ---------------- K2: MFMA mu -> (q,k,v) -> phi_q, phi_k (transposed GEMM), VT(bf16) ----------------
// Block = 256 thr (4 waves). Wave owns 32 consecutive rows of one head.
__global__ __launch_bounds__(256) void k2_mfma(const unsigned short* __restrict__ ubf,
                                               const unsigned short* __restrict__ Wfrag,
                                               const unsigned short* __restrict__ Pfrag,
                                               unsigned short* __restrict__ VT,
                                               unsigned short* __restrict__ phiq, unsigned short* __restrict__ phik) {
  __shared__ short sbuf[2][4][32 * 72];   // s rows (bf16), stride 72
  __shared__ float sfront[2][4][32];      // per-row log2-domain front
  int w = threadIdx.x >> 6, lane = threadIdx.x & 63;
  int q = lane >> 4, l = lane & 15;
  int b = blockIdx.x;
  int h = b >> 8, t = b & 255;
  int n0 = t * 128 + w * 32;
  int r0 = h * 32768 + n0;

  // A-fragments of u (bf16 direct loads)
  s8v afr[2][2];
#pragma unroll
  for (int mt = 0; mt < 2; ++mt)
#pragma unroll
    for (int ks = 0; ks < 2; ++ks)
      afr[mt][ks] = *(const s8v*)(ubf + (size_t)(n0 + mt * 16 + l) * 64 + ks * 32 + q * 8);

  const s8v* Wf = (const s8v*)Wfrag;
  const s8v* Pf = (const s8v*)Pfrag;

  // ---- Phase 1: three mu GEMMs + row nonlinearity ----
#pragma unroll
  for (int sm = 0; sm < 3; ++sm) {
    f4v acc[2][4];
#pragma unroll
    for (int mt = 0; mt < 2; ++mt)
#pragma unroll
      for (int nt = 0; nt < 4; ++nt) acc[mt][nt] = (f4v)(0.f);
#pragma unroll
    for (int ks = 0; ks < 2; ++ks)
#pragma unroll
      for (int nt = 0; nt < 4; ++nt) {
        s8v bf = Wf[(((sm * 8 + h) * 2 + ks) * 4 + nt) * 64 + lane];
#pragma unroll
        for (int mt = 0; mt < 2; ++mt)
          acc[mt][nt] = __builtin_amdgcn_mfma_f32_16x16x32_bf16(afr[mt][ks], bf, acc[mt][nt], 0, 0, 0);
      }
#pragma unroll
    for (int mt = 0; mt < 2; ++mt) {
      float rs[4];
#pragma unroll
      for (int reg = 0; reg < 4; ++reg) {
        float v0 = (l == 0) ? 0.f : acc[mt][0][reg];
        rs[reg] = v0 * v0 + acc[mt][1][reg] * acc[mt][1][reg] + acc[mt][2][reg] * acc[mt][2][reg] +
                  acc[mt][3][reg] * acc[mt][3][reg];
      }
#pragma unroll
      for (int reg = 0; reg < 4; ++reg) {
#pragma unroll
        for (int off = 1; off < 16; off <<= 1) rs[reg] += __shfl_xor(rs[reg], off, 64);
      }
#pragma unroll
      for (int reg = 0; reg < 4; ++reg) {
        float x = fmaxf(sqrtf(rs[reg]), EPSF);
        float e = exp2f(x * LOG2E);
        float sh = 0.5f * (e - frcp(e));
        float ratio = sh * frcp(x);
        float sh2 = sh * sh;
        int row = mt * 16 + q * 4 + reg;
        if (sm == 2) {
          float tt = sqrtf(1.f + sh2);
          float vb[4];
#pragma unroll
          for (int nt = 0; nt < 4; ++nt) {
            float val = acc[mt][nt][reg] * ratio;
            if (l == 0 && nt == 0) val = tt;
            vb[nt] = val;
          }
          // VT[h][d][n]: can't pack across reg here (d varies per nt, n fixed); store via per-reg path below
          // store 4 d-values as scalar shorts (d = nt*16+l, n = n0+row)
#pragma unroll
          for (int nt = 0; nt < 4; ++nt)
            VT[(((size_t)(h * 64 + nt * 16 + l)) << 15) + n0 + row] = f2bf(vb[nt]);
        } else {
          float lf = -sh2 * LOG2E - LOG2SQRT63;
          if (l == 0) sfront[sm][w][row] = lf;
#pragma unroll
          for (int nt = 0; nt < 4; ++nt) {
            float val = acc[mt][nt][reg] * ratio;
            if (l == 0 && nt == 0) val = 0.f;
            sbuf[sm][w][row * 72 + nt * 16 + l] = (short)(__float_as_uint(val) >> 16);  // trunc bf16
          }
        }
      }
    }
  }

  // ---- Phase 2: phi^T = (sqrt2*log2e*P)^T-as-A  @  s-as-B ; phi = exp2(acc + lf) ----
#pragma unroll
  for (int sm = 0; sm < 2; ++sm) {
    s8v bsf[2][2];  // [nt][ks] : B[k][n], n = nt*16+l (node), k = ks*32+q*8+j
#pragma unroll
    for (int nt = 0; nt < 2; ++nt)
#pragma unroll
      for (int ks = 0; ks < 2; ++ks)
        bsf[nt][ks] = *(const s8v*)&sbuf[sm][w][(nt * 16 + l) * 72 + ks * 32 + q * 8];
    float lf0 = sfront[sm][w][l];
    float lf1 = sfront[sm][w][16 + l];
    unsigned short* dst = sm ? phik : phiq;
#pragma unroll
    for (int mt = 0; mt < 8; ++mt) {
      f4v a0 = (f4v)(0.f), a1 = (f4v)(0.f);
#pragma unroll
      for (int ks = 0; ks < 2; ++ks) {
        s8v ap = Pf[(mt * 2 + ks) * 64 + lane];
        a0 = __builtin_amdgcn_mfma_f32_16x16x32_bf16(ap, bsf[0][ks], a0, 0, 0, 0);
        a1 = __builtin_amdgcn_mfma_f32_16x16x32_bf16(ap, bsf[1][ks], a1, 0, 0, 0);
      }
      // C' row = m = mt*16+q*4+reg, col = node = nt*16+l ; 4 regs are m-contiguous -> 8B store
      float v00 = exp2f(a0[0] + lf0), v01 = exp2f(a0[1] + lf0), v02 = exp2f(a0[2] + lf0), v03 = exp2f(a0[3] + lf0);
      float v10 = exp2f(a1[0] + lf1), v11 = exp2f(a1[1] + lf1), v12 = exp2f(a1[2] + lf1), v13 = exp2f(a1[3] + lf1);
      uint2 p0, p1;
      p0.x = pack2(v00, v01); p0.y = pack2(v02, v03);
      p1.x = pack2(v10, v11); p1.y = pack2(v12, v13);
      *(uint2*)(dst + (size_t)(r0 + l) * 128 + mt * 16 + q * 4) = p0;
      *(uint2*)(dst + (size_t)(r0 + 16 + l) * 128 + mt * 16 + q * 4) = p1;
    }
  }
}

// ---------------- K3: MFMA split-K  part[c][h] += phik_h^T @ V_h  (no atomics) ----------------
__global__ __launch_bounds__(256) void k3_mfma(const unsigned short* __restrict__ phik,
                                               const unsigned short* __restrict__ VT,
                                               float* __restrict__ part) {
  int b = blockIdx.x;
  int h = b >> 7, c = b & 127;
  int w = threadIdx.x >> 6, lane = threadIdx.x & 63;
  int q = lane >> 4, l = lane & 15;
  int n0 = c * 256;

  f4v acc[2][4];
#pragma unroll
  for (int mtl = 0; mtl < 2; ++mtl)
#pragma unroll
    for (int nt = 0; nt < 4; ++nt) acc[mtl][nt] = (f4v)(0.f);

  const unsigned short* ap = phik + (size_t)(8 * (n0 + q * 8) + h) * 128 + l;

  for (int ks = 0; ks < 8; ++ks) {
    int nb = n0 + ks * 32;
    s8v bfr[4];
#pragma unroll
    for (int nt = 0; nt < 4; ++nt)
      bfr[nt] = *(const s8v*)(VT + (((size_t)(h * 64 + nt * 16 + l)) << 15) + nb + q * 8);
    s8v afr[2];
#pragma unroll
    for (int mtl = 0; mtl < 2; ++mtl) {
      int moff = (w * 2 + mtl) * 16;
      s8v a;
#pragma unroll
      for (int j = 0; j < 8; ++j) a[j] = (short)ap[(size_t)(ks * 32 + j) * 1024 + moff];
      afr[mtl] = a;
    }
#pragma unroll
    for (int mtl = 0; mtl < 2; ++mtl)
#pragma unroll
      for (int nt = 0; nt < 4; ++nt)
        acc[mtl][nt] = __builtin_amdgcn_mfma_f32_16x16x32_bf16(afr[mtl], bfr[nt], acc[mtl][nt], 0, 0, 0);
  }

  float* dst = part + (((size_t)(c * 8 + h)) << 13);
#pragma unroll
  for (int mtl = 0; mtl < 2; ++mtl)
#pragma unroll
    for (int nt = 0; nt < 4; ++nt)
#pragma unroll
      for (int reg = 0; reg < 4; ++reg)
        dst[((w * 2 + mtl) * 16 + q * 4 + reg) * 64 + nt * 16 + l] = acc[mtl][nt][reg];
}

// ---------------- K3p: reduce 128 split-K partials -> lastB (bf16 B-frag order) ----------------
__global__ __launch_bounds__(256) void k3p_pack(const float* __restrict__ part, unsigned short* __restrict__ lastB) {
  int t = blockIdx.x * 256 + threadIdx.x;  // 65536 = h*8192 + k*64 + n
  float s = 0.f;
#pragma unroll 8
  for (int c = 0; c < 128; ++c) s += part[((size_t)c << 16) + t];
  int n = t & 63, k = (t >> 6) & 127, h = t >> 13;
  int ks = k >> 5, j = k & 7, qq = (k >> 3) & 3;
  int lane = qq * 16 + (n & 15), nt = n >> 4;
  lastB[((((h * 4 + ks) * 4 + nt) * 64 + lane) << 3) + j] = f2bf(s);
}

// ---------------- K4: MFMA zo = phiq @ last[h'] ; row-norm; 8-head mean; final normalize ----------------
__global__ __launch_bounds__(512) void k4_mfma(const unsigned short* __restrict__ phiq,
                                               const unsigned short* __restrict__ lastB,
                                               const float* __restrict__ ea, float* __restrict__ out) {
  __shared__ float zbuf[8][32][64];
  int w = threadIdx.x >> 6, lane = threadIdx.x & 63;
  int q = lane >> 4, l = lane & 15;
  int n0 = blockIdx.x * 32;

  const s8v* Bf = (const s8v*)lastB;
  s8v bf[4][4];
#pragma unroll
  for (int ks = 0; ks < 4; ++ks)
#pragma unroll
    for (int nt = 0; nt < 4; ++nt) bf[ks][nt] = Bf[((w * 4 + ks) * 4 + nt) * 64 + lane];

  s8v af[2][4];
#pragma unroll
  for (int mt = 0; mt < 2; ++mt)
#pragma unroll
    for (int ks = 0; ks < 4; ++ks)
      af[mt][ks] = *(const s8v*)(phiq + (size_t)(8 * (n0 + mt * 16 + l) + w) * 128 + ks * 32 + q * 8);

  f4v acc[2][4];
#pragma unroll
  for (int mt = 0; mt < 2; ++mt)
#pragma unroll
    for (int nt = 0; nt < 4; ++nt) acc[mt][nt] = (f4v)(0.f);
#pragma unroll
  for (int ks = 0; ks < 4; ++ks)
#pragma unroll
    for (int nt = 0; nt < 4; ++nt)
#pragma unroll
      for (int mt = 0; mt < 2; ++mt)
        acc[mt][nt] = __builtin_amdgcn_mfma_f32_16x16x32_bf16(af[mt][ks], bf[ks][nt], acc[mt][nt], 0, 0, 0);

#pragma unroll
  for (int mt = 0; mt < 2; ++mt) {
    float rs[4];
#pragma unroll
    for (int reg = 0; reg < 4; ++reg) {
      float v0 = acc[mt][0][reg];
      float s0 = (l == 0) ? -v0 * v0 : v0 * v0;
      rs[reg] = s0 + acc[mt][1][reg] * acc[mt][1][reg] + acc[mt][2][reg] * acc[mt][2][reg] +
                acc[mt][3][reg] * acc[mt][3][reg];
    }
#pragma unroll
    for (int reg = 0; reg < 4; ++reg) {
#pragma unroll
      for (int off = 1; off < 16; off <<= 1) rs[reg] += __shfl_xor(rs[reg], off, 64);
    }
#pragma unroll
    for (int reg = 0; reg < 4; ++reg) {
      float inv = 1.f / sqrtf(fabsf(rs[reg]));
      int i = mt * 16 + q * 4 + reg;
#pragma unroll
      for (int nt = 0; nt < 4; ++nt) zbuf[w][i][nt * 16 + l] = acc[mt][nt][reg] * inv;
    }
  }
  __syncthreads();

  int tid = threadIdx.x;
  int i = tid >> 4, c0 = (tid & 15) * 4;
  float4 s = make_float4(0.f, 0.f, 0.f, 0.f);
#pragma unroll
  for (int w2 = 0; w2 < 8; ++w2) {
    float4 v = *(const float4*)&zbuf[w2][i][c0];
    s.x += v.x; s.y += v.y; s.z += v.z; s.w += v.w;
  }
  s.x *= 0.125f; s.y *= 0.125f; s.z *= 0.125f; s.w *= 0.125f;
  float m2 = ((c0 == 0) ? -s.x * s.x : s.x * s.x) + s.y * s.y + s.z * s.z + s.w * s.w;
#pragma unroll
  for (int off = 1; off < 16; off <<= 1) m2 += __shfl_xor(m2, off, 64);
  float inv = 1.f / sqrtf(fabsf(m2));
  float4 o = make_float4(s.x * inv, s.y * inv, s.z * inv, s.w * inv);
  *(float4*)(out + (size_t)(n0 + i) * 64 + c0) = o;
  if (blockIdx.x == 0 && tid == 0) out[(size_t)NNODES * 64] = ea[0] * (1.0f / 524288.0f);
}

// ---------------- K5: link loss ----------------
__global__ __launch_bounds__(256) void k5_ea(const unsigned short* __restrict__ phiq,
                                             const unsigned short* __restrict__ phik,
                                             const int* __restrict__ ei, float* __restrict__ ea) {
  __shared__ float part[4];
  int lane = threadIdx.x & 63, w = threadIdx.x >> 6;
  int wid = blockIdx.x * 4 + w;
  float acc = 0.f;
  for (int i = 0; i < 64; ++i) {
    int e = wid * 64 + i;
    int s = ei[e];
    int d = ei[NEDGES + e];
    const unsigned short* bq = phiq + (size_t)d * 1024;
    const unsigned short* bk = phik + (size_t)s * 1024;
    uint4 qa = *(const uint4*)(bq + lane * 16);
    uint4 qb = *(const uint4*)(bq + lane * 16 + 8);
    uint4 ka = *(const uint4*)(bk + lane * 16);
    uint4 kb = *(const uint4*)(bk + lane * 16 + 8);
    unsigned qs[8] = {qa.x, qa.y, qa.z, qa.w, qb.x, qb.y, qb.z, qb.w};
    unsigned ks[8] = {ka.x, ka.y, ka.z, ka.w, kb.x, kb.y, kb.z, kb.w};
#pragma unroll
    for (int p = 0; p < 8; ++p) {
      float q0 = __uint_as_float(qs[p] << 16);
      float q1 = __uint_as_float(qs[p] & 0xffff0000u);
      float k0 = __uint_as_float(ks[p] << 16);
      float k1 = __uint_as_float(ks[p] & 0xffff0000u);
      acc = fmaf(q0, k0, acc);
      acc = fmaf(q1, k1, acc);
    }
  }
  acc = wave_sum(acc);
  if (lane == 0) part[w] = acc;
  __syncthreads();
  if (threadIdx.x == 0) atomicAdd(ea, part[0] + part[1] + part[2] + part[3]);
}

// ---------------- launch ----------------
extern "C" void kernel_launch(void* const* d_in, const int* in_sizes, int n_in,
                              void* d_out, int out_size, void* d_ws, size_t ws_size,
                              hipStream_t stream) {
  const float* z  = (const float*)d_in[0];
  const float* Wq = (const float*)d_in[1];
  const float* Wk = (const float*)d_in[2];
  const float* Wv = (const float*)d_in[3];
  const float* P  = (const float*)d_in[4];
  const int* ei   = (const int*)d_in[5];
  char* ws = (char*)d_ws;
  unsigned short* Wfrag = (unsigned short*)(ws + OFF_WFRAG);
  unsigned short* lastB = (unsigned short*)(ws + OFF_LASTB);  // sequenced reuse of Wfrag region
  unsigned short* Pfrag = (unsigned short*)(ws + OFF_PFRAG);
  float*          ea    = (float*)(ws + OFF_EA);
  unsigned short* ubf   = (unsigned short*)(ws + OFF_U);
  unsigned short* VT    = (unsigned short*)(ws + OFF_VT);
  float*          part  = (float*)(ws + OFF_PART);
  unsigned short* phiq  = (unsigned short*)(ws + OFF_PHIQ);
  unsigned short* phik  = (unsigned short*)(ws + OFF_PHIK);

  hipMemsetAsync(ea, 0, 4, stream);
  k0_prep<<<96, 256, 0, stream>>>(Wq, Wk, Wv, P, Wfrag, Pfrag);
  k1_u<<<NNODES / 4, 256, 0, stream>>>(z, ubf);
  k2_mfma<<<2048, 256, 0, stream>>>(ubf, Wfrag, Pfrag, VT, phiq, phik);
  k3_mfma<<<1024, 256, 0, stream>>>(phik, VT, part);
  k3p_pack<<<256, 256, 0, stream>>>(part, lastB);
  k5_ea<<<NEDGES / 256, 256, 0, stream>>>(phiq, phik, ei, ea);
  k4_mfma<<<NNODES / 32, 512, 0, stream>>>(phiq, lastB, ea, (float*)d_out);
}

// Round 6
// 239.011 us; speedup vs baseline: 4.6605x; 1.0872x over previous
//
#include <hip/hip_runtime.h>

#define DEV __device__ __forceinline__

// ---------------- constants ----------------
// N_NODES=32768, N_EDGES=65536, H=8, D=64, DS=63, M=128, R=H*N=262144
#define NNODES 32768
#define NEDGES 65536
#define NROWS  262144
#define EPSF   1e-7f
#define SQRT2F 1.4142135623730951f
#define LOG2E  1.4426950408889634f
#define LOG2SQRT63 2.9886399611087573f   // log2(sqrt(63))

// ---------------- ws layout (bytes) ----------------
// Sequenced reuse: Wfrag (k0->k2) then lastB (k3p->k4) share offset 0.
#define OFF_WFRAG 0u          // bf16 [3][8][2][4][64][8]  W in MFMA B-frag order (196608 B) [dead after k2]
#define OFF_LASTB 0u          // bf16 [8][4][4][64][8] B-frag of last (131072 B) [written k3p, read k4]
#define OFF_PFRAG 196608u     // bf16 [8][2][64][8]  sqrt(2)*log2e*P, MFMA A-frag order (16384 B)
#define OFF_EA    212992u     // float [1] (zeroed)
#define OFF_U     409600u     // bf16 [N][64] u (4194304 B) [dead after k2]
#define OFF_PART  42352640u   // bf16 [256 c][8 h][64 d][128 m] split-K partials of last (33554432 B)
#define OFF_PHIQ  75907072u   // bf16 [R][128]
#define OFF_PHIK  143015936u  // bf16 [R][128]
// end: 210124800

typedef short s8v __attribute__((ext_vector_type(8)));   // 8 bf16 in 4 VGPRs (MFMA A/B frag)
typedef float f4v __attribute__((ext_vector_type(4)));   // MFMA C/D frag

// ---------------- helpers ----------------
DEV float wave_sum(float v) {
#pragma unroll
  for (int o = 1; o < 64; o <<= 1) v += __shfl_xor(v, o, 64);
  return v;
}
DEV unsigned short f2bf(float f) {  // rne
  unsigned u = __float_as_uint(f);
  return (unsigned short)((u + 0x7fffu + ((u >> 16) & 1u)) >> 16);
}
DEV float bf2f(unsigned short h) { return __uint_as_float(((unsigned)h) << 16); }
// pack two f32 -> two bf16 (round-half-up) in one uint: low short = bf16(lo), high = bf16(hi)
DEV unsigned pack2(float lo, float hi) {
  return __builtin_amdgcn_perm(__float_as_uint(hi) + 0x8000u, __float_as_uint(lo) + 0x8000u, 0x07060302u);
}
DEV float frcp(float x) { return __builtin_amdgcn_rcpf(x); }

// ---------------- K0: pack W (B-frag) and sqrt(2)*log2e*P (A-frag) as bf16 ----------------
__global__ __launch_bounds__(256) void k0_prep(const float* __restrict__ Wq, const float* __restrict__ Wk,
                                               const float* __restrict__ Wv, const float* __restrict__ P,
                                               unsigned short* __restrict__ Wfrag, unsigned short* __restrict__ Pfrag) {
  int tid = blockIdx.x * blockDim.x + threadIdx.x;
  int stride = gridDim.x * blockDim.x;
  // Wfrag[sm][h][ks][nt][lane][j] : B[k][n], n = nt*16+(lane&15), k = ks*32+(lane>>4)*8+j
  for (int i = tid; i < 98304; i += stride) {
    int j = i & 7, lane = (i >> 3) & 63, nt = (i >> 9) & 3, ks = (i >> 11) & 1, h = (i >> 12) & 7, sm = i >> 15;
    int k = ks * 32 + (lane >> 4) * 8 + j;
    int n = nt * 16 + (lane & 15);
    const float* W = (sm == 0) ? Wq : ((sm == 1) ? Wk : Wv);
    Wfrag[i] = f2bf(W[(h * 64 + n) * 64 + k]);
  }
  // Pfrag[mt8][ks2][lane][j] : A[m][k], m = mt*16+(lane&15), k = ks*32+(lane>>4)*8+j ; k=0 zero pad
  for (int i = tid; i < 8192; i += stride) {
    int j = i & 7, lane = (i >> 3) & 63, ks = (i >> 9) & 1, mt = (i >> 10) & 7;
    int k = ks * 32 + (lane >> 4) * 8 + j;
    int m = mt * 16 + (lane & 15);
    Pfrag[i] = (k == 0) ? (unsigned short)0 : f2bf(P[(k - 1) * 128 + m] * (SQRT2F * LOG2E));
  }
}

// ---------------- K1: u = logmap0(proj(expmap0(z))) -> bf16 ----------------
__global__ __launch_bounds__(256) void k1_u(const float* __restrict__ z, unsigned short* __restrict__ ubf) {
  int lane = threadIdx.x & 63, w = threadIdx.x >> 6;
  int node = blockIdx.x * 4 + w;
  float x = z[node * 64 + lane];
  float xs = lane ? x : 0.f;
  float s2 = wave_sum(xs * xs);
  float xn = fmaxf(sqrtf(s2), EPSF);
  float sh = sinhf(xn);
  float t0 = sqrtf(1.f + sh * sh);
  float tt = fmaxf(t0, 1.f + EPSF);
  float al = acoshf(tt);
  ubf[node * 64 + lane] = lane ? f2bf(al * x / xn) : (unsigned short)0;
}

// ---------------- K2: fused mu -> (q,k,v) -> phi_q, phi_k ; + last partial (phik^T @ V) ----------------
// Block = 256 thr (4 waves), block (h, t) owns 128 nodes. LDS:
//   sbuf   [2][4][32*72] bf16 + sfront (37888 B)  -- phase1 -> phase2, DEAD after phase-2 reads
//   kbufT  [128 m][132]  bf16 (33792 B)           -- ALIASES sbuf after barrier; phik exchange
//   vbufT  [64 d][136]   bf16 (17408 B)           -- V exchange (written phase 1)
// Fused GEMM: wave w computes m-slice [w*32, w*32+32) over all 128 block nodes -> part[t][h][d][m] bf16.
__global__ __launch_bounds__(256) void k2_mfma(const unsigned short* __restrict__ ubf,
                                               const unsigned short* __restrict__ Wfrag,
                                               const unsigned short* __restrict__ Pfrag,
                                               unsigned short* __restrict__ phiq, unsigned short* __restrict__ phik,
                                               unsigned short* __restrict__ part) {
  __shared__ short sbuf_raw[18944];       // 37888 B = sbuf 36864 + sfront 1024
  __shared__ short vbufT[64 * 136];       // 17408 B
  short* sbuf = sbuf_raw;                 // [(sm*4+w)*2304 + row*72 + col]
  float* sfront = (float*)(sbuf_raw + 18432);  // [(sm*4+w)*32 + row]
  short* kbufT = sbuf_raw;                // alias: [m*132 + node], 16896 shorts

  int w = threadIdx.x >> 6, lane = threadIdx.x & 63;
  int q = lane >> 4, l = lane & 15;
  int b = blockIdx.x;
  int h = b >> 8, t = b & 255;
  int n0 = t * 128 + w * 32;
  int r0 = h * 32768 + n0;

  // A-fragments of u (bf16 direct loads)
  s8v afr[2][2];
#pragma unroll
  for (int mt = 0; mt < 2; ++mt)
#pragma unroll
    for (int ks = 0; ks < 2; ++ks)
      afr[mt][ks] = *(const s8v*)(ubf + (size_t)(n0 + mt * 16 + l) * 64 + ks * 32 + q * 8);

  const s8v* Wf = (const s8v*)Wfrag;
  const s8v* Pf = (const s8v*)Pfrag;

  // ---- Phase 1: three mu GEMMs + row nonlinearity; V -> vbufT ----
#pragma unroll
  for (int sm = 0; sm < 3; ++sm) {
    f4v acc[2][4];
#pragma unroll
    for (int mt = 0; mt < 2; ++mt)
#pragma unroll
      for (int nt = 0; nt < 4; ++nt) acc[mt][nt] = (f4v)(0.f);
#pragma unroll
    for (int ks = 0; ks < 2; ++ks)
#pragma unroll
      for (int nt = 0; nt < 4; ++nt) {
        s8v bf = Wf[(((sm * 8 + h) * 2 + ks) * 4 + nt) * 64 + lane];
#pragma unroll
        for (int mt = 0; mt < 2; ++mt)
          acc[mt][nt] = __builtin_amdgcn_mfma_f32_16x16x32_bf16(afr[mt][ks], bf, acc[mt][nt], 0, 0, 0);
      }
#pragma unroll
    for (int mt = 0; mt < 2; ++mt) {
      float rs[4];
#pragma unroll
      for (int reg = 0; reg < 4; ++reg) {
        float v0 = (l == 0) ? 0.f : acc[mt][0][reg];
        rs[reg] = v0 * v0 + acc[mt][1][reg] * acc[mt][1][reg] + acc[mt][2][reg] * acc[mt][2][reg] +
                  acc[mt][3][reg] * acc[mt][3][reg];
      }
#pragma unroll
      for (int reg = 0; reg < 4; ++reg) {
#pragma unroll
        for (int off = 1; off < 16; off <<= 1) rs[reg] += __shfl_xor(rs[reg], off, 64);
      }
      float vreg[4][4];  // [nt][reg], sm==2 only
#pragma unroll
      for (int reg = 0; reg < 4; ++reg) {
        float x = fmaxf(sqrtf(rs[reg]), EPSF);
        float e = exp2f(x * LOG2E);
        float sh = 0.5f * (e - frcp(e));
        float ratio = sh * frcp(x);
        float sh2 = sh * sh;
        int row = mt * 16 + q * 4 + reg;
        if (sm == 2) {
          float tt2 = sqrtf(1.f + sh2);
#pragma unroll
          for (int nt = 0; nt < 4; ++nt) {
            float val = acc[mt][nt][reg] * ratio;
            if (l == 0 && nt == 0) val = tt2;  // time component (d=0)
            vreg[nt][reg] = val;
          }
        } else {
          float lf = -sh2 * LOG2E - LOG2SQRT63;
          if (l == 0) sfront[(sm * 4 + w) * 32 + row] = lf;
#pragma unroll
          for (int nt = 0; nt < 4; ++nt) {
            float val = acc[mt][nt][reg] * ratio;
            if (l == 0 && nt == 0) val = 0.f;
            sbuf[(sm * 4 + w) * 2304 + row * 72 + nt * 16 + l] = (short)(__float_as_uint(val) >> 16);
          }
        }
      }
      if (sm == 2) {
        // vbufT[d][node]: d = nt*16+l fixed, 4 consecutive nodes (reg) -> 8B write
#pragma unroll
        for (int nt = 0; nt < 4; ++nt) {
          uint2 pk;
          pk.x = pack2(vreg[nt][0], vreg[nt][1]);
          pk.y = pack2(vreg[nt][2], vreg[nt][3]);
          *(uint2*)&vbufT[(nt * 16 + l) * 136 + w * 32 + mt * 16 + q * 4] = pk;
        }
      }
    }
  }

  // ---- Phase 2: phi^T GEMM ; phi = exp2(acc + lf) -> global ; keep phik regs ----
  uint2 keep0[8], keep1[8];
#pragma unroll
  for (int sm = 0; sm < 2; ++sm) {
    s8v bsf[2][2];  // [nt2][ks] : B[k=c][n=node]
#pragma unroll
    for (int nt = 0; nt < 2; ++nt)
#pragma unroll
      for (int ks = 0; ks < 2; ++ks)
        bsf[nt][ks] = *(const s8v*)&sbuf[(sm * 4 + w) * 2304 + (nt * 16 + l) * 72 + ks * 32 + q * 8];
    float lf0 = sfront[(sm * 4 + w) * 32 + l];
    float lf1 = sfront[(sm * 4 + w) * 32 + 16 + l];
    unsigned short* dst = sm ? phik : phiq;
#pragma unroll
    for (int mt = 0; mt < 8; ++mt) {
      f4v a0 = (f4v)(0.f), a1 = (f4v)(0.f);
#pragma unroll
      for (int ks = 0; ks < 2; ++ks) {
        s8v ap = Pf[(mt * 2 + ks) * 64 + lane];
        a0 = __builtin_amdgcn_mfma_f32_16x16x32_bf16(ap, bsf[0][ks], a0, 0, 0, 0);
        a1 = __builtin_amdgcn_mfma_f32_16x16x32_bf16(ap, bsf[1][ks], a1, 0, 0, 0);
      }
      float v00 = exp2f(a0[0] + lf0), v01 = exp2f(a0[1] + lf0), v02 = exp2f(a0[2] + lf0), v03 = exp2f(a0[3] + lf0);
      float v10 = exp2f(a1[0] + lf1), v11 = exp2f(a1[1] + lf1), v12 = exp2f(a1[2] + lf1), v13 = exp2f(a1[3] + lf1);
      uint2 p0, p1;
      p0.x = pack2(v00, v01); p0.y = pack2(v02, v03);
      p1.x = pack2(v10, v11); p1.y = pack2(v12, v13);
      *(uint2*)(dst + (size_t)(r0 + l) * 128 + mt * 16 + q * 4) = p0;
      *(uint2*)(dst + (size_t)(r0 + 16 + l) * 128 + mt * 16 + q * 4) = p1;
      if (sm == 1) { keep0[mt] = p0; keep1[mt] = p1; }
    }
  }

  __syncthreads();  // sbuf fully consumed by all waves -> safe to alias as kbufT

  // scatter phik into kbufT[m][node] (stride 132)
  {
    int nd0 = w * 32 + l, nd1 = w * 32 + 16 + l;
#pragma unroll
    for (int mt = 0; mt < 8; ++mt) {
      int m = mt * 16 + q * 4;
      kbufT[(m + 0) * 132 + nd0] = (short)(keep0[mt].x & 0xffffu);
      kbufT[(m + 1) * 132 + nd0] = (short)(keep0[mt].x >> 16);
      kbufT[(m + 2) * 132 + nd0] = (short)(keep0[mt].y & 0xffffu);
      kbufT[(m + 3) * 132 + nd0] = (short)(keep0[mt].y >> 16);
      kbufT[(m + 0) * 132 + nd1] = (short)(keep1[mt].x & 0xffffu);
      kbufT[(m + 1) * 132 + nd1] = (short)(keep1[mt].x >> 16);
      kbufT[(m + 2) * 132 + nd1] = (short)(keep1[mt].y & 0xffffu);
      kbufT[(m + 3) * 132 + nd1] = (short)(keep1[mt].y >> 16);
    }
  }
  __syncthreads();  // kbufT + vbufT ready

  // ---- Fused GEMM: D[m][d] = sum_node kbufT[m][node] * vbufT[d][node], m-slice per wave ----
  f4v facc[2][4];
#pragma unroll
  for (int mtl = 0; mtl < 2; ++mtl)
#pragma unroll
    for (int nt = 0; nt < 4; ++nt) facc[mtl][nt] = (f4v)(0.f);
#pragma unroll
  for (int kc = 0; kc < 4; ++kc) {
    s8v bv[4];
#pragma unroll
    for (int nt = 0; nt < 4; ++nt)
      bv[nt] = *(const s8v*)&vbufT[(nt * 16 + l) * 136 + kc * 32 + q * 8];
    s8v av[2];
#pragma unroll
    for (int mtl = 0; mtl < 2; ++mtl) {
      const short* kb = &kbufT[((2 * w + mtl) * 16 + l) * 132 + kc * 32 + q * 8];
      union { s8v v; long long L[2]; } ua;
      ua.L[0] = *(const long long*)kb;
      ua.L[1] = *(const long long*)(kb + 4);
      av[mtl] = ua.v;
    }
#pragma unroll
    for (int mtl = 0; mtl < 2; ++mtl)
#pragma unroll
      for (int nt = 0; nt < 4; ++nt)
        facc[mtl][nt] = __builtin_amdgcn_mfma_f32_16x16x32_bf16(av[mtl], bv[nt], facc[mtl][nt], 0, 0, 0);
  }
  // store part[t][h][d][m] bf16, m-contiguous 8B stores
#pragma unroll
  for (int mtl = 0; mtl < 2; ++mtl)
#pragma unroll
    for (int nt = 0; nt < 4; ++nt) {
      uint2 pk;
      pk.x = pack2(facc[mtl][nt][0], facc[mtl][nt][1]);
      pk.y = pack2(facc[mtl][nt][2], facc[mtl][nt][3]);
      int d = nt * 16 + l;
      int m = (2 * w + mtl) * 16 + q * 4;
      *(uint2*)(part + ((size_t)((t * 8 + h) * 64 + d)) * 128 + m) = pk;
    }
}

// ---------------- K3p: reduce 256 bf16 partials -> lastB (bf16 B-frag order) ----------------
// thread handles 2 consecutive m (one uint per read). 32768 threads.
__global__ __launch_bounds__(256) void k3p_pack(const unsigned* __restrict__ part32, unsigned short* __restrict__ lastB) {
  int t2 = blockIdx.x * 256 + threadIdx.x;  // 32768 = h*4096 + d*64 + m/2
  float s0 = 0.f, s1 = 0.f;
#pragma unroll 8
  for (int c = 0; c < 256; ++c) {
    unsigned v = part32[((size_t)c << 12) + t2];
    s0 += __uint_as_float(v << 16);
    s1 += __uint_as_float(v & 0xffff0000u);
  }
  int m = (t2 & 63) * 2, d = (t2 >> 6) & 63, h = t2 >> 12;
  int ks = m >> 5, j = m & 7, qq = (m >> 3) & 3;
  int lane = qq * 16 + (d & 15), nt = d >> 4;
  unsigned short* dst = &lastB[((((h * 4 + ks) * 4 + nt) * 64 + lane) << 3) + j];
  dst[0] = f2bf(s0);
  dst[1] = f2bf(s1);
}

// ---------------- K4: MFMA zo = phiq @ last[h'] ; row-norm; 8-head mean; final normalize ----------------
__global__ __launch_bounds__(512) void k4_mfma(const unsigned short* __restrict__ phiq,
                                               const unsigned short* __restrict__ lastB,
                                               const float* __restrict__ ea, float* __restrict__ out) {
  __shared__ float zbuf[8][32][64];
  int w = threadIdx.x >> 6, lane = threadIdx.x & 63;
  int q = lane >> 4, l = lane & 15;
  int n0 = blockIdx.x * 32;

  const s8v* Bf = (const s8v*)lastB;
  s8v bf[4][4];
#pragma unroll
  for (int ks = 0; ks < 4; ++ks)
#pragma unroll
    for (int nt = 0; nt < 4; ++nt) bf[ks][nt] = Bf[((w * 4 + ks) * 4 + nt) * 64 + lane];

  s8v af[2][4];
#pragma unroll
  for (int mt = 0; mt < 2; ++mt)
#pragma unroll
    for (int ks = 0; ks < 4; ++ks)
      af[mt][ks] = *(const s8v*)(phiq + (size_t)(8 * (n0 + mt * 16 + l) + w) * 128 + ks * 32 + q * 8);

  f4v acc[2][4];
#pragma unroll
  for (int mt = 0; mt < 2; ++mt)
#pragma unroll
    for (int nt = 0; nt < 4; ++nt) acc[mt][nt] = (f4v)(0.f);
#pragma unroll
  for (int ks = 0; ks < 4; ++ks)
#pragma unroll
    for (int nt = 0; nt < 4; ++nt)
#pragma unroll
      for (int mt = 0; mt < 2; ++mt)
        acc[mt][nt] = __builtin_amdgcn_mfma_f32_16x16x32_bf16(af[mt][ks], bf[ks][nt], acc[mt][nt], 0, 0, 0);

#pragma unroll
  for (int mt = 0; mt < 2; ++mt) {
    float rs[4];
#pragma unroll
    for (int reg = 0; reg < 4; ++reg) {
      float v0 = acc[mt][0][reg];
      float s0 = (l == 0) ? -v0 * v0 : v0 * v0;
      rs[reg] = s0 + acc[mt][1][reg] * acc[mt][1][reg] + acc[mt][2][reg] * acc[mt][2][reg] +
                acc[mt][3][reg] * acc[mt][3][reg];
    }
#pragma unroll
    for (int reg = 0; reg < 4; ++reg) {
#pragma unroll
      for (int off = 1; off < 16; off <<= 1) rs[reg] += __shfl_xor(rs[reg], off, 64);
    }
#pragma unroll
    for (int reg = 0; reg < 4; ++reg) {
      float inv = 1.f / sqrtf(fabsf(rs[reg]));
      int i = mt * 16 + q * 4 + reg;
#pragma unroll
      for (int nt = 0; nt < 4; ++nt) zbuf[w][i][nt * 16 + l] = acc[mt][nt][reg] * inv;
    }
  }
  __syncthreads();

  int tid = threadIdx.x;
  int i = tid >> 4, c0 = (tid & 15) * 4;
  float4 s = make_float4(0.f, 0.f, 0.f, 0.f);
#pragma unroll
  for (int w2 = 0; w2 < 8; ++w2) {
    float4 v = *(const float4*)&zbuf[w2][i][c0];
    s.x += v.x; s.y += v.y; s.z += v.z; s.w += v.w;
  }
  s.x *= 0.125f; s.y *= 0.125f; s.z *= 0.125f; s.w *= 0.125f;
  float m2 = ((c0 == 0) ? -s.x * s.x : s.x * s.x) + s.y * s.y + s.z * s.z + s.w * s.w;
#pragma unroll
  for (int off = 1; off < 16; off <<= 1) m2 += __shfl_xor(m2, off, 64);
  float inv = 1.f / sqrtf(fabsf(m2));
  float4 o = make_float4(s.x * inv, s.y * inv, s.z * inv, s.w * inv);
  *(float4*)(out + (size_t)(n0 + i) * 64 + c0) = o;
  if (blockIdx.x == 0 && tid == 0) out[(size_t)NNODES * 64] = ea[0] * (1.0f / 524288.0f);
}

// ---------------- K5: link loss (16 edges/wave, 1024 blocks) ----------------
__global__ __launch_bounds__(256) void k5_ea(const unsigned short* __restrict__ phiq,
                                             const unsigned short* __restrict__ phik,
                                             const int* __restrict__ ei, float* __restrict__ ea) {
  __shared__ float part[4];
  int lane = threadIdx.x & 63, w = threadIdx.x >> 6;
  int wid = blockIdx.x * 4 + w;
  float acc = 0.f;
  for (int i = 0; i < 16; ++i) {
    int e = wid * 16 + i;
    int s = ei[e];
    int d = ei[NEDGES + e];
    const unsigned short* bq = phiq + (size_t)d * 1024;
    const unsigned short* bk = phik + (size_t)s * 1024;
    uint4 qa = *(const uint4*)(bq + lane * 16);
    uint4 qb = *(const uint4*)(bq + lane * 16 + 8);
    uint4 ka = *(const uint4*)(bk + lane * 16);
    uint4 kb = *(const uint4*)(bk + lane * 16 + 8);
    unsigned qs[8] = {qa.x, qa.y, qa.z, qa.w, qb.x, qb.y, qb.z, qb.w};
    unsigned ks[8] = {ka.x, ka.y, ka.z, ka.w, kb.x, kb.y, kb.z, kb.w};
#pragma unroll
    for (int p = 0; p < 8; ++p) {
      float q0 = __uint_as_float(qs[p] << 16);
      float q1 = __uint_as_float(qs[p] & 0xffff0000u);
      float k0 = __uint_as_float(ks[p] << 16);
      float k1 = __uint_as_float(ks[p] & 0xffff0000u);
      acc = fmaf(q0, k0, acc);
      acc = fmaf(q1, k1, acc);
    }
  }
  acc = wave_sum(acc);
  if (lane == 0) part[w] = acc;
  __syncthreads();
  if (threadIdx.x == 0) atomicAdd(ea, part[0] + part[1] + part[2] + part[3]);
}

// ---------------- launch ----------------
extern "C" void kernel_launch(void* const* d_in, const int* in_sizes, int n_in,
                              void* d_out, int out_size, void* d_ws, size_t ws_size,
                              hipStream_t stream) {
  const float* z  = (const float*)d_in[0];
  const float* Wq = (const float*)d_in[1];
  const float* Wk = (const float*)d_in[2];
  const float* Wv = (const float*)d_in[3];
  const float* P  = (const float*)d_in[4];
  const int* ei   = (const int*)d_in[5];
  char* ws = (char*)d_ws;
  unsigned short* Wfrag = (unsigned short*)(ws + OFF_WFRAG);
  unsigned short* lastB = (unsigned short*)(ws + OFF_LASTB);  // sequenced reuse of Wfrag region
  unsigned short* Pfrag = (unsigned short*)(ws + OFF_PFRAG);
  float*          ea    = (float*)(ws + OFF_EA);
  unsigned short* ubf   = (unsigned short*)(ws + OFF_U);
  unsigned short* part  = (unsigned short*)(ws + OFF_PART);
  unsigned short* phiq  = (unsigned short*)(ws + OFF_PHIQ);
  unsigned short* phik  = (unsigned short*)(ws + OFF_PHIK);

  hipMemsetAsync(ea, 0, 4, stream);
  k0_prep<<<96, 256, 0, stream>>>(Wq, Wk, Wv, P, Wfrag, Pfrag);
  k1_u<<<NNODES / 4, 256, 0, stream>>>(z, ubf);
  k2_mfma<<<2048, 256, 0, stream>>>(ubf, Wfrag, Pfrag, phiq, phik, part);
  k3p_pack<<<128, 256, 0, stream>>>((const unsigned*)part, lastB);
  k5_ea<<<NEDGES / 64, 256, 0, stream>>>(phiq, phik, ei, ea);
  k4_mfma<<<NNODES / 32, 512, 0, stream>>>(phiq, lastB, ea, (float*)d_out);
}

// Round 7
// 223.401 us; speedup vs baseline: 4.9862x; 1.0699x over previous
//
#include <hip/hip_runtime.h>

#define DEV __device__ __forceinline__

// ---------------- constants ----------------
// N_NODES=32768, N_EDGES=65536, H=8, D=64, DS=63, M=128, R=H*N=262144
#define NNODES 32768
#define NEDGES 65536
#define NROWS  262144
#define EPSF   1e-7f
#define SQRT2F 1.4142135623730951f
#define LOG2E  1.4426950408889634f
#define LOG2SQRT63 2.9886399611087573f   // log2(sqrt(63))

// ---------------- ws layout (bytes) ----------------
// Sequenced reuse: Wfrag (k0->k2) then lastB (k3p->k4) share offset 0.
#define OFF_WFRAG 0u          // bf16 [3][8][2][4][64][8]  W in MFMA B-frag order (196608 B) [dead after k2]
#define OFF_LASTB 0u          // bf16 [8][4][4][64][8] B-frag of last (131072 B) [written k3p, read k4]
#define OFF_PFRAG 196608u     // bf16 [8][2][64][8]  sqrt(2)*log2e*P, MFMA A-frag order (16384 B)
#define OFF_EA    212992u     // float [1] (zeroed)
#define OFF_U     409600u     // bf16 [N][64] u (4194304 B) [dead after k2]
#define OFF_PART  42352640u   // bf16 [256 c][8 h][64 d][128 m] split-K partials of last (33554432 B)
#define OFF_PHIQ  75907072u   // bf16 [R][128]
#define OFF_PHIK  143015936u  // bf16 [R][128]
// end: 210124800

typedef short s8v __attribute__((ext_vector_type(8)));   // 8 bf16 in 4 VGPRs (MFMA A/B frag)
typedef float f4v __attribute__((ext_vector_type(4)));   // MFMA C/D frag

// ---------------- helpers ----------------
DEV float wave_sum(float v) {
#pragma unroll
  for (int o = 1; o < 64; o <<= 1) v += __shfl_xor(v, o, 64);
  return v;
}
DEV unsigned short f2bf(float f) {  // rne
  unsigned u = __float_as_uint(f);
  return (unsigned short)((u + 0x7fffu + ((u >> 16) & 1u)) >> 16);
}
DEV float bf2f(unsigned short h) { return __uint_as_float(((unsigned)h) << 16); }
// pack two f32 -> two bf16 (round-half-up) in one uint: low short = bf16(lo), high = bf16(hi)
DEV unsigned pack2(float lo, float hi) {
  return __builtin_amdgcn_perm(__float_as_uint(hi) + 0x8000u, __float_as_uint(lo) + 0x8000u, 0x07060302u);
}
DEV float frcp(float x) { return __builtin_amdgcn_rcpf(x); }

// ---------------- K0: pack W (B-frag) and sqrt(2)*log2e*P (A-frag) as bf16 ----------------
__global__ __launch_bounds__(256) void k0_prep(const float* __restrict__ Wq, const float* __restrict__ Wk,
                                               const float* __restrict__ Wv, const float* __restrict__ P,
                                               unsigned short* __restrict__ Wfrag, unsigned short* __restrict__ Pfrag) {
  int tid = blockIdx.x * blockDim.x + threadIdx.x;
  int stride = gridDim.x * blockDim.x;
  // Wfrag[sm][h][ks][nt][lane][j] : B[k][n], n = nt*16+(lane&15), k = ks*32+(lane>>4)*8+j
  for (int i = tid; i < 98304; i += stride) {
    int j = i & 7, lane = (i >> 3) & 63, nt = (i >> 9) & 3, ks = (i >> 11) & 1, h = (i >> 12) & 7, sm = i >> 15;
    int k = ks * 32 + (lane >> 4) * 8 + j;
    int n = nt * 16 + (lane & 15);
    const float* W = (sm == 0) ? Wq : ((sm == 1) ? Wk : Wv);
    Wfrag[i] = f2bf(W[(h * 64 + n) * 64 + k]);
  }
  // Pfrag[mt8][ks2][lane][j] : A[m][k], m = mt*16+(lane&15), k = ks*32+(lane>>4)*8+j ; k=0 zero pad
  for (int i = tid; i < 8192; i += stride) {
    int j = i & 7, lane = (i >> 3) & 63, ks = (i >> 9) & 1, mt = (i >> 10) & 7;
    int k = ks * 32 + (lane >> 4) * 8 + j;
    int m = mt * 16 + (lane & 15);
    Pfrag[i] = (k == 0) ? (unsigned short)0 : f2bf(P[(k - 1) * 128 + m] * (SQRT2F * LOG2E));
  }
}

// ---------------- K1: u = logmap0(proj(expmap0(z))) == [0, z[1:]] identically -> bf16 cast ----------------
// acosh(max(cosh t,1+eps)) = t for t >= ~4.7e-4; here t = ||z[1:]|| ~ 0.08, so u = z with u[0]=0.
__global__ __launch_bounds__(256) void k1_cast(const float* __restrict__ z, unsigned short* __restrict__ ubf) {
  int i = blockIdx.x * 256 + threadIdx.x;  // 524288 float4 groups
  float4 v = *(const float4*)(z + (size_t)i * 4);
  if ((i & 15) == 0) v.x = 0.f;  // time slot
  uint2 pk;
  pk.x = pack2(v.x, v.y);
  pk.y = pack2(v.z, v.w);
  *(uint2*)(ubf + (size_t)i * 4) = pk;
}

// ---------------- K2: fused mu -> (q,k,v) -> phi_q, phi_k ; + last partial (phik^T @ V) ----------------
// Block = 256 thr (4 waves), block (h, t) owns 128 nodes. LDS (51200 B total -> 3 blocks/CU):
//   pre-barrier:  sbuf [2][4][32*72] bf16 (36864 B) + sfront (1024 B)
//   post-barrier: kbufT [128 m][132] bf16 (33792 B) + vbufT [64 d][136] bf16 (17408 B)  [alias]
// V is held in packed-bf16 registers (vkeep) across phase 2 so vbufT can alias dead sbuf.
__global__ __launch_bounds__(256) void k2_mfma(const unsigned short* __restrict__ ubf,
                                               const unsigned short* __restrict__ Wfrag,
                                               const unsigned short* __restrict__ Pfrag,
                                               unsigned short* __restrict__ phiq, unsigned short* __restrict__ phik,
                                               unsigned short* __restrict__ part) {
  __shared__ short lds_raw[25600];             // 51200 B
  short* sbuf = lds_raw;                       // [(sm*4+w)*2304 + row*72 + col]
  float* sfront = (float*)(lds_raw + 18432);   // [(sm*4+w)*32 + row]
  short* kbufT = lds_raw;                      // post-barrier alias: [m*132 + node]
  short* vbufT = lds_raw + 16896;              // post-barrier alias: [d*136 + node]

  int w = threadIdx.x >> 6, lane = threadIdx.x & 63;
  int q = lane >> 4, l = lane & 15;
  int b = blockIdx.x;
  int h = b >> 8, t = b & 255;
  int n0 = t * 128 + w * 32;
  int r0 = h * 32768 + n0;

  // A-fragments of u (bf16 direct loads)
  s8v afr[2][2];
#pragma unroll
  for (int mt = 0; mt < 2; ++mt)
#pragma unroll
    for (int ks = 0; ks < 2; ++ks)
      afr[mt][ks] = *(const s8v*)(ubf + (size_t)(n0 + mt * 16 + l) * 64 + ks * 32 + q * 8);

  const s8v* Wf = (const s8v*)Wfrag;
  const s8v* Pf = (const s8v*)Pfrag;
  uint2 vkeep[2][4];  // packed V rows: [mt][nt], pairs along node (reg) axis

  // ---- Phase 1: three mu GEMMs + row nonlinearity; V -> vkeep regs ----
#pragma unroll
  for (int sm = 0; sm < 3; ++sm) {
    f4v acc[2][4];
#pragma unroll
    for (int mt = 0; mt < 2; ++mt)
#pragma unroll
      for (int nt = 0; nt < 4; ++nt) acc[mt][nt] = (f4v)(0.f);
#pragma unroll
    for (int ks = 0; ks < 2; ++ks)
#pragma unroll
      for (int nt = 0; nt < 4; ++nt) {
        s8v bf = Wf[(((sm * 8 + h) * 2 + ks) * 4 + nt) * 64 + lane];
#pragma unroll
        for (int mt = 0; mt < 2; ++mt)
          acc[mt][nt] = __builtin_amdgcn_mfma_f32_16x16x32_bf16(afr[mt][ks], bf, acc[mt][nt], 0, 0, 0);
      }
#pragma unroll
    for (int mt = 0; mt < 2; ++mt) {
      float rs[4];
#pragma unroll
      for (int reg = 0; reg < 4; ++reg) {
        float v0 = (l == 0) ? 0.f : acc[mt][0][reg];
        rs[reg] = v0 * v0 + acc[mt][1][reg] * acc[mt][1][reg] + acc[mt][2][reg] * acc[mt][2][reg] +
                  acc[mt][3][reg] * acc[mt][3][reg];
      }
#pragma unroll
      for (int reg = 0; reg < 4; ++reg) {
#pragma unroll
        for (int off = 1; off < 16; off <<= 1) rs[reg] += __shfl_xor(rs[reg], off, 64);
      }
      float vreg[4][4];  // [nt][reg], sm==2 only
#pragma unroll
      for (int reg = 0; reg < 4; ++reg) {
        float x = fmaxf(sqrtf(rs[reg]), EPSF);
        float e = exp2f(x * LOG2E);
        float sh = 0.5f * (e - frcp(e));
        float ratio = sh * frcp(x);
        float sh2 = sh * sh;
        int row = mt * 16 + q * 4 + reg;
        if (sm == 2) {
          float tt2 = sqrtf(1.f + sh2);
#pragma unroll
          for (int nt = 0; nt < 4; ++nt) {
            float val = acc[mt][nt][reg] * ratio;
            if (l == 0 && nt == 0) val = tt2;  // time component (d=0)
            vreg[nt][reg] = val;
          }
        } else {
          float lf = -sh2 * LOG2E - LOG2SQRT63;
          if (l == 0) sfront[(sm * 4 + w) * 32 + row] = lf;
#pragma unroll
          for (int nt = 0; nt < 4; ++nt) {
            float val = acc[mt][nt][reg] * ratio;
            if (l == 0 && nt == 0) val = 0.f;
            sbuf[(sm * 4 + w) * 2304 + row * 72 + nt * 16 + l] = (short)(__float_as_uint(val) >> 16);
          }
        }
      }
      if (sm == 2) {
#pragma unroll
        for (int nt = 0; nt < 4; ++nt) {
          vkeep[mt][nt].x = pack2(vreg[nt][0], vreg[nt][1]);
          vkeep[mt][nt].y = pack2(vreg[nt][2], vreg[nt][3]);
        }
      }
    }
  }

  // ---- Phase 2: phi^T GEMM ; phi = exp2(acc + lf) -> global ; keep phik regs ----
  uint2 keep0[8], keep1[8];
#pragma unroll
  for (int sm = 0; sm < 2; ++sm) {
    s8v bsf[2][2];  // [nt2][ks] : B[k=c][n=node]
#pragma unroll
    for (int nt = 0; nt < 2; ++nt)
#pragma unroll
      for (int ks = 0; ks < 2; ++ks)
        bsf[nt][ks] = *(const s8v*)&sbuf[(sm * 4 + w) * 2304 + (nt * 16 + l) * 72 + ks * 32 + q * 8];
    float lf0 = sfront[(sm * 4 + w) * 32 + l];
    float lf1 = sfront[(sm * 4 + w) * 32 + 16 + l];
    unsigned short* dst = sm ? phik : phiq;
#pragma unroll
    for (int mt = 0; mt < 8; ++mt) {
      f4v a0 = (f4v)(0.f), a1 = (f4v)(0.f);
#pragma unroll
      for (int ks = 0; ks < 2; ++ks) {
        s8v ap = Pf[(mt * 2 + ks) * 64 + lane];
        a0 = __builtin_amdgcn_mfma_f32_16x16x32_bf16(ap, bsf[0][ks], a0, 0, 0, 0);
        a1 = __builtin_amdgcn_mfma_f32_16x16x32_bf16(ap, bsf[1][ks], a1, 0, 0, 0);
      }
      float v00 = exp2f(a0[0] + lf0), v01 = exp2f(a0[1] + lf0), v02 = exp2f(a0[2] + lf0), v03 = exp2f(a0[3] + lf0);
      float v10 = exp2f(a1[0] + lf1), v11 = exp2f(a1[1] + lf1), v12 = exp2f(a1[2] + lf1), v13 = exp2f(a1[3] + lf1);
      uint2 p0, p1;
      p0.x = pack2(v00, v01); p0.y = pack2(v02, v03);
      p1.x = pack2(v10, v11); p1.y = pack2(v12, v13);
      *(uint2*)(dst + (size_t)(r0 + l) * 128 + mt * 16 + q * 4) = p0;
      *(uint2*)(dst + (size_t)(r0 + 16 + l) * 128 + mt * 16 + q * 4) = p1;
      if (sm == 1) { keep0[mt] = p0; keep1[mt] = p1; }
    }
  }

  __syncthreads();  // sbuf + sfront fully consumed -> safe to alias as kbufT/vbufT

  // scatter phik into kbufT[m][node] (stride 132); write vbufT[d][node] (stride 136) from vkeep
  {
    int nd0 = w * 32 + l, nd1 = nd0 + 16;
#pragma unroll
    for (int mt = 0; mt < 8; ++mt) {
      int m = mt * 16 + q * 4;
      kbufT[(m + 0) * 132 + nd0] = (short)(keep0[mt].x & 0xffffu);
      kbufT[(m + 1) * 132 + nd0] = (short)(keep0[mt].x >> 16);
      kbufT[(m + 2) * 132 + nd0] = (short)(keep0[mt].y & 0xffffu);
      kbufT[(m + 3) * 132 + nd0] = (short)(keep0[mt].y >> 16);
      kbufT[(m + 0) * 132 + nd1] = (short)(keep1[mt].x & 0xffffu);
      kbufT[(m + 1) * 132 + nd1] = (short)(keep1[mt].x >> 16);
      kbufT[(m + 2) * 132 + nd1] = (short)(keep1[mt].y & 0xffffu);
      kbufT[(m + 3) * 132 + nd1] = (short)(keep1[mt].y >> 16);
    }
#pragma unroll
    for (int mt = 0; mt < 2; ++mt)
#pragma unroll
      for (int nt = 0; nt < 4; ++nt)
        *(uint2*)&vbufT[(nt * 16 + l) * 136 + w * 32 + mt * 16 + q * 4] = vkeep[mt][nt];
  }
  __syncthreads();  // kbufT + vbufT ready

  // ---- Fused GEMM: D[m][d] = sum_node kbufT[m][node] * vbufT[d][node], m-slice per wave ----
  f4v facc[2][4];
#pragma unroll
  for (int mtl = 0; mtl < 2; ++mtl)
#pragma unroll
    for (int nt = 0; nt < 4; ++nt) facc[mtl][nt] = (f4v)(0.f);
#pragma unroll
  for (int kc = 0; kc < 4; ++kc) {
    s8v bv[4];
#pragma unroll
    for (int nt = 0; nt < 4; ++nt)
      bv[nt] = *(const s8v*)&vbufT[(nt * 16 + l) * 136 + kc * 32 + q * 8];
    s8v av[2];
#pragma unroll
    for (int mtl = 0; mtl < 2; ++mtl) {
      const short* kb = &kbufT[((2 * w + mtl) * 16 + l) * 132 + kc * 32 + q * 8];
      union { s8v v; long long L[2]; } ua;
      ua.L[0] = *(const long long*)kb;
      ua.L[1] = *(const long long*)(kb + 4);
      av[mtl] = ua.v;
    }
#pragma unroll
    for (int mtl = 0; mtl < 2; ++mtl)
#pragma unroll
      for (int nt = 0; nt < 4; ++nt)
        facc[mtl][nt] = __builtin_amdgcn_mfma_f32_16x16x32_bf16(av[mtl], bv[nt], facc[mtl][nt], 0, 0, 0);
  }
  // store part[t][h][d][m] bf16, m-contiguous 8B stores
#pragma unroll
  for (int mtl = 0; mtl < 2; ++mtl)
#pragma unroll
    for (int nt = 0; nt < 4; ++nt) {
      uint2 pk;
      pk.x = pack2(facc[mtl][nt][0], facc[mtl][nt][1]);
      pk.y = pack2(facc[mtl][nt][2], facc[mtl][nt][3]);
      int d = nt * 16 + l;
      int m = (2 * w + mtl) * 16 + q * 4;
      *(uint2*)(part + ((size_t)((t * 8 + h) * 64 + d)) * 128 + m) = pk;
    }
}

// ---------------- K3p: reduce 256 bf16 partials -> lastB (bf16 B-frag order) ----------------
__global__ __launch_bounds__(256) void k3p_pack(const unsigned* __restrict__ part32, unsigned short* __restrict__ lastB) {
  int t2 = blockIdx.x * 256 + threadIdx.x;  // 32768 = h*4096 + d*64 + m/2
  float s0 = 0.f, s1 = 0.f;
#pragma unroll 8
  for (int c = 0; c < 256; ++c) {
    unsigned v = part32[((size_t)c << 12) + t2];
    s0 += __uint_as_float(v << 16);
    s1 += __uint_as_float(v & 0xffff0000u);
  }
  int m = (t2 & 63) * 2, d = (t2 >> 6) & 63, h = t2 >> 12;
  int ks = m >> 5, j = m & 7, qq = (m >> 3) & 3;
  int lane = qq * 16 + (d & 15), nt = d >> 4;
  unsigned short* dst = &lastB[((((h * 4 + ks) * 4 + nt) * 64 + lane) << 3) + j];
  dst[0] = f2bf(s0);
  dst[1] = f2bf(s1);
}

// ---------------- K4: MFMA zo = phiq @ last[h'] ; row-norm; 8-head mean; final normalize ----------------
// zbufT[w][d][i2] = packed bf16 pair (rows 2*i2, 2*i2+1) of normalized zo. 36864 B -> 4 blocks/CU.
__global__ __launch_bounds__(512) void k4_mfma(const unsigned short* __restrict__ phiq,
                                               const unsigned short* __restrict__ lastB,
                                               const float* __restrict__ ea, float* __restrict__ out) {
  __shared__ unsigned zbufT[8][64][18];
  int w = threadIdx.x >> 6, lane = threadIdx.x & 63;
  int q = lane >> 4, l = lane & 15;
  int n0 = blockIdx.x * 32;

  const s8v* Bf = (const s8v*)lastB;
  s8v bf[4][4];
#pragma unroll
  for (int ks = 0; ks < 4; ++ks)
#pragma unroll
    for (int nt = 0; nt < 4; ++nt) bf[ks][nt] = Bf[((w * 4 + ks) * 4 + nt) * 64 + lane];

  s8v af[2][4];
#pragma unroll
  for (int mt = 0; mt < 2; ++mt)
#pragma unroll
    for (int ks = 0; ks < 4; ++ks)
      af[mt][ks] = *(const s8v*)(phiq + (size_t)(8 * (n0 + mt * 16 + l) + w) * 128 + ks * 32 + q * 8);

  f4v acc[2][4];
#pragma unroll
  for (int mt = 0; mt < 2; ++mt)
#pragma unroll
    for (int nt = 0; nt < 4; ++nt) acc[mt][nt] = (f4v)(0.f);
#pragma unroll
  for (int ks = 0; ks < 4; ++ks)
#pragma unroll
    for (int nt = 0; nt < 4; ++nt)
#pragma unroll
      for (int mt = 0; mt < 2; ++mt)
        acc[mt][nt] = __builtin_amdgcn_mfma_f32_16x16x32_bf16(af[mt][ks], bf[ks][nt], acc[mt][nt], 0, 0, 0);

#pragma unroll
  for (int mt = 0; mt < 2; ++mt) {
    float rs[4];
#pragma unroll
    for (int reg = 0; reg < 4; ++reg) {
      float v0 = acc[mt][0][reg];
      float s0 = (l == 0) ? -v0 * v0 : v0 * v0;
      rs[reg] = s0 + acc[mt][1][reg] * acc[mt][1][reg] + acc[mt][2][reg] * acc[mt][2][reg] +
                acc[mt][3][reg] * acc[mt][3][reg];
    }
#pragma unroll
    for (int reg = 0; reg < 4; ++reg) {
#pragma unroll
      for (int off = 1; off < 16; off <<= 1) rs[reg] += __shfl_xor(rs[reg], off, 64);
    }
    float inv[4];
#pragma unroll
    for (int reg = 0; reg < 4; ++reg) inv[reg] = 1.f / sqrtf(fabsf(rs[reg]));
#pragma unroll
    for (int nt = 0; nt < 4; ++nt) {
      uint2 pk;
      pk.x = pack2(acc[mt][nt][0] * inv[0], acc[mt][nt][1] * inv[1]);
      pk.y = pack2(acc[mt][nt][2] * inv[2], acc[mt][nt][3] * inv[3]);
      *(uint2*)&zbufT[w][nt * 16 + l][mt * 8 + q * 2] = pk;
    }
  }
  __syncthreads();

  int tid = threadIdx.x;
  int i = tid >> 4, dg = tid & 15;  // row i 0..31, d-group dg*4..+3
  int i2 = i >> 1, sel = i & 1;
  float s[4] = {0.f, 0.f, 0.f, 0.f};
#pragma unroll
  for (int w2 = 0; w2 < 8; ++w2) {
#pragma unroll
    for (int j = 0; j < 4; ++j) {
      unsigned u = zbufT[w2][dg * 4 + j][i2];
      s[j] += bf2f((unsigned short)(sel ? (u >> 16) : (u & 0xffffu)));
    }
  }
  float m2 = 0.f;
#pragma unroll
  for (int j = 0; j < 4; ++j) {
    s[j] *= 0.125f;
    m2 += ((dg == 0 && j == 0) ? -s[j] * s[j] : s[j] * s[j]);
  }
#pragma unroll
  for (int off = 1; off < 16; off <<= 1) m2 += __shfl_xor(m2, off, 64);
  float inv = 1.f / sqrtf(fabsf(m2));
  float4 o = make_float4(s[0] * inv, s[1] * inv, s[2] * inv, s[3] * inv);
  *(float4*)(out + (size_t)(n0 + i) * 64 + dg * 4) = o;
  if (blockIdx.x == 0 && tid == 0) out[(size_t)NNODES * 64] = ea[0] * (1.0f / 524288.0f);
}

// ---------------- K5: link loss (16 edges/wave, 1024 blocks) ----------------
__global__ __launch_bounds__(256) void k5_ea(const unsigned short* __restrict__ phiq,
                                             const unsigned short* __restrict__ phik,
                                             const int* __restrict__ ei, float* __restrict__ ea) {
  __shared__ float part[4];
  int lane = threadIdx.x & 63, w = threadIdx.x >> 6;
  int wid = blockIdx.x * 4 + w;
  float acc = 0.f;
  for (int i = 0; i < 16; ++i) {
    int e = wid * 16 + i;
    int s = ei[e];
    int d = ei[NEDGES + e];
    const unsigned short* bq = phiq + (size_t)d * 1024;
    const unsigned short* bk = phik + (size_t)s * 1024;
    uint4 qa = *(const uint4*)(bq + lane * 16);
    uint4 qb = *(const uint4*)(bq + lane * 16 + 8);
    uint4 ka = *(const uint4*)(bk + lane * 16);
    uint4 kb = *(const uint4*)(bk + lane * 16 + 8);
    unsigned qs[8] = {qa.x, qa.y, qa.z, qa.w, qb.x, qb.y, qb.z, qb.w};
    unsigned ks[8] = {ka.x, ka.y, ka.z, ka.w, kb.x, kb.y, kb.z, kb.w};
#pragma unroll
    for (int p = 0; p < 8; ++p) {
      float q0 = __uint_as_float(qs[p] << 16);
      float q1 = __uint_as_float(qs[p] & 0xffff0000u);
      float k0 = __uint_as_float(ks[p] << 16);
      float k1 = __uint_as_float(ks[p] & 0xffff0000u);
      acc = fmaf(q0, k0, acc);
      acc = fmaf(q1, k1, acc);
    }
  }
  acc = wave_sum(acc);
  if (lane == 0) part[w] = acc;
  __syncthreads();
  if (threadIdx.x == 0) atomicAdd(ea, part[0] + part[1] + part[2] + part[3]);
}

// ---------------- launch ----------------
extern "C" void kernel_launch(void* const* d_in, const int* in_sizes, int n_in,
                              void* d_out, int out_size, void* d_ws, size_t ws_size,
                              hipStream_t stream) {
  const float* z  = (const float*)d_in[0];
  const float* Wq = (const float*)d_in[1];
  const float* Wk = (const float*)d_in[2];
  const float* Wv = (const float*)d_in[3];
  const float* P  = (const float*)d_in[4];
  const int* ei   = (const int*)d_in[5];
  char* ws = (char*)d_ws;
  unsigned short* Wfrag = (unsigned short*)(ws + OFF_WFRAG);
  unsigned short* lastB = (unsigned short*)(ws + OFF_LASTB);  // sequenced reuse of Wfrag region
  unsigned short* Pfrag = (unsigned short*)(ws + OFF_PFRAG);
  float*          ea    = (float*)(ws + OFF_EA);
  unsigned short* ubf   = (unsigned short*)(ws + OFF_U);
  unsigned short* part  = (unsigned short*)(ws + OFF_PART);
  unsigned short* phiq  = (unsigned short*)(ws + OFF_PHIQ);
  unsigned short* phik  = (unsigned short*)(ws + OFF_PHIK);

  hipMemsetAsync(ea, 0, 4, stream);
  k0_prep<<<96, 256, 0, stream>>>(Wq, Wk, Wv, P, Wfrag, Pfrag);
  k1_cast<<<2048, 256, 0, stream>>>(z, ubf);
  k2_mfma<<<2048, 256, 0, stream>>>(ubf, Wfrag, Pfrag, phiq, phik, part);
  k3p_pack<<<128, 256, 0, stream>>>((const unsigned*)part, lastB);
  k5_ea<<<NEDGES / 64, 256, 0, stream>>>(phiq, phik, ei, ea);
  k4_mfma<<<NNODES / 32, 512, 0, stream>>>(phiq, lastB, ea, (float*)d_out);
}

// Round 8
// 218.531 us; speedup vs baseline: 5.0973x; 1.0223x over previous
//
#include <hip/hip_runtime.h>

#define DEV __device__ __forceinline__

// ---------------- constants ----------------
// N_NODES=32768, N_EDGES=65536, H=8, D=64, DS=63, M=128, R=H*N=262144
#define NNODES 32768
#define NEDGES 65536
#define NROWS  262144
#define EPSF   1e-7f
#define SQRT2F 1.4142135623730951f
#define LOG2E  1.4426950408889634f
#define LOG2SQRT63 2.9886399611087573f   // log2(sqrt(63))

// ---------------- ws layout (bytes) ----------------
// Sequenced reuse: Wfrag (k01->k2) then lastB (k3p->k4) share offset 0.
#define OFF_WFRAG 0u          // bf16 [3][8][2][4][64][8]  W in MFMA B-frag order (196608 B) [dead after k2]
#define OFF_LASTB 0u          // bf16 [8][4][4][64][8] B-frag of last (131072 B) [written k3p, read k4]
#define OFF_PFRAG 196608u     // bf16 [8][2][64][8]  sqrt(2)*log2e*P, MFMA A-frag order (16384 B)
#define OFF_EA    212992u     // float [1] (zeroed by k01)
#define OFF_U     409600u     // bf16 [N][64] u (4194304 B) [dead after k2]
#define OFF_PART  42352640u   // bf16 [256 c][8 h][64 d][128 m] split-K partials of last (33554432 B)
#define OFF_PHIQ  75907072u   // bf16 [R][128]
#define OFF_PHIK  143015936u  // bf16 [R][128]
// end: 210124800

typedef short s8v __attribute__((ext_vector_type(8)));   // 8 bf16 in 4 VGPRs (MFMA A/B frag)
typedef float f4v __attribute__((ext_vector_type(4)));   // MFMA C/D frag

// ---------------- helpers ----------------
DEV unsigned short f2bf(float f) {  // rne
  unsigned u = __float_as_uint(f);
  return (unsigned short)((u + 0x7fffu + ((u >> 16) & 1u)) >> 16);
}
DEV float bf2f(unsigned short h) { return __uint_as_float(((unsigned)h) << 16); }
// pack two f32 -> two bf16 (round-half-up) in one uint: low short = bf16(lo), high = bf16(hi)
DEV unsigned pack2(float lo, float hi) {
  return __builtin_amdgcn_perm(__float_as_uint(hi) + 0x8000u, __float_as_uint(lo) + 0x8000u, 0x07060302u);
}
DEV float frcp(float x) { return __builtin_amdgcn_rcpf(x); }

// ---------------- K01: u cast (+ blocks<96: pack W/P frags; block0: zero ea) ----------------
// u = logmap0(proj(expmap0(z))) == [0, z[1:]] identically (acosh(cosh t)=t for t~0.08).
__global__ __launch_bounds__(256) void k01_prep(const float* __restrict__ z, unsigned short* __restrict__ ubf,
                                                const float* __restrict__ Wq, const float* __restrict__ Wk,
                                                const float* __restrict__ Wv, const float* __restrict__ P,
                                                unsigned short* __restrict__ Wfrag, unsigned short* __restrict__ Pfrag,
                                                float* __restrict__ ea) {
  int i = blockIdx.x * 256 + threadIdx.x;  // 524288 float4 groups
  float4 v = *(const float4*)(z + (size_t)i * 4);
  if ((i & 15) == 0) v.x = 0.f;  // time slot
  uint2 pk;
  pk.x = pack2(v.x, v.y);
  pk.y = pack2(v.z, v.w);
  *(uint2*)(ubf + (size_t)i * 4) = pk;

  if (blockIdx.x < 96) {
    if (i == 0) ea[0] = 0.f;
    int stride = 96 * 256;
    // Wfrag[sm][h][ks][nt][lane][j] : B[k][n], n = nt*16+(lane&15), k = ks*32+(lane>>4)*8+j
    for (int t = i; t < 98304; t += stride) {
      int j = t & 7, lane = (t >> 3) & 63, nt = (t >> 9) & 3, ks = (t >> 11) & 1, h = (t >> 12) & 7, sm = t >> 15;
      int k = ks * 32 + (lane >> 4) * 8 + j;
      int n = nt * 16 + (lane & 15);
      const float* W = (sm == 0) ? Wq : ((sm == 1) ? Wk : Wv);
      Wfrag[t] = f2bf(W[(h * 64 + n) * 64 + k]);
    }
    // Pfrag[mt8][ks2][lane][j] : A[m][k], m = mt*16+(lane&15), k = ks*32+(lane>>4)*8+j ; k=0 zero pad
    for (int t = i; t < 8192; t += stride) {
      int j = t & 7, lane = (t >> 3) & 63, ks = (t >> 9) & 1, mt = (t >> 10) & 7;
      int k = ks * 32 + (lane >> 4) * 8 + j;
      int m = mt * 16 + (lane & 15);
      Pfrag[t] = (k == 0) ? (unsigned short)0 : f2bf(P[(k - 1) * 128 + m] * (SQRT2F * LOG2E));
    }
  }
}

// ---------------- K2: fused mu -> (q,k,v) -> phi_q, phi_k ; + last partial (phik^T @ V) ----------------
// Block = 256 thr (4 waves), block (h, t) owns 128 nodes. LDS 37888 B -> 4 blocks/CU:
//   pre-barrier:  sbuf [2][4][32*72] bf16 (36864 B) + sfront (1024 B)
//   post-barrier: kbufT [128 m][68] bf16 (17408 B) + vbufT [64 d][72] bf16 (9216 B)  [alias, per 64-node half]
// Fused GEMM runs in two 64-node halves; V held in packed regs (vkeep), phik in keep0/keep1.
__global__ __launch_bounds__(256) void k2_mfma(const unsigned short* __restrict__ ubf,
                                               const unsigned short* __restrict__ Wfrag,
                                               const unsigned short* __restrict__ Pfrag,
                                               unsigned short* __restrict__ phiq, unsigned short* __restrict__ phik,
                                               unsigned short* __restrict__ part) {
  __shared__ short lds_raw[18944];             // 37888 B
  short* sbuf = lds_raw;                       // [(sm*4+w)*2304 + row*72 + col]
  float* sfront = (float*)(lds_raw + 18432);   // [(sm*4+w)*32 + row]
  short* kbufT = lds_raw;                      // post-barrier alias: [m*68 + nloc]
  short* vbufT = lds_raw + 8704;               // post-barrier alias: [d*72 + nloc]

  int w = threadIdx.x >> 6, lane = threadIdx.x & 63;
  int q = lane >> 4, l = lane & 15;
  int b = blockIdx.x;
  int h = b >> 8, t = b & 255;
  int n0 = t * 128 + w * 32;
  int r0 = h * 32768 + n0;

  // A-fragments of u (bf16 direct loads)
  s8v afr[2][2];
#pragma unroll
  for (int mt = 0; mt < 2; ++mt)
#pragma unroll
    for (int ks = 0; ks < 2; ++ks)
      afr[mt][ks] = *(const s8v*)(ubf + (size_t)(n0 + mt * 16 + l) * 64 + ks * 32 + q * 8);

  const s8v* Wf = (const s8v*)Wfrag;
  const s8v* Pf = (const s8v*)Pfrag;
  uint2 vkeep[2][4];  // packed V rows: [mt][nt], pairs along node (reg) axis

  // ---- Phase 1: three mu GEMMs + row nonlinearity; V -> vkeep regs ----
#pragma unroll
  for (int sm = 0; sm < 3; ++sm) {
    f4v acc[2][4];
#pragma unroll
    for (int mt = 0; mt < 2; ++mt)
#pragma unroll
      for (int nt = 0; nt < 4; ++nt) acc[mt][nt] = (f4v)(0.f);
#pragma unroll
    for (int ks = 0; ks < 2; ++ks)
#pragma unroll
      for (int nt = 0; nt < 4; ++nt) {
        s8v bf = Wf[(((sm * 8 + h) * 2 + ks) * 4 + nt) * 64 + lane];
#pragma unroll
        for (int mt = 0; mt < 2; ++mt)
          acc[mt][nt] = __builtin_amdgcn_mfma_f32_16x16x32_bf16(afr[mt][ks], bf, acc[mt][nt], 0, 0, 0);
      }
#pragma unroll
    for (int mt = 0; mt < 2; ++mt) {
      float rs[4];
#pragma unroll
      for (int reg = 0; reg < 4; ++reg) {
        float v0 = (l == 0) ? 0.f : acc[mt][0][reg];
        rs[reg] = v0 * v0 + acc[mt][1][reg] * acc[mt][1][reg] + acc[mt][2][reg] * acc[mt][2][reg] +
                  acc[mt][3][reg] * acc[mt][3][reg];
      }
#pragma unroll
      for (int reg = 0; reg < 4; ++reg) {
#pragma unroll
        for (int off = 1; off < 16; off <<= 1) rs[reg] += __shfl_xor(rs[reg], off, 64);
      }
      float vreg[4][4];  // [nt][reg], sm==2 only
#pragma unroll
      for (int reg = 0; reg < 4; ++reg) {
        float x = fmaxf(sqrtf(rs[reg]), EPSF);
        float e = exp2f(x * LOG2E);
        float sh = 0.5f * (e - frcp(e));
        float ratio = sh * frcp(x);
        float sh2 = sh * sh;
        int row = mt * 16 + q * 4 + reg;
        if (sm == 2) {
          float tt2 = sqrtf(1.f + sh2);
#pragma unroll
          for (int nt = 0; nt < 4; ++nt) {
            float val = acc[mt][nt][reg] * ratio;
            if (l == 0 && nt == 0) val = tt2;  // time component (d=0)
            vreg[nt][reg] = val;
          }
        } else {
          float lf = -sh2 * LOG2E - LOG2SQRT63;
          if (l == 0) sfront[(sm * 4 + w) * 32 + row] = lf;
#pragma unroll
          for (int nt = 0; nt < 4; ++nt) {
            float val = acc[mt][nt][reg] * ratio;
            if (l == 0 && nt == 0) val = 0.f;
            sbuf[(sm * 4 + w) * 2304 + row * 72 + nt * 16 + l] = (short)(__float_as_uint(val) >> 16);
          }
        }
      }
      if (sm == 2) {
#pragma unroll
        for (int nt = 0; nt < 4; ++nt) {
          vkeep[mt][nt].x = pack2(vreg[nt][0], vreg[nt][1]);
          vkeep[mt][nt].y = pack2(vreg[nt][2], vreg[nt][3]);
        }
      }
    }
  }

  // ---- Phase 2: phi^T GEMM ; phi = exp2(acc + lf) -> global ; keep phik regs ----
  uint2 keep0[8], keep1[8];
#pragma unroll
  for (int sm = 0; sm < 2; ++sm) {
    s8v bsf[2][2];  // [nt2][ks] : B[k=c][n=node]
#pragma unroll
    for (int nt = 0; nt < 2; ++nt)
#pragma unroll
      for (int ks = 0; ks < 2; ++ks)
        bsf[nt][ks] = *(const s8v*)&sbuf[(sm * 4 + w) * 2304 + (nt * 16 + l) * 72 + ks * 32 + q * 8];
    float lf0 = sfront[(sm * 4 + w) * 32 + l];
    float lf1 = sfront[(sm * 4 + w) * 32 + 16 + l];
    unsigned short* dst = sm ? phik : phiq;
#pragma unroll
    for (int mt = 0; mt < 8; ++mt) {
      f4v a0 = (f4v)(0.f), a1 = (f4v)(0.f);
#pragma unroll
      for (int ks = 0; ks < 2; ++ks) {
        s8v ap = Pf[(mt * 2 + ks) * 64 + lane];
        a0 = __builtin_amdgcn_mfma_f32_16x16x32_bf16(ap, bsf[0][ks], a0, 0, 0, 0);
        a1 = __builtin_amdgcn_mfma_f32_16x16x32_bf16(ap, bsf[1][ks], a1, 0, 0, 0);
      }
      float v00 = exp2f(a0[0] + lf0), v01 = exp2f(a0[1] + lf0), v02 = exp2f(a0[2] + lf0), v03 = exp2f(a0[3] + lf0);
      float v10 = exp2f(a1[0] + lf1), v11 = exp2f(a1[1] + lf1), v12 = exp2f(a1[2] + lf1), v13 = exp2f(a1[3] + lf1);
      uint2 p0, p1;
      p0.x = pack2(v00, v01); p0.y = pack2(v02, v03);
      p1.x = pack2(v10, v11); p1.y = pack2(v12, v13);
      *(uint2*)(dst + (size_t)(r0 + l) * 128 + mt * 16 + q * 4) = p0;
      *(uint2*)(dst + (size_t)(r0 + 16 + l) * 128 + mt * 16 + q * 4) = p1;
      if (sm == 1) { keep0[mt] = p0; keep1[mt] = p1; }
    }
  }

  // ---- Fused GEMM over two 64-node halves: D[m][d] = sum_node phik[node][m] * V[node][d] ----
  f4v facc[2][4];
#pragma unroll
  for (int mtl = 0; mtl < 2; ++mtl)
#pragma unroll
    for (int nt = 0; nt < 4; ++nt) facc[mtl][nt] = (f4v)(0.f);

#pragma unroll
  for (int hf = 0; hf < 2; ++hf) {
    __syncthreads();  // previous contents (sbuf / prior half) fully consumed
    if ((w >> 1) == hf) {
      int nd0 = (w & 1) * 32 + l, nd1 = nd0 + 16;
#pragma unroll
      for (int mt = 0; mt < 8; ++mt) {
        int m = mt * 16 + q * 4;
        kbufT[(m + 0) * 68 + nd0] = (short)(keep0[mt].x & 0xffffu);
        kbufT[(m + 1) * 68 + nd0] = (short)(keep0[mt].x >> 16);
        kbufT[(m + 2) * 68 + nd0] = (short)(keep0[mt].y & 0xffffu);
        kbufT[(m + 3) * 68 + nd0] = (short)(keep0[mt].y >> 16);
        kbufT[(m + 0) * 68 + nd1] = (short)(keep1[mt].x & 0xffffu);
        kbufT[(m + 1) * 68 + nd1] = (short)(keep1[mt].x >> 16);
        kbufT[(m + 2) * 68 + nd1] = (short)(keep1[mt].y & 0xffffu);
        kbufT[(m + 3) * 68 + nd1] = (short)(keep1[mt].y >> 16);
      }
#pragma unroll
      for (int mt = 0; mt < 2; ++mt)
#pragma unroll
        for (int nt = 0; nt < 4; ++nt)
          *(uint2*)&vbufT[(nt * 16 + l) * 72 + (w & 1) * 32 + mt * 16 + q * 4] = vkeep[mt][nt];
    }
    __syncthreads();  // half ready
#pragma unroll
    for (int kc = 0; kc < 2; ++kc) {
      s8v bv[4];
#pragma unroll
      for (int nt = 0; nt < 4; ++nt)
        bv[nt] = *(const s8v*)&vbufT[(nt * 16 + l) * 72 + kc * 32 + q * 8];
      s8v av[2];
#pragma unroll
      for (int mtl = 0; mtl < 2; ++mtl) {
        const short* kb = &kbufT[((2 * w + mtl) * 16 + l) * 68 + kc * 32 + q * 8];
        union { s8v v; long long L[2]; } ua;
        ua.L[0] = *(const long long*)kb;
        ua.L[1] = *(const long long*)(kb + 4);
        av[mtl] = ua.v;
      }
#pragma unroll
      for (int mtl = 0; mtl < 2; ++mtl)
#pragma unroll
        for (int nt = 0; nt < 4; ++nt)
          facc[mtl][nt] = __builtin_amdgcn_mfma_f32_16x16x32_bf16(av[mtl], bv[nt], facc[mtl][nt], 0, 0, 0);
    }
  }

  // store part[t][h][d][m] bf16, m-contiguous 8B stores
#pragma unroll
  for (int mtl = 0; mtl < 2; ++mtl)
#pragma unroll
    for (int nt = 0; nt < 4; ++nt) {
      uint2 pk;
      pk.x = pack2(facc[mtl][nt][0], facc[mtl][nt][1]);
      pk.y = pack2(facc[mtl][nt][2], facc[mtl][nt][3]);
      int d = nt * 16 + l;
      int m = (2 * w + mtl) * 16 + q * 4;
      *(uint2*)(part + ((size_t)((t * 8 + h) * 64 + d)) * 128 + m) = pk;
    }
}

// ---------------- K3p: reduce 256 bf16 partials -> lastB (bf16 B-frag order) ----------------
__global__ __launch_bounds__(256) void k3p_pack(const unsigned* __restrict__ part32, unsigned short* __restrict__ lastB) {
  int t2 = blockIdx.x * 256 + threadIdx.x;  // 32768 = h*4096 + d*64 + m/2
  float s0 = 0.f, s1 = 0.f;
#pragma unroll 16
  for (int c = 0; c < 256; ++c) {
    unsigned v = part32[((size_t)c << 12) + t2];
    s0 += __uint_as_float(v << 16);
    s1 += __uint_as_float(v & 0xffff0000u);
  }
  int m = (t2 & 63) * 2, d = (t2 >> 6) & 63, h = t2 >> 12;
  int ks = m >> 5, j = m & 7, qq = (m >> 3) & 3;
  int lane = qq * 16 + (d & 15), nt = d >> 4;
  unsigned short* dst = &lastB[((((h * 4 + ks) * 4 + nt) * 64 + lane) << 3) + j];
  dst[0] = f2bf(s0);
  dst[1] = f2bf(s1);
}

// ---------------- K4: MFMA zo = phiq @ last[h'] ; row-norm; 8-head mean; final normalize ----------------
// zbufT[w][d][i2] = packed bf16 pair (rows 2*i2, 2*i2+1) of normalized zo. 36864 B -> 4 blocks/CU.
__global__ __launch_bounds__(512) void k4_mfma(const unsigned short* __restrict__ phiq,
                                               const unsigned short* __restrict__ lastB,
                                               const float* __restrict__ ea, float* __restrict__ out) {
  __shared__ unsigned zbufT[8][64][18];
  int w = threadIdx.x >> 6, lane = threadIdx.x & 63;
  int q = lane >> 4, l = lane & 15;
  int n0 = blockIdx.x * 32;

  const s8v* Bf = (const s8v*)lastB;
  s8v bf[4][4];
#pragma unroll
  for (int ks = 0; ks < 4; ++ks)
#pragma unroll
    for (int nt = 0; nt < 4; ++nt) bf[ks][nt] = Bf[((w * 4 + ks) * 4 + nt) * 64 + lane];

  s8v af[2][4];
#pragma unroll
  for (int mt = 0; mt < 2; ++mt)
#pragma unroll
    for (int ks = 0; ks < 4; ++ks)
      af[mt][ks] = *(const s8v*)(phiq + (size_t)(8 * (n0 + mt * 16 + l) + w) * 128 + ks * 32 + q * 8);

  f4v acc[2][4];
#pragma unroll
  for (int mt = 0; mt < 2; ++mt)
#pragma unroll
    for (int nt = 0; nt < 4; ++nt) acc[mt][nt] = (f4v)(0.f);
#pragma unroll
  for (int ks = 0; ks < 4; ++ks)
#pragma unroll
    for (int nt = 0; nt < 4; ++nt)
#pragma unroll
      for (int mt = 0; mt < 2; ++mt)
        acc[mt][nt] = __builtin_amdgcn_mfma_f32_16x16x32_bf16(af[mt][ks], bf[ks][nt], acc[mt][nt], 0, 0, 0);

#pragma unroll
  for (int mt = 0; mt < 2; ++mt) {
    float rs[4];
#pragma unroll
    for (int reg = 0; reg < 4; ++reg) {
      float v0 = acc[mt][0][reg];
      float s0 = (l == 0) ? -v0 * v0 : v0 * v0;
      rs[reg] = s0 + acc[mt][1][reg] * acc[mt][1][reg] + acc[mt][2][reg] * acc[mt][2][reg] +
                acc[mt][3][reg] * acc[mt][3][reg];
    }
#pragma unroll
    for (int reg = 0; reg < 4; ++reg) {
#pragma unroll
      for (int off = 1; off < 16; off <<= 1) rs[reg] += __shfl_xor(rs[reg], off, 64);
    }
    float inv[4];
#pragma unroll
    for (int reg = 0; reg < 4; ++reg) inv[reg] = 1.f / sqrtf(fabsf(rs[reg]));
#pragma unroll
    for (int nt = 0; nt < 4; ++nt) {
      uint2 pk;
      pk.x = pack2(acc[mt][nt][0] * inv[0], acc[mt][nt][1] * inv[1]);
      pk.y = pack2(acc[mt][nt][2] * inv[2], acc[mt][nt][3] * inv[3]);
      *(uint2*)&zbufT[w][nt * 16 + l][mt * 8 + q * 2] = pk;
    }
  }
  __syncthreads();

  int tid = threadIdx.x;
  int i = tid >> 4, dg = tid & 15;  // row i 0..31, d-group dg*4..+3
  int i2 = i >> 1, sel = i & 1;
  float s[4] = {0.f, 0.f, 0.f, 0.f};
#pragma unroll
  for (int w2 = 0; w2 < 8; ++w2) {
#pragma unroll
    for (int j = 0; j < 4; ++j) {
      unsigned u = zbufT[w2][dg * 4 + j][i2];
      s[j] += bf2f((unsigned short)(sel ? (u >> 16) : (u & 0xffffu)));
    }
  }
  float m2 = 0.f;
#pragma unroll
  for (int j = 0; j < 4; ++j) {
    s[j] *= 0.125f;
    m2 += ((dg == 0 && j == 0) ? -s[j] * s[j] : s[j] * s[j]);
  }
#pragma unroll
  for (int off = 1; off < 16; off <<= 1) m2 += __shfl_xor(m2, off, 64);
  float inv = 1.f / sqrtf(fabsf(m2));
  float4 o = make_float4(s[0] * inv, s[1] * inv, s[2] * inv, s[3] * inv);
  *(float4*)(out + (size_t)(n0 + i) * 64 + dg * 4) = o;
  if (blockIdx.x == 0 && tid == 0) out[(size_t)NNODES * 64] = ea[0] * (1.0f / 524288.0f);
}

// ---------------- K5: link loss (16 edges/wave, 1024 blocks) ----------------
__global__ __launch_bounds__(256) void k5_ea(const unsigned short* __restrict__ phiq,
                                             const unsigned short* __restrict__ phik,
                                             const int* __restrict__ ei, float* __restrict__ ea) {
  __shared__ float part[4];
  int lane = threadIdx.x & 63, w = threadIdx.x >> 6;
  int wid = blockIdx.x * 4 + w;
  float acc = 0.f;
  for (int i = 0; i < 16; ++i) {
    int e = wid * 16 + i;
    int s = ei[e];
    int d = ei[NEDGES + e];
    const unsigned short* bq = phiq + (size_t)d * 1024;
    const unsigned short* bk = phik + (size_t)s * 1024;
    uint4 qa = *(const uint4*)(bq + lane * 16);
    uint4 qb = *(const uint4*)(bq + lane * 16 + 8);
    uint4 ka = *(const uint4*)(bk + lane * 16);
    uint4 kb = *(const uint4*)(bk + lane * 16 + 8);
    unsigned qs[8] = {qa.x, qa.y, qa.z, qa.w, qb.x, qb.y, qb.z, qb.w};
    unsigned ks[8] = {ka.x, ka.y, ka.z, ka.w, kb.x, kb.y, kb.z, kb.w};
#pragma unroll
    for (int p = 0; p < 8; ++p) {
      float q0 = __uint_as_float(qs[p] << 16);
      float q1 = __uint_as_float(qs[p] & 0xffff0000u);
      float k0 = __uint_as_float(ks[p] << 16);
      float k1 = __uint_as_float(ks[p] & 0xffff0000u);
      acc = fmaf(q0, k0, acc);
      acc = fmaf(q1, k1, acc);
    }
  }
#pragma unroll
  for (int o = 1; o < 64; o <<= 1) acc += __shfl_xor(acc, o, 64);
  if (lane == 0) part[w] = acc;
  __syncthreads();
  if (threadIdx.x == 0) atomicAdd(ea, part[0] + part[1] + part[2] + part[3]);
}

// ---------------- launch ----------------
extern "C" void kernel_launch(void* const* d_in, const int* in_sizes, int n_in,
                              void* d_out, int out_size, void* d_ws, size_t ws_size,
                              hipStream_t stream) {
  const float* z  = (const float*)d_in[0];
  const float* Wq = (const float*)d_in[1];
  const float* Wk = (const float*)d_in[2];
  const float* Wv = (const float*)d_in[3];
  const float* P  = (const float*)d_in[4];
  const int* ei   = (const int*)d_in[5];
  char* ws = (char*)d_ws;
  unsigned short* Wfrag = (unsigned short*)(ws + OFF_WFRAG);
  unsigned short* lastB = (unsigned short*)(ws + OFF_LASTB);  // sequenced reuse of Wfrag region
  unsigned short* Pfrag = (unsigned short*)(ws + OFF_PFRAG);
  float*          ea    = (float*)(ws + OFF_EA);
  unsigned short* ubf   = (unsigned short*)(ws + OFF_U);
  unsigned short* part  = (unsigned short*)(ws + OFF_PART);
  unsigned short* phiq  = (unsigned short*)(ws + OFF_PHIQ);
  unsigned short* phik  = (unsigned short*)(ws + OFF_PHIK);

  k01_prep<<<2048, 256, 0, stream>>>(z, ubf, Wq, Wk, Wv, P, Wfrag, Pfrag, ea);
  k2_mfma<<<2048, 256, 0, stream>>>(ubf, Wfrag, Pfrag, phiq, phik, part);
  k3p_pack<<<128, 256, 0, stream>>>((const unsigned*)part, lastB);
  k5_ea<<<NEDGES / 64, 256, 0, stream>>>(phiq, phik, ei, ea);
  k4_mfma<<<NNODES / 32, 512, 0, stream>>>(phiq, lastB, ea, (float*)d_out);
}

// Round 9
// 201.882 us; speedup vs baseline: 5.5177x; 1.0825x over previous
//
#include <hip/hip_runtime.h>

#define DEV __device__ __forceinline__

// ---------------- constants ----------------
// N_NODES=32768, N_EDGES=65536, H=8, D=64, DS=63, M=128, R=H*N=262144
#define NNODES 32768
#define NEDGES 65536
#define NROWS  262144
#define EPSF   1e-7f
#define SQRT2F 1.4142135623730951f
#define LOG2E  1.4426950408889634f
#define LOG2SQRT63 2.9886399611087573f   // log2(sqrt(63))

// ---------------- ws layout (bytes) ----------------
// Sequenced reuse: Wfrag (k01->k2) then lastB (k3p->k4) share offset 0.
#define OFF_WFRAG 0u          // bf16 [3][8][2][4][64][8]  W in MFMA B-frag order (196608 B) [dead after k2]
#define OFF_LASTB 0u          // bf8  [8][4][4][64][8] B-frag of last (65536 B) [written k3p, read k4]
#define OFF_PFRAG 196608u     // bf16 [8][2][64][8]  sqrt(2)*log2e*P, MFMA A-frag order (16384 B)
#define OFF_EA    212992u     // float [1] (zeroed by k01)
#define OFF_U     409600u     // bf16 [N][64] u (4194304 B) [dead after k2]
#define OFF_PART  42352640u   // bf16 [256 c][8 h][64 d][128 m] split-K partials of last (33554432 B)
#define OFF_PHIQ  75907072u   // fp8 e4m3 [R][128] (33554432 B)
#define OFF_PHIK  143015936u  // fp8 e4m3 [R][128] (33554432 B)
// end well under previous 210 MB footprint

typedef short s8v __attribute__((ext_vector_type(8)));   // 8 bf16 in 4 VGPRs (MFMA A/B frag)
typedef float f4v __attribute__((ext_vector_type(4)));   // MFMA C/D frag
typedef float f2v __attribute__((ext_vector_type(2)));

// ---------------- helpers ----------------
DEV unsigned short f2bf(float f) {  // rne
  unsigned u = __float_as_uint(f);
  return (unsigned short)((u + 0x7fffu + ((u >> 16) & 1u)) >> 16);
}
DEV float bf2f(unsigned short h) { return __uint_as_float(((unsigned)h) << 16); }
// pack two f32 -> two bf16 (round-half-up) in one uint: low short = bf16(lo), high = bf16(hi)
DEV unsigned pack2(float lo, float hi) {
  return __builtin_amdgcn_perm(__float_as_uint(hi) + 0x8000u, __float_as_uint(lo) + 0x8000u, 0x07060302u);
}
DEV float frcp(float x) { return __builtin_amdgcn_rcpf(x); }

// ---------------- K01: u cast (+ blocks<96: pack W/P frags; block0: zero ea) ----------------
// u = logmap0(proj(expmap0(z))) == [0, z[1:]] identically (acosh(cosh t)=t for t~0.08).
__global__ __launch_bounds__(256) void k01_prep(const float* __restrict__ z, unsigned short* __restrict__ ubf,
                                                const float* __restrict__ Wq, const float* __restrict__ Wk,
                                                const float* __restrict__ Wv, const float* __restrict__ P,
                                                unsigned short* __restrict__ Wfrag, unsigned short* __restrict__ Pfrag,
                                                float* __restrict__ ea) {
  int i = blockIdx.x * 256 + threadIdx.x;  // 524288 float4 groups
  float4 v = *(const float4*)(z + (size_t)i * 4);
  if ((i & 15) == 0) v.x = 0.f;  // time slot
  uint2 pk;
  pk.x = pack2(v.x, v.y);
  pk.y = pack2(v.z, v.w);
  *(uint2*)(ubf + (size_t)i * 4) = pk;

  if (blockIdx.x < 96) {
    if (i == 0) ea[0] = 0.f;
    int stride = 96 * 256;
    // Wfrag[sm][h][ks][nt][lane][j] : B[k][n], n = nt*16+(lane&15), k = ks*32+(lane>>4)*8+j
    for (int t = i; t < 98304; t += stride) {
      int j = t & 7, lane = (t >> 3) & 63, nt = (t >> 9) & 3, ks = (t >> 11) & 1, h = (t >> 12) & 7, sm = t >> 15;
      int k = ks * 32 + (lane >> 4) * 8 + j;
      int n = nt * 16 + (lane & 15);
      const float* W = (sm == 0) ? Wq : ((sm == 1) ? Wk : Wv);
      Wfrag[t] = f2bf(W[(h * 64 + n) * 64 + k]);
    }
    // Pfrag[mt8][ks2][lane][j] : A[m][k], m = mt*16+(lane&15), k = ks*32+(lane>>4)*8+j ; k=0 zero pad
    for (int t = i; t < 8192; t += stride) {
      int j = t & 7, lane = (t >> 3) & 63, ks = (t >> 9) & 1, mt = (t >> 10) & 7;
      int k = ks * 32 + (lane >> 4) * 8 + j;
      int m = mt * 16 + (lane & 15);
      Pfrag[t] = (k == 0) ? (unsigned short)0 : f2bf(P[(k - 1) * 128 + m] * (SQRT2F * LOG2E));
    }
  }
}

// ---------------- K2: fused mu -> (q,k,v) -> phi_q, phi_k (fp8) ; + last partial (phik^T @ V) ----------------
// Block = 256 thr (4 waves), block (h, t) owns 128 nodes. LDS 37888 B.
//   pre-barrier:  sbuf [2][4][32*72] bf16 (36864 B) + sfront (1024 B)
//   post-barrier: kbufT [128 m][68] bf16 (17408 B) + vbufT [64 d][72] bf16 (9216 B)  [alias, per 64-node half]
// phi stored to global as fp8 e4m3; phik kept in bf16 regs for the fused GEMM (full precision).
__global__ __launch_bounds__(256) void k2_mfma(const unsigned short* __restrict__ ubf,
                                               const unsigned short* __restrict__ Wfrag,
                                               const unsigned short* __restrict__ Pfrag,
                                               unsigned char* __restrict__ phiq, unsigned char* __restrict__ phik,
                                               unsigned short* __restrict__ part) {
  __shared__ short lds_raw[18944];             // 37888 B
  short* sbuf = lds_raw;                       // [(sm*4+w)*2304 + row*72 + col]
  float* sfront = (float*)(lds_raw + 18432);   // [(sm*4+w)*32 + row]
  short* kbufT = lds_raw;                      // post-barrier alias: [m*68 + nloc]
  short* vbufT = lds_raw + 8704;               // post-barrier alias: [d*72 + nloc]

  int w = threadIdx.x >> 6, lane = threadIdx.x & 63;
  int q = lane >> 4, l = lane & 15;
  int b = blockIdx.x;
  int h = b >> 8, t = b & 255;
  int n0 = t * 128 + w * 32;
  int r0 = h * 32768 + n0;

  // A-fragments of u (bf16 direct loads)
  s8v afr[2][2];
#pragma unroll
  for (int mt = 0; mt < 2; ++mt)
#pragma unroll
    for (int ks = 0; ks < 2; ++ks)
      afr[mt][ks] = *(const s8v*)(ubf + (size_t)(n0 + mt * 16 + l) * 64 + ks * 32 + q * 8);

  const s8v* Wf = (const s8v*)Wfrag;
  const s8v* Pf = (const s8v*)Pfrag;
  uint2 vkeep[2][4];  // packed V rows: [mt][nt], pairs along node (reg) axis

  // ---- Phase 1: three mu GEMMs + row nonlinearity; V -> vkeep regs ----
#pragma unroll
  for (int sm = 0; sm < 3; ++sm) {
    f4v acc[2][4];
#pragma unroll
    for (int mt = 0; mt < 2; ++mt)
#pragma unroll
      for (int nt = 0; nt < 4; ++nt) acc[mt][nt] = (f4v)(0.f);
#pragma unroll
    for (int ks = 0; ks < 2; ++ks)
#pragma unroll
      for (int nt = 0; nt < 4; ++nt) {
        s8v bf = Wf[(((sm * 8 + h) * 2 + ks) * 4 + nt) * 64 + lane];
#pragma unroll
        for (int mt = 0; mt < 2; ++mt)
          acc[mt][nt] = __builtin_amdgcn_mfma_f32_16x16x32_bf16(afr[mt][ks], bf, acc[mt][nt], 0, 0, 0);
      }
#pragma unroll
    for (int mt = 0; mt < 2; ++mt) {
      float rs[4];
#pragma unroll
      for (int reg = 0; reg < 4; ++reg) {
        float v0 = (l == 0) ? 0.f : acc[mt][0][reg];
        rs[reg] = v0 * v0 + acc[mt][1][reg] * acc[mt][1][reg] + acc[mt][2][reg] * acc[mt][2][reg] +
                  acc[mt][3][reg] * acc[mt][3][reg];
      }
#pragma unroll
      for (int reg = 0; reg < 4; ++reg) {
#pragma unroll
        for (int off = 1; off < 16; off <<= 1) rs[reg] += __shfl_xor(rs[reg], off, 64);
      }
      float vreg[4][4];  // [nt][reg], sm==2 only
#pragma unroll
      for (int reg = 0; reg < 4; ++reg) {
        float x = fmaxf(sqrtf(rs[reg]), EPSF);
        float e = exp2f(x * LOG2E);
        float sh = 0.5f * (e - frcp(e));
        float ratio = sh * frcp(x);
        float sh2 = sh * sh;
        int row = mt * 16 + q * 4 + reg;
        if (sm == 2) {
          float tt2 = sqrtf(1.f + sh2);
#pragma unroll
          for (int nt = 0; nt < 4; ++nt) {
            float val = acc[mt][nt][reg] * ratio;
            if (l == 0 && nt == 0) val = tt2;  // time component (d=0)
            vreg[nt][reg] = val;
          }
        } else {
          float lf = -sh2 * LOG2E - LOG2SQRT63;
          if (l == 0) sfront[(sm * 4 + w) * 32 + row] = lf;
#pragma unroll
          for (int nt = 0; nt < 4; ++nt) {
            float val = acc[mt][nt][reg] * ratio;
            if (l == 0 && nt == 0) val = 0.f;
            sbuf[(sm * 4 + w) * 2304 + row * 72 + nt * 16 + l] = (short)(__float_as_uint(val) >> 16);
          }
        }
      }
      if (sm == 2) {
#pragma unroll
        for (int nt = 0; nt < 4; ++nt) {
          vkeep[mt][nt].x = pack2(vreg[nt][0], vreg[nt][1]);
          vkeep[mt][nt].y = pack2(vreg[nt][2], vreg[nt][3]);
        }
      }
    }
  }

  // ---- Phase 2: phi^T GEMM ; phi = exp2(acc + lf) -> fp8 global ; keep phik bf16 regs ----
  uint2 keep0[8], keep1[8];
#pragma unroll
  for (int sm = 0; sm < 2; ++sm) {
    s8v bsf[2][2];  // [nt2][ks] : B[k=c][n=node]
#pragma unroll
    for (int nt = 0; nt < 2; ++nt)
#pragma unroll
      for (int ks = 0; ks < 2; ++ks)
        bsf[nt][ks] = *(const s8v*)&sbuf[(sm * 4 + w) * 2304 + (nt * 16 + l) * 72 + ks * 32 + q * 8];
    float lf0 = sfront[(sm * 4 + w) * 32 + l];
    float lf1 = sfront[(sm * 4 + w) * 32 + 16 + l];
    unsigned char* dst = sm ? phik : phiq;
#pragma unroll
    for (int mt = 0; mt < 8; ++mt) {
      f4v a0 = (f4v)(0.f), a1 = (f4v)(0.f);
#pragma unroll
      for (int ks = 0; ks < 2; ++ks) {
        s8v ap = Pf[(mt * 2 + ks) * 64 + lane];
        a0 = __builtin_amdgcn_mfma_f32_16x16x32_bf16(ap, bsf[0][ks], a0, 0, 0, 0);
        a1 = __builtin_amdgcn_mfma_f32_16x16x32_bf16(ap, bsf[1][ks], a1, 0, 0, 0);
      }
      float v00 = exp2f(a0[0] + lf0), v01 = exp2f(a0[1] + lf0), v02 = exp2f(a0[2] + lf0), v03 = exp2f(a0[3] + lf0);
      float v10 = exp2f(a1[0] + lf1), v11 = exp2f(a1[1] + lf1), v12 = exp2f(a1[2] + lf1), v13 = exp2f(a1[3] + lf1);
      unsigned p0 = __builtin_amdgcn_cvt_pk_fp8_f32(v00, v01, 0, 0);
      p0 = __builtin_amdgcn_cvt_pk_fp8_f32(v02, v03, p0, 1);
      unsigned p1 = __builtin_amdgcn_cvt_pk_fp8_f32(v10, v11, 0, 0);
      p1 = __builtin_amdgcn_cvt_pk_fp8_f32(v12, v13, p1, 1);
      *(unsigned*)(dst + (size_t)(r0 + l) * 128 + mt * 16 + q * 4) = p0;
      *(unsigned*)(dst + (size_t)(r0 + 16 + l) * 128 + mt * 16 + q * 4) = p1;
      if (sm == 1) {
        keep0[mt].x = pack2(v00, v01); keep0[mt].y = pack2(v02, v03);
        keep1[mt].x = pack2(v10, v11); keep1[mt].y = pack2(v12, v13);
      }
    }
  }

  // ---- Fused GEMM over two 64-node halves: D[m][d] = sum_node phik[node][m] * V[node][d] ----
  f4v facc[2][4];
#pragma unroll
  for (int mtl = 0; mtl < 2; ++mtl)
#pragma unroll
    for (int nt = 0; nt < 4; ++nt) facc[mtl][nt] = (f4v)(0.f);

#pragma unroll
  for (int hf = 0; hf < 2; ++hf) {
    __syncthreads();  // previous contents (sbuf / prior half) fully consumed
    if ((w >> 1) == hf) {
      int nd0 = (w & 1) * 32 + l, nd1 = nd0 + 16;
#pragma unroll
      for (int mt = 0; mt < 8; ++mt) {
        int m = mt * 16 + q * 4;
        kbufT[(m + 0) * 68 + nd0] = (short)(keep0[mt].x & 0xffffu);
        kbufT[(m + 1) * 68 + nd0] = (short)(keep0[mt].x >> 16);
        kbufT[(m + 2) * 68 + nd0] = (short)(keep0[mt].y & 0xffffu);
        kbufT[(m + 3) * 68 + nd0] = (short)(keep0[mt].y >> 16);
        kbufT[(m + 0) * 68 + nd1] = (short)(keep1[mt].x & 0xffffu);
        kbufT[(m + 1) * 68 + nd1] = (short)(keep1[mt].x >> 16);
        kbufT[(m + 2) * 68 + nd1] = (short)(keep1[mt].y & 0xffffu);
        kbufT[(m + 3) * 68 + nd1] = (short)(keep1[mt].y >> 16);
      }
#pragma unroll
      for (int mt = 0; mt < 2; ++mt)
#pragma unroll
        for (int nt = 0; nt < 4; ++nt)
          *(uint2*)&vbufT[(nt * 16 + l) * 72 + (w & 1) * 32 + mt * 16 + q * 4] = vkeep[mt][nt];
    }
    __syncthreads();  // half ready
#pragma unroll
    for (int kc = 0; kc < 2; ++kc) {
      s8v bv[4];
#pragma unroll
      for (int nt = 0; nt < 4; ++nt)
        bv[nt] = *(const s8v*)&vbufT[(nt * 16 + l) * 72 + kc * 32 + q * 8];
      s8v av[2];
#pragma unroll
      for (int mtl = 0; mtl < 2; ++mtl) {
        const short* kb = &kbufT[((2 * w + mtl) * 16 + l) * 68 + kc * 32 + q * 8];
        union { s8v v; long long L[2]; } ua;
        ua.L[0] = *(const long long*)kb;
        ua.L[1] = *(const long long*)(kb + 4);
        av[mtl] = ua.v;
      }
#pragma unroll
      for (int mtl = 0; mtl < 2; ++mtl)
#pragma unroll
        for (int nt = 0; nt < 4; ++nt)
          facc[mtl][nt] = __builtin_amdgcn_mfma_f32_16x16x32_bf16(av[mtl], bv[nt], facc[mtl][nt], 0, 0, 0);
    }
  }

  // store part[t][h][d][m] bf16, m-contiguous 8B stores
#pragma unroll
  for (int mtl = 0; mtl < 2; ++mtl)
#pragma unroll
    for (int nt = 0; nt < 4; ++nt) {
      uint2 pk;
      pk.x = pack2(facc[mtl][nt][0], facc[mtl][nt][1]);
      pk.y = pack2(facc[mtl][nt][2], facc[mtl][nt][3]);
      int d = nt * 16 + l;
      int m = (2 * w + mtl) * 16 + q * 4;
      *(uint2*)(part + ((size_t)((t * 8 + h) * 64 + d)) * 128 + m) = pk;
    }
}

// ---------------- K3p: reduce 256 bf16 partials -> lastB (bf8 e5m2, B-frag byte order) ----------------
__global__ __launch_bounds__(256) void k3p_pack(const unsigned* __restrict__ part32, unsigned char* __restrict__ lastB) {
  int t2 = blockIdx.x * 256 + threadIdx.x;  // 32768 = h*4096 + d*64 + m/2
  float s0 = 0.f, s1 = 0.f;
#pragma unroll 16
  for (int c = 0; c < 256; ++c) {
    unsigned v = part32[((size_t)c << 12) + t2];
    s0 += __uint_as_float(v << 16);
    s1 += __uint_as_float(v & 0xffff0000u);
  }
  int m = (t2 & 63) * 2, d = (t2 >> 6) & 63, h = t2 >> 12;
  int ks = m >> 5, j = m & 7, qq = (m >> 3) & 3;
  int lane = qq * 16 + (d & 15), nt = d >> 4;
  unsigned r = __builtin_amdgcn_cvt_pk_bf8_f32(s0, s1, 0, 0);  // low 2 bytes = bf8(s0), bf8(s1)
  *(unsigned short*)(lastB + ((((h * 4 + ks) * 4 + nt) * 64 + lane) << 3) + j) = (unsigned short)r;
}

// ---------------- K4: fp8xbf8 MFMA zo = phiq @ last[h'] ; row-norm; 8-head mean; final normalize ----------------
// zbufT[w][d][i2] = packed bf16 pair (rows 2*i2, 2*i2+1) of normalized zo. 36864 B -> 4 blocks/CU.
__global__ __launch_bounds__(512) void k4_mfma(const unsigned char* __restrict__ phiq,
                                               const unsigned char* __restrict__ lastB,
                                               const float* __restrict__ ea, float* __restrict__ out) {
  __shared__ unsigned zbufT[8][64][18];
  int w = threadIdx.x >> 6, lane = threadIdx.x & 63;
  int q = lane >> 4, l = lane & 15;
  int n0 = blockIdx.x * 32;

  const long* Bf = (const long*)lastB;
  long bf[4][4];
#pragma unroll
  for (int ks = 0; ks < 4; ++ks)
#pragma unroll
    for (int nt = 0; nt < 4; ++nt) bf[ks][nt] = Bf[((w * 4 + ks) * 4 + nt) * 64 + lane];

  long af[2][4];
#pragma unroll
  for (int mt = 0; mt < 2; ++mt)
#pragma unroll
    for (int ks = 0; ks < 4; ++ks)
      af[mt][ks] = *(const long*)(phiq + (size_t)(8 * (n0 + mt * 16 + l) + w) * 128 + ks * 32 + q * 8);

  f4v acc[2][4];
#pragma unroll
  for (int mt = 0; mt < 2; ++mt)
#pragma unroll
    for (int nt = 0; nt < 4; ++nt) acc[mt][nt] = (f4v)(0.f);
#pragma unroll
  for (int ks = 0; ks < 4; ++ks)
#pragma unroll
    for (int nt = 0; nt < 4; ++nt)
#pragma unroll
      for (int mt = 0; mt < 2; ++mt)
        acc[mt][nt] = __builtin_amdgcn_mfma_f32_16x16x32_fp8_bf8(af[mt][ks], bf[ks][nt], acc[mt][nt], 0, 0, 0);

#pragma unroll
  for (int mt = 0; mt < 2; ++mt) {
    float rs[4];
#pragma unroll
    for (int reg = 0; reg < 4; ++reg) {
      float v0 = acc[mt][0][reg];
      float s0 = (l == 0) ? -v0 * v0 : v0 * v0;
      rs[reg] = s0 + acc[mt][1][reg] * acc[mt][1][reg] + acc[mt][2][reg] * acc[mt][2][reg] +
                acc[mt][3][reg] * acc[mt][3][reg];
    }
#pragma unroll
    for (int reg = 0; reg < 4; ++reg) {
#pragma unroll
      for (int off = 1; off < 16; off <<= 1) rs[reg] += __shfl_xor(rs[reg], off, 64);
    }
    float inv[4];
#pragma unroll
    for (int reg = 0; reg < 4; ++reg) inv[reg] = 1.f / sqrtf(fabsf(rs[reg]));
#pragma unroll
    for (int nt = 0; nt < 4; ++nt) {
      uint2 pk;
      pk.x = pack2(acc[mt][nt][0] * inv[0], acc[mt][nt][1] * inv[1]);
      pk.y = pack2(acc[mt][nt][2] * inv[2], acc[mt][nt][3] * inv[3]);
      *(uint2*)&zbufT[w][nt * 16 + l][mt * 8 + q * 2] = pk;
    }
  }
  __syncthreads();

  int tid = threadIdx.x;
  int i = tid >> 4, dg = tid & 15;  // row i 0..31, d-group dg*4..+3
  int i2 = i >> 1, sel = i & 1;
  float s[4] = {0.f, 0.f, 0.f, 0.f};
#pragma unroll
  for (int w2 = 0; w2 < 8; ++w2) {
#pragma unroll
    for (int j = 0; j < 4; ++j) {
      unsigned u = zbufT[w2][dg * 4 + j][i2];
      s[j] += bf2f((unsigned short)(sel ? (u >> 16) : (u & 0xffffu)));
    }
  }
  float m2 = 0.f;
#pragma unroll
  for (int j = 0; j < 4; ++j) {
    s[j] *= 0.125f;
    m2 += ((dg == 0 && j == 0) ? -s[j] * s[j] : s[j] * s[j]);
  }
#pragma unroll
  for (int off = 1; off < 16; off <<= 1) m2 += __shfl_xor(m2, off, 64);
  float inv = 1.f / sqrtf(fabsf(m2));
  float4 o = make_float4(s[0] * inv, s[1] * inv, s[2] * inv, s[3] * inv);
  *(float4*)(out + (size_t)(n0 + i) * 64 + dg * 4) = o;
  if (blockIdx.x == 0 && tid == 0) out[(size_t)NNODES * 64] = ea[0] * (1.0f / 524288.0f);
}

// ---------------- K5: link loss, fp8 gather (16 edges/wave, 1024 blocks) ----------------
__global__ __launch_bounds__(256) void k5_ea(const unsigned char* __restrict__ phiq,
                                             const unsigned char* __restrict__ phik,
                                             const int* __restrict__ ei, float* __restrict__ ea) {
  __shared__ float part[4];
  int lane = threadIdx.x & 63, w = threadIdx.x >> 6;
  int wid = blockIdx.x * 4 + w;
  float acc = 0.f;
  for (int i = 0; i < 16; ++i) {
    int e = wid * 16 + i;
    int s = ei[e];
    int d = ei[NEDGES + e];
    uint4 qa = *(const uint4*)(phiq + (size_t)d * 1024 + lane * 16);
    uint4 ka = *(const uint4*)(phik + (size_t)s * 1024 + lane * 16);
    unsigned qs[4] = {qa.x, qa.y, qa.z, qa.w};
    unsigned ks[4] = {ka.x, ka.y, ka.z, ka.w};
#pragma unroll
    for (int p = 0; p < 4; ++p) {
      f2v q0 = __builtin_amdgcn_cvt_pk_f32_fp8(qs[p], 0);
      f2v q1 = __builtin_amdgcn_cvt_pk_f32_fp8(qs[p], 1);
      f2v k0 = __builtin_amdgcn_cvt_pk_f32_fp8(ks[p], 0);
      f2v k1 = __builtin_amdgcn_cvt_pk_f32_fp8(ks[p], 1);
      acc = fmaf(q0.x, k0.x, acc);
      acc = fmaf(q0.y, k0.y, acc);
      acc = fmaf(q1.x, k1.x, acc);
      acc = fmaf(q1.y, k1.y, acc);
    }
  }
#pragma unroll
  for (int o = 1; o < 64; o <<= 1) acc += __shfl_xor(acc, o, 64);
  if (lane == 0) part[w] = acc;
  __syncthreads();
  if (threadIdx.x == 0) atomicAdd(ea, part[0] + part[1] + part[2] + part[3]);
}

// ---------------- launch ----------------
extern "C" void kernel_launch(void* const* d_in, const int* in_sizes, int n_in,
                              void* d_out, int out_size, void* d_ws, size_t ws_size,
                              hipStream_t stream) {
  const float* z  = (const float*)d_in[0];
  const float* Wq = (const float*)d_in[1];
  const float* Wk = (const float*)d_in[2];
  const float* Wv = (const float*)d_in[3];
  const float* P  = (const float*)d_in[4];
  const int* ei   = (const int*)d_in[5];
  char* ws = (char*)d_ws;
  unsigned short* Wfrag = (unsigned short*)(ws + OFF_WFRAG);
  unsigned char*  lastB = (unsigned char*)(ws + OFF_LASTB);  // sequenced reuse of Wfrag region
  unsigned short* Pfrag = (unsigned short*)(ws + OFF_PFRAG);
  float*          ea    = (float*)(ws + OFF_EA);
  unsigned short* ubf   = (unsigned short*)(ws + OFF_U);
  unsigned short* part  = (unsigned short*)(ws + OFF_PART);
  unsigned char*  phiq  = (unsigned char*)(ws + OFF_PHIQ);
  unsigned char*  phik  = (unsigned char*)(ws + OFF_PHIK);

  k01_prep<<<2048, 256, 0, stream>>>(z, ubf, Wq, Wk, Wv, P, Wfrag, Pfrag, ea);
  k2_mfma<<<2048, 256, 0, stream>>>(ubf, Wfrag, Pfrag, phiq, phik, part);
  k3p_pack<<<128, 256, 0, stream>>>((const unsigned*)part, lastB);
  k5_ea<<<NEDGES / 64, 256, 0, stream>>>(phiq, phik, ei, ea);
  k4_mfma<<<NNODES / 32, 512, 0, stream>>>(phiq, lastB, ea, (float*)d_out);
}

// Round 10
// 193.959 us; speedup vs baseline: 5.7431x; 1.0408x over previous
//
#include <hip/hip_runtime.h>

#define DEV __device__ __forceinline__

// ---------------- constants ----------------
// N_NODES=32768, N_EDGES=65536, H=8, D=64, DS=63, M=128, R=H*N=262144
#define NNODES 32768
#define NEDGES 65536
#define NROWS  262144
#define EPSF   1e-7f
#define SQRT2F 1.4142135623730951f
#define LOG2E  1.4426950408889634f
#define LOG2SQRT63 2.9886399611087573f   // log2(sqrt(63))

// ---------------- ws layout (bytes) ----------------
// Sequenced reuse: Wfrag (k01->k2) then lastB (k35->k4) share offset 0.
#define OFF_WFRAG 0u          // bf16 [3][8][2][4][64][8]  W in MFMA B-frag order (196608 B) [dead after k2]
#define OFF_LASTB 0u          // bf8  [8][4][4][64][8] B-frag of last (65536 B) [written k35, read k4]
#define OFF_PFRAG 196608u     // bf16 [8][2][64][8]  sqrt(2)*log2e*P, MFMA A-frag order (16384 B)
#define OFF_EA    212992u     // float [1] (zeroed by k01)
#define OFF_U     409600u     // bf16 [N][64] u (4194304 B) [dead after k2]
#define OFF_PART  42352640u   // bf16 [256 c][8 h][64 d][128 m] split-K partials of last (33554432 B)
#define OFF_PHIQ  75907072u   // fp8 e4m3 [R][128] (33554432 B)
#define OFF_PHIK  143015936u  // fp8 e4m3 [R][128] (33554432 B)

typedef short s8v __attribute__((ext_vector_type(8)));   // 8 bf16 in 4 VGPRs (MFMA A/B frag)
typedef float f4v __attribute__((ext_vector_type(4)));   // MFMA C/D frag
typedef float f2v __attribute__((ext_vector_type(2)));

// ---------------- helpers ----------------
DEV unsigned short f2bf(float f) {  // rne
  unsigned u = __float_as_uint(f);
  return (unsigned short)((u + 0x7fffu + ((u >> 16) & 1u)) >> 16);
}
DEV float bf2f(unsigned short h) { return __uint_as_float(((unsigned)h) << 16); }
// pack two f32 -> two bf16 (round-half-up) in one uint: low short = bf16(lo), high = bf16(hi)
DEV unsigned pack2(float lo, float hi) {
  return __builtin_amdgcn_perm(__float_as_uint(hi) + 0x8000u, __float_as_uint(lo) + 0x8000u, 0x07060302u);
}
DEV float frcp(float x) { return __builtin_amdgcn_rcpf(x); }
DEV float fsqrt(float x) { return __builtin_amdgcn_sqrtf(x); }    // raw v_sqrt_f32, args in normal range
DEV float fexp2(float x) { return __builtin_amdgcn_exp2f(x); }    // raw v_exp_f32, args in normal range

// ---------------- K01: u cast (+ blocks<96: pack W/P frags; block0: zero ea) ----------------
// u = logmap0(proj(expmap0(z))) == [0, z[1:]] identically (acosh(cosh t)=t for t~0.08).
__global__ __launch_bounds__(256) void k01_prep(const float* __restrict__ z, unsigned short* __restrict__ ubf,
                                                const float* __restrict__ Wq, const float* __restrict__ Wk,
                                                const float* __restrict__ Wv, const float* __restrict__ P,
                                                unsigned short* __restrict__ Wfrag, unsigned short* __restrict__ Pfrag,
                                                float* __restrict__ ea) {
  int i = blockIdx.x * 256 + threadIdx.x;  // 524288 float4 groups
  float4 v = *(const float4*)(z + (size_t)i * 4);
  if ((i & 15) == 0) v.x = 0.f;  // time slot
  uint2 pk;
  pk.x = pack2(v.x, v.y);
  pk.y = pack2(v.z, v.w);
  *(uint2*)(ubf + (size_t)i * 4) = pk;

  if (blockIdx.x < 96) {
    if (i == 0) ea[0] = 0.f;
    int stride = 96 * 256;
    // Wfrag[sm][h][ks][nt][lane][j] : B[k][n], n = nt*16+(lane&15), k = ks*32+(lane>>4)*8+j
    for (int t = i; t < 98304; t += stride) {
      int j = t & 7, lane = (t >> 3) & 63, nt = (t >> 9) & 3, ks = (t >> 11) & 1, h = (t >> 12) & 7, sm = t >> 15;
      int k = ks * 32 + (lane >> 4) * 8 + j;
      int n = nt * 16 + (lane & 15);
      const float* W = (sm == 0) ? Wq : ((sm == 1) ? Wk : Wv);
      Wfrag[t] = f2bf(W[(h * 64 + n) * 64 + k]);
    }
    // Pfrag[mt8][ks2][lane][j] : A[m][k], m = mt*16+(lane&15), k = ks*32+(lane>>4)*8+j ; k=0 zero pad
    for (int t = i; t < 8192; t += stride) {
      int j = t & 7, lane = (t >> 3) & 63, ks = (t >> 9) & 1, mt = (t >> 10) & 7;
      int k = ks * 32 + (lane >> 4) * 8 + j;
      int m = mt * 16 + (lane & 15);
      Pfrag[t] = (k == 0) ? (unsigned short)0 : f2bf(P[(k - 1) * 128 + m] * (SQRT2F * LOG2E));
    }
  }
}

// ---------------- K2: fused mu -> (q,k,v) -> phi_q, phi_k (fp8) ; + last partial (phik^T @ V) ----------------
// Block = 256 thr (4 waves), block (h, t) owns 128 nodes. LDS 37888 B.
//   pre-barrier:  sbuf [2][4][32*72] bf16 (36864 B) + sfront (1024 B)
//   post-barrier: kbufT [128 m][68] bf16 (17408 B) + vbufT [64 d][72] bf16 (9216 B)  [alias, per 64-node half]
__global__ __launch_bounds__(256) void k2_mfma(const unsigned short* __restrict__ ubf,
                                               const unsigned short* __restrict__ Wfrag,
                                               const unsigned short* __restrict__ Pfrag,
                                               unsigned char* __restrict__ phiq, unsigned char* __restrict__ phik,
                                               unsigned short* __restrict__ part) {
  __shared__ short lds_raw[18944];             // 37888 B
  short* sbuf = lds_raw;                       // [(sm*4+w)*2304 + row*72 + col]
  float* sfront = (float*)(lds_raw + 18432);   // [(sm*4+w)*32 + row]
  short* kbufT = lds_raw;                      // post-barrier alias: [m*68 + nloc]
  short* vbufT = lds_raw + 8704;               // post-barrier alias: [d*72 + nloc]

  int w = threadIdx.x >> 6, lane = threadIdx.x & 63;
  int q = lane >> 4, l = lane & 15;
  int b = blockIdx.x;
  int h = b >> 8, t = b & 255;
  int n0 = t * 128 + w * 32;
  int r0 = h * 32768 + n0;

  // A-fragments of u (bf16 direct loads)
  s8v afr[2][2];
#pragma unroll
  for (int mt = 0; mt < 2; ++mt)
#pragma unroll
    for (int ks = 0; ks < 2; ++ks)
      afr[mt][ks] = *(const s8v*)(ubf + (size_t)(n0 + mt * 16 + l) * 64 + ks * 32 + q * 8);

  const s8v* Wf = (const s8v*)Wfrag;
  const s8v* Pf = (const s8v*)Pfrag;
  uint2 vkeep[2][4];  // packed V rows: [mt][nt], pairs along node (reg) axis

  // ---- Phase 1: three mu GEMMs + row nonlinearity; V -> vkeep regs ----
#pragma unroll
  for (int sm = 0; sm < 3; ++sm) {
    f4v acc[2][4];
#pragma unroll
    for (int mt = 0; mt < 2; ++mt)
#pragma unroll
      for (int nt = 0; nt < 4; ++nt) acc[mt][nt] = (f4v)(0.f);
#pragma unroll
    for (int ks = 0; ks < 2; ++ks)
#pragma unroll
      for (int nt = 0; nt < 4; ++nt) {
        s8v bf = Wf[(((sm * 8 + h) * 2 + ks) * 4 + nt) * 64 + lane];
#pragma unroll
        for (int mt = 0; mt < 2; ++mt)
          acc[mt][nt] = __builtin_amdgcn_mfma_f32_16x16x32_bf16(afr[mt][ks], bf, acc[mt][nt], 0, 0, 0);
      }
#pragma unroll
    for (int mt = 0; mt < 2; ++mt) {
      float rs[4];
#pragma unroll
      for (int reg = 0; reg < 4; ++reg) {
        float v0 = (l == 0) ? 0.f : acc[mt][0][reg];
        rs[reg] = v0 * v0 + acc[mt][1][reg] * acc[mt][1][reg] + acc[mt][2][reg] * acc[mt][2][reg] +
                  acc[mt][3][reg] * acc[mt][3][reg];
      }
#pragma unroll
      for (int reg = 0; reg < 4; ++reg) {
#pragma unroll
        for (int off = 1; off < 16; off <<= 1) rs[reg] += __shfl_xor(rs[reg], off, 64);
      }
      float vreg[4][4];  // [nt][reg], sm==2 only
#pragma unroll
      for (int reg = 0; reg < 4; ++reg) {
        float x = fmaxf(fsqrt(rs[reg]), EPSF);
        float e = fexp2(x * LOG2E);
        float sh = 0.5f * (e - frcp(e));
        float ratio = sh * frcp(x);
        float sh2 = sh * sh;
        int row = mt * 16 + q * 4 + reg;
        if (sm == 2) {
          float tt2 = fsqrt(1.f + sh2);
#pragma unroll
          for (int nt = 0; nt < 4; ++nt) {
            float val = acc[mt][nt][reg] * ratio;
            if (l == 0 && nt == 0) val = tt2;  // time component (d=0)
            vreg[nt][reg] = val;
          }
        } else {
          float lf = -sh2 * LOG2E - LOG2SQRT63;
          if (l == 0) sfront[(sm * 4 + w) * 32 + row] = lf;
#pragma unroll
          for (int nt = 0; nt < 4; ++nt) {
            float val = acc[mt][nt][reg] * ratio;
            if (l == 0 && nt == 0) val = 0.f;
            sbuf[(sm * 4 + w) * 2304 + row * 72 + nt * 16 + l] = (short)(__float_as_uint(val) >> 16);
          }
        }
      }
      if (sm == 2) {
#pragma unroll
        for (int nt = 0; nt < 4; ++nt) {
          vkeep[mt][nt].x = pack2(vreg[nt][0], vreg[nt][1]);
          vkeep[mt][nt].y = pack2(vreg[nt][2], vreg[nt][3]);
        }
      }
    }
  }

  // ---- Phase 2: phi^T GEMM ; phi = exp2(acc + lf) -> fp8 global ; keep phik bf16 regs ----
  uint2 keep0[8], keep1[8];
#pragma unroll
  for (int sm = 0; sm < 2; ++sm) {
    s8v bsf[2][2];  // [nt2][ks] : B[k=c][n=node]
#pragma unroll
    for (int nt = 0; nt < 2; ++nt)
#pragma unroll
      for (int ks = 0; ks < 2; ++ks)
        bsf[nt][ks] = *(const s8v*)&sbuf[(sm * 4 + w) * 2304 + (nt * 16 + l) * 72 + ks * 32 + q * 8];
    float lf0 = sfront[(sm * 4 + w) * 32 + l];
    float lf1 = sfront[(sm * 4 + w) * 32 + 16 + l];
    unsigned char* dst = sm ? phik : phiq;
#pragma unroll
    for (int mt = 0; mt < 8; ++mt) {
      f4v a0 = (f4v)(0.f), a1 = (f4v)(0.f);
#pragma unroll
      for (int ks = 0; ks < 2; ++ks) {
        s8v ap = Pf[(mt * 2 + ks) * 64 + lane];
        a0 = __builtin_amdgcn_mfma_f32_16x16x32_bf16(ap, bsf[0][ks], a0, 0, 0, 0);
        a1 = __builtin_amdgcn_mfma_f32_16x16x32_bf16(ap, bsf[1][ks], a1, 0, 0, 0);
      }
      float v00 = fexp2(a0[0] + lf0), v01 = fexp2(a0[1] + lf0), v02 = fexp2(a0[2] + lf0), v03 = fexp2(a0[3] + lf0);
      float v10 = fexp2(a1[0] + lf1), v11 = fexp2(a1[1] + lf1), v12 = fexp2(a1[2] + lf1), v13 = fexp2(a1[3] + lf1);
      unsigned p0 = __builtin_amdgcn_cvt_pk_fp8_f32(v00, v01, 0, 0);
      p0 = __builtin_amdgcn_cvt_pk_fp8_f32(v02, v03, p0, 1);
      unsigned p1 = __builtin_amdgcn_cvt_pk_fp8_f32(v10, v11, 0, 0);
      p1 = __builtin_amdgcn_cvt_pk_fp8_f32(v12, v13, p1, 1);
      *(unsigned*)(dst + (size_t)(r0 + l) * 128 + mt * 16 + q * 4) = p0;
      *(unsigned*)(dst + (size_t)(r0 + 16 + l) * 128 + mt * 16 + q * 4) = p1;
      if (sm == 1) {
        keep0[mt].x = pack2(v00, v01); keep0[mt].y = pack2(v02, v03);
        keep1[mt].x = pack2(v10, v11); keep1[mt].y = pack2(v12, v13);
      }
    }
  }

  // ---- Fused GEMM over two 64-node halves: D[m][d] = sum_node phik[node][m] * V[node][d] ----
  f4v facc[2][4];
#pragma unroll
  for (int mtl = 0; mtl < 2; ++mtl)
#pragma unroll
    for (int nt = 0; nt < 4; ++nt) facc[mtl][nt] = (f4v)(0.f);

#pragma unroll
  for (int hf = 0; hf < 2; ++hf) {
    __syncthreads();  // previous contents (sbuf / prior half) fully consumed
    if ((w >> 1) == hf) {
      int nd0 = (w & 1) * 32 + l, nd1 = nd0 + 16;
#pragma unroll
      for (int mt = 0; mt < 8; ++mt) {
        int m = mt * 16 + q * 4;
        kbufT[(m + 0) * 68 + nd0] = (short)(keep0[mt].x & 0xffffu);
        kbufT[(m + 1) * 68 + nd0] = (short)(keep0[mt].x >> 16);
        kbufT[(m + 2) * 68 + nd0] = (short)(keep0[mt].y & 0xffffu);
        kbufT[(m + 3) * 68 + nd0] = (short)(keep0[mt].y >> 16);
        kbufT[(m + 0) * 68 + nd1] = (short)(keep1[mt].x & 0xffffu);
        kbufT[(m + 1) * 68 + nd1] = (short)(keep1[mt].x >> 16);
        kbufT[(m + 2) * 68 + nd1] = (short)(keep1[mt].y & 0xffffu);
        kbufT[(m + 3) * 68 + nd1] = (short)(keep1[mt].y >> 16);
      }
#pragma unroll
      for (int mt = 0; mt < 2; ++mt)
#pragma unroll
        for (int nt = 0; nt < 4; ++nt)
          *(uint2*)&vbufT[(nt * 16 + l) * 72 + (w & 1) * 32 + mt * 16 + q * 4] = vkeep[mt][nt];
    }
    __syncthreads();  // half ready
#pragma unroll
    for (int kc = 0; kc < 2; ++kc) {
      s8v bv[4];
#pragma unroll
      for (int nt = 0; nt < 4; ++nt)
        bv[nt] = *(const s8v*)&vbufT[(nt * 16 + l) * 72 + kc * 32 + q * 8];
      s8v av[2];
#pragma unroll
      for (int mtl = 0; mtl < 2; ++mtl) {
        const short* kb = &kbufT[((2 * w + mtl) * 16 + l) * 68 + kc * 32 + q * 8];
        union { s8v v; long long L[2]; } ua;
        ua.L[0] = *(const long long*)kb;
        ua.L[1] = *(const long long*)(kb + 4);
        av[mtl] = ua.v;
      }
#pragma unroll
      for (int mtl = 0; mtl < 2; ++mtl)
#pragma unroll
        for (int nt = 0; nt < 4; ++nt)
          facc[mtl][nt] = __builtin_amdgcn_mfma_f32_16x16x32_bf16(av[mtl], bv[nt], facc[mtl][nt], 0, 0, 0);
    }
  }

  // store part[t][h][d][m] bf16, m-contiguous 8B stores
#pragma unroll
  for (int mtl = 0; mtl < 2; ++mtl)
#pragma unroll
    for (int nt = 0; nt < 4; ++nt) {
      uint2 pk;
      pk.x = pack2(facc[mtl][nt][0], facc[mtl][nt][1]);
      pk.y = pack2(facc[mtl][nt][2], facc[mtl][nt][3]);
      int d = nt * 16 + l;
      int m = (2 * w + mtl) * 16 + q * 4;
      *(uint2*)(part + ((size_t)((t * 8 + h) * 64 + d)) * 128 + m) = pk;
    }
}

// ---------------- K35: fused (blocks<128: reduce partials -> lastB bf8) + (else: link loss) ----------------
__global__ __launch_bounds__(256) void k35(const unsigned* __restrict__ part32, unsigned char* __restrict__ lastB,
                                           const unsigned char* __restrict__ phiq,
                                           const unsigned char* __restrict__ phik,
                                           const int* __restrict__ ei, float* __restrict__ ea) {
  int b = blockIdx.x;
  if (b < 128) {
    // reduce 256 bf16 partials -> lastB (bf8 e5m2, B-frag byte order)
    int t2 = b * 256 + threadIdx.x;  // 32768 = h*4096 + d*64 + m/2
    float s0 = 0.f, s1 = 0.f;
#pragma unroll 16
    for (int c = 0; c < 256; ++c) {
      unsigned v = part32[((size_t)c << 12) + t2];
      s0 += __uint_as_float(v << 16);
      s1 += __uint_as_float(v & 0xffff0000u);
    }
    int m = (t2 & 63) * 2, d = (t2 >> 6) & 63, h = t2 >> 12;
    int ks = m >> 5, j = m & 7, qq = (m >> 3) & 3;
    int lane = qq * 16 + (d & 15), nt = d >> 4;
    unsigned r = __builtin_amdgcn_cvt_pk_bf8_f32(s0, s1, 0, 0);
    *(unsigned short*)(lastB + ((((h * 4 + ks) * 4 + nt) * 64 + lane) << 3) + j) = (unsigned short)r;
    return;
  }
  // link loss: 8 edges per wave, 2-edge batches for load ILP
  __shared__ float part[4];
  int lane = threadIdx.x & 63, w = threadIdx.x >> 6;
  int wid = (b - 128) * 4 + w;  // 8192 waves
  float acc0 = 0.f, acc1 = 0.f;
#pragma unroll
  for (int i = 0; i < 8; i += 2) {
    int e0 = wid * 8 + i, e1 = e0 + 1;
    int s0 = ei[e0], d0 = ei[NEDGES + e0];
    int s1 = ei[e1], d1 = ei[NEDGES + e1];
    uint4 qa = *(const uint4*)(phiq + (size_t)d0 * 1024 + lane * 16);
    uint4 ka = *(const uint4*)(phik + (size_t)s0 * 1024 + lane * 16);
    uint4 qb = *(const uint4*)(phiq + (size_t)d1 * 1024 + lane * 16);
    uint4 kb = *(const uint4*)(phik + (size_t)s1 * 1024 + lane * 16);
    unsigned qs[8] = {qa.x, qa.y, qa.z, qa.w, qb.x, qb.y, qb.z, qb.w};
    unsigned ks[8] = {ka.x, ka.y, ka.z, ka.w, kb.x, kb.y, kb.z, kb.w};
#pragma unroll
    for (int p = 0; p < 8; ++p) {
      f2v q0 = __builtin_amdgcn_cvt_pk_f32_fp8(qs[p], 0);
      f2v q1 = __builtin_amdgcn_cvt_pk_f32_fp8(qs[p], 1);
      f2v k0 = __builtin_amdgcn_cvt_pk_f32_fp8(ks[p], 0);
      f2v k1 = __builtin_amdgcn_cvt_pk_f32_fp8(ks[p], 1);
      float t0 = fmaf(q0.x, k0.x, q0.y * k0.y);
      float t1 = fmaf(q1.x, k1.x, q1.y * k1.y);
      if (p < 4) acc0 += t0 + t1; else acc1 += t0 + t1;
    }
  }
  float acc = acc0 + acc1;
#pragma unroll
  for (int o = 1; o < 64; o <<= 1) acc += __shfl_xor(acc, o, 64);
  if (lane == 0) part[w] = acc;
  __syncthreads();
  if (threadIdx.x == 0) atomicAdd(ea, part[0] + part[1] + part[2] + part[3]);
}

// ---------------- K4: fp8xbf8 MFMA zo = phiq @ last[h'] ; row-norm; 8-head mean; final normalize ----------------
__global__ __launch_bounds__(512) void k4_mfma(const unsigned char* __restrict__ phiq,
                                               const unsigned char* __restrict__ lastB,
                                               const float* __restrict__ ea, float* __restrict__ out) {
  __shared__ unsigned zbufT[8][64][18];
  int w = threadIdx.x >> 6, lane = threadIdx.x & 63;
  int q = lane >> 4, l = lane & 15;
  int n0 = blockIdx.x * 32;

  const long* Bf = (const long*)lastB;
  long bf[4][4];
#pragma unroll
  for (int ks = 0; ks < 4; ++ks)
#pragma unroll
    for (int nt = 0; nt < 4; ++nt) bf[ks][nt] = Bf[((w * 4 + ks) * 4 + nt) * 64 + lane];

  long af[2][4];
#pragma unroll
  for (int mt = 0; mt < 2; ++mt)
#pragma unroll
    for (int ks = 0; ks < 4; ++ks)
      af[mt][ks] = *(const long*)(phiq + (size_t)(8 * (n0 + mt * 16 + l) + w) * 128 + ks * 32 + q * 8);

  f4v acc[2][4];
#pragma unroll
  for (int mt = 0; mt < 2; ++mt)
#pragma unroll
    for (int nt = 0; nt < 4; ++nt) acc[mt][nt] = (f4v)(0.f);
#pragma unroll
  for (int ks = 0; ks < 4; ++ks)
#pragma unroll
    for (int nt = 0; nt < 4; ++nt)
#pragma unroll
      for (int mt = 0; mt < 2; ++mt)
        acc[mt][nt] = __builtin_amdgcn_mfma_f32_16x16x32_fp8_bf8(af[mt][ks], bf[ks][nt], acc[mt][nt], 0, 0, 0);

#pragma unroll
  for (int mt = 0; mt < 2; ++mt) {
    float rs[4];
#pragma unroll
    for (int reg = 0; reg < 4; ++reg) {
      float v0 = acc[mt][0][reg];
      float s0 = (l == 0) ? -v0 * v0 : v0 * v0;
      rs[reg] = s0 + acc[mt][1][reg] * acc[mt][1][reg] + acc[mt][2][reg] * acc[mt][2][reg] +
                acc[mt][3][reg] * acc[mt][3][reg];
    }
#pragma unroll
    for (int reg = 0; reg < 4; ++reg) {
#pragma unroll
      for (int off = 1; off < 16; off <<= 1) rs[reg] += __shfl_xor(rs[reg], off, 64);
    }
    float inv[4];
#pragma unroll
    for (int reg = 0; reg < 4; ++reg) inv[reg] = frcp(fsqrt(fabsf(rs[reg])));
#pragma unroll
    for (int nt = 0; nt < 4; ++nt) {
      uint2 pk;
      pk.x = pack2(acc[mt][nt][0] * inv[0], acc[mt][nt][1] * inv[1]);
      pk.y = pack2(acc[mt][nt][2] * inv[2], acc[mt][nt][3] * inv[3]);
      *(uint2*)&zbufT[w][nt * 16 + l][mt * 8 + q * 2] = pk;
    }
  }
  __syncthreads();

  int tid = threadIdx.x;
  int i = tid >> 4, dg = tid & 15;  // row i 0..31, d-group dg*4..+3
  int i2 = i >> 1, sel = i & 1;
  float s[4] = {0.f, 0.f, 0.f, 0.f};
#pragma unroll
  for (int w2 = 0; w2 < 8; ++w2) {
#pragma unroll
    for (int j = 0; j < 4; ++j) {
      unsigned u = zbufT[w2][dg * 4 + j][i2];
      s[j] += bf2f((unsigned short)(sel ? (u >> 16) : (u & 0xffffu)));
    }
  }
  float m2 = 0.f;
#pragma unroll
  for (int j = 0; j < 4; ++j) {
    s[j] *= 0.125f;
    m2 += ((dg == 0 && j == 0) ? -s[j] * s[j] : s[j] * s[j]);
  }
#pragma unroll
  for (int off = 1; off < 16; off <<= 1) m2 += __shfl_xor(m2, off, 64);
  float inv = frcp(fsqrt(fabsf(m2)));
  float4 o = make_float4(s[0] * inv, s[1] * inv, s[2] * inv, s[3] * inv);
  *(float4*)(out + (size_t)(n0 + i) * 64 + dg * 4) = o;
  if (blockIdx.x == 0 && tid == 0) out[(size_t)NNODES * 64] = ea[0] * (1.0f / 524288.0f);
}

// ---------------- launch ----------------
extern "C" void kernel_launch(void* const* d_in, const int* in_sizes, int n_in,
                              void* d_out, int out_size, void* d_ws, size_t ws_size,
                              hipStream_t stream) {
  const float* z  = (const float*)d_in[0];
  const float* Wq = (const float*)d_in[1];
  const float* Wk = (const float*)d_in[2];
  const float* Wv = (const float*)d_in[3];
  const float* P  = (const float*)d_in[4];
  const int* ei   = (const int*)d_in[5];
  char* ws = (char*)d_ws;
  unsigned short* Wfrag = (unsigned short*)(ws + OFF_WFRAG);
  unsigned char*  lastB = (unsigned char*)(ws + OFF_LASTB);  // sequenced reuse of Wfrag region
  unsigned short* Pfrag = (unsigned short*)(ws + OFF_PFRAG);
  float*          ea    = (float*)(ws + OFF_EA);
  unsigned short* ubf   = (unsigned short*)(ws + OFF_U);
  unsigned short* part  = (unsigned short*)(ws + OFF_PART);
  unsigned char*  phiq  = (unsigned char*)(ws + OFF_PHIQ);
  unsigned char*  phik  = (unsigned char*)(ws + OFF_PHIK);

  k01_prep<<<2048, 256, 0, stream>>>(z, ubf, Wq, Wk, Wv, P, Wfrag, Pfrag, ea);
  k2_mfma<<<2048, 256, 0, stream>>>(ubf, Wfrag, Pfrag, phiq, phik, part);
  k35<<<128 + 2048, 256, 0, stream>>>((const unsigned*)part, lastB, phiq, phik, ei, ea);
  k4_mfma<<<NNODES / 32, 512, 0, stream>>>(phiq, lastB, ea, (float*)d_out);
}